// Round 1
// baseline (6163.356 us; speedup 1.0000x reference)
//
#include <hip/hip_runtime.h>
#include <hip/hip_bf16.h>
#include <math.h>

#define N_NODES 50000
#define N_EDGES 800000
#define DIM 128
#define NHEAD 8
#define DHEAD 16
#define SDIM 10

// ---------- order-preserving float<->uint encoding for atomicMax ----------
__device__ __forceinline__ unsigned fenc(float f) {
    unsigned u = __float_as_uint(f);
    return (u & 0x80000000u) ? ~u : (u | 0x80000000u);
}
__device__ __forceinline__ float fdec(unsigned u) {
    return __uint_as_float((u & 0x80000000u) ? (u ^ 0x80000000u) : ~u);
}
#define ENC_NEG_INF 0x007FFFFFu   // fenc(-inf)

// ---------- init accumulators ----------
__global__ __launch_bounds__(256) void init_kernel(unsigned* __restrict__ menc,
                                                   float* __restrict__ ssum,
                                                   float* __restrict__ agg) {
    int idx = blockIdx.x * 256 + threadIdx.x;
    if (idx < N_NODES * DIM) agg[idx] = 0.f;
    if (idx < N_NODES * NHEAD) { menc[idx] = ENC_NEG_INF; ssum[idx] = 0.f; }
}

// ---------- f32 GEMM: C[n,128] = A[n,128] @ W[128,128] + bias (opt relu) ----
// Block: 256 threads. Per block: 64 rows in two 32-row chunks.
// W fully staged in LDS (64KB); X chunk staged (16KB). 4x4 register blocking.
template <int RELU>
__global__ __launch_bounds__(256) void gemm128_kernel(
    const float* __restrict__ A, const float* __restrict__ W,
    const float* __restrict__ bias, float* __restrict__ C, int nrows) {
    __shared__ float Wl[128 * 128];
    __shared__ float Xl[32 * 128];
    const int t = threadIdx.x;
    {
        const float4* W4 = (const float4*)W;
        float4* Wl4 = (float4*)Wl;
#pragma unroll
        for (int i = 0; i < 16; ++i) Wl4[t + 256 * i] = W4[t + 256 * i];
    }
    const int tc = t & 31;   // column group: cols 4*tc .. 4*tc+3
    const int tr = t >> 5;   // row group: rows 4*tr .. 4*tr+3 within chunk
    const float4 bv = ((const float4*)bias)[tc];
    const int row0 = blockIdx.x * 64;

    for (int chunk = 0; chunk < 64; chunk += 32) {
        const int rbase = row0 + chunk;
        __syncthreads();   // W visible (1st iter) / Xl reuse safe (2nd iter)
#pragma unroll
        for (int i = 0; i < 4; ++i) {
            int idx = t + 256 * i;          // float4 slot in 32x128 tile
            int r = idx >> 5, cc = idx & 31;
            float4 val = {0.f, 0.f, 0.f, 0.f};
            if (rbase + r < nrows) val = ((const float4*)A)[(size_t)(rbase + r) * 32 + cc];
            ((float4*)Xl)[idx] = val;
        }
        __syncthreads();

        float acc[4][4] = {};
#pragma unroll 8
        for (int k = 0; k < 128; ++k) {
            float4 w = *(const float4*)&Wl[k * 128 + tc * 4];
#pragma unroll
            for (int i = 0; i < 4; ++i) {
                float xv = Xl[(tr * 4 + i) * 128 + k];
                acc[i][0] = fmaf(xv, w.x, acc[i][0]);
                acc[i][1] = fmaf(xv, w.y, acc[i][1]);
                acc[i][2] = fmaf(xv, w.z, acc[i][2]);
                acc[i][3] = fmaf(xv, w.w, acc[i][3]);
            }
        }
#pragma unroll
        for (int i = 0; i < 4; ++i) {
            int r = rbase + tr * 4 + i;
            if (r < nrows) {
                float4 o;
                o.x = acc[i][0] + bv.x;
                o.y = acc[i][1] + bv.y;
                o.z = acc[i][2] + bv.z;
                o.w = acc[i][3] + bv.w;
                if (RELU) {
                    o.x = fmaxf(o.x, 0.f); o.y = fmaxf(o.y, 0.f);
                    o.z = fmaxf(o.z, 0.f); o.w = fmaxf(o.w, 0.f);
                }
                ((float4*)C)[(size_t)r * 32 + tc] = o;
            }
        }
    }
}

// ---------- sec_bias[n,h] = security_features[n,:] @ Wsec + bsec ----------
__global__ __launch_bounds__(256) void secbias_kernel(
    const float* __restrict__ sec, const float* __restrict__ Wsec,
    const float* __restrict__ bsec, float* __restrict__ secb) {
    int idx = blockIdx.x * 256 + threadIdx.x;
    if (idx >= N_NODES * NHEAD) return;
    int n = idx >> 3, h = idx & 7;
    float acc = bsec[h];
#pragma unroll
    for (int j = 0; j < SDIM; ++j) acc = fmaf(sec[n * SDIM + j], Wsec[j * NHEAD + h], acc);
    secb[idx] = acc;
}

// ---------- pass 1: scores + segment max ----------
__global__ __launch_bounds__(256) void scores_kernel(
    const float* __restrict__ q, const float* __restrict__ k,
    const float* __restrict__ secb, const int* __restrict__ src,
    const int* __restrict__ dst, float* __restrict__ scores,
    unsigned* __restrict__ menc) {
    int idx = blockIdx.x * 256 + threadIdx.x;
    if (idx >= N_EDGES * NHEAD) return;
    int e = idx >> 3, h = idx & 7;
    int s = src[e], d = dst[e];
    const float4* qr = (const float4*)(q + (size_t)d * DIM + h * DHEAD);
    const float4* kr = (const float4*)(k + (size_t)s * DIM + h * DHEAD);
    float acc = 0.f;
#pragma unroll
    for (int i = 0; i < 4; ++i) {
        float4 a = qr[i], b = kr[i];
        acc += a.x * b.x + a.y * b.y + a.z * b.z + a.w * b.w;
    }
    float sc = acc * 0.25f + secb[s * NHEAD + h];   // 1/sqrt(16) = 0.25
    scores[idx] = sc;
    atomicMax(&menc[d * NHEAD + h], fenc(sc));
}

// ---------- pass 2: exp + segment sum ----------
__global__ __launch_bounds__(256) void exp_kernel(
    float* __restrict__ scores, const int* __restrict__ dst,
    const unsigned* __restrict__ menc, float* __restrict__ ssum) {
    int idx = blockIdx.x * 256 + threadIdx.x;
    if (idx >= N_EDGES * NHEAD) return;
    int e = idx >> 3, h = idx & 7;
    int d = dst[e];
    float ev = expf(scores[idx] - fdec(menc[d * NHEAD + h]));
    scores[idx] = ev;
    atomicAdd(&ssum[d * NHEAD + h], ev);
}

// ---------- pass 3: normalize (final attn) + scatter attn*v into agg ----------
__global__ __launch_bounds__(256) void normscatter_kernel(
    float* __restrict__ attn, const int* __restrict__ src,
    const int* __restrict__ dst, const float* __restrict__ ssum,
    const float* __restrict__ v, float* __restrict__ agg) {
    int idx = blockIdx.x * 256 + threadIdx.x;
    if (idx >= N_EDGES * NHEAD) return;
    int e = idx >> 3, h = idx & 7;
    int s = src[e], d = dst[e];
    float a = attn[idx] / (ssum[d * NHEAD + h] + 1e-9f);
    attn[idx] = a;
    const float4* vr = (const float4*)(v + (size_t)s * DIM + h * DHEAD);
    float* ag = agg + (size_t)d * DIM + h * DHEAD;
#pragma unroll
    for (int i = 0; i < 4; ++i) {
        float4 vv = vr[i];
        atomicAdd(ag + 4 * i + 0, a * vv.x);
        atomicAdd(ag + 4 * i + 1, a * vv.y);
        atomicAdd(ag + 4 * i + 2, a * vv.z);
        atomicAdd(ag + 4 * i + 3, a * vv.w);
    }
}

// ---------- fused residual-add + LayerNorm (wave per row) ----------
__global__ __launch_bounds__(256) void ln_add_kernel(
    const float* __restrict__ A, const float* __restrict__ B,
    const float* __restrict__ g, const float* __restrict__ be,
    float* __restrict__ out) {
    int row = blockIdx.x * 4 + (threadIdx.x >> 6);
    int lane = threadIdx.x & 63;
    if (row >= N_NODES) return;
    float2 av = ((const float2*)(A + (size_t)row * DIM))[lane];
    float2 bvv = ((const float2*)(B + (size_t)row * DIM))[lane];
    float x0 = av.x + bvv.x, x1 = av.y + bvv.y;
    float s = x0 + x1;
#pragma unroll
    for (int m = 32; m; m >>= 1) s += __shfl_xor(s, m);
    float mean = s * (1.f / 128.f);
    float d0 = x0 - mean, d1 = x1 - mean;
    float vs = d0 * d0 + d1 * d1;
#pragma unroll
    for (int m = 32; m; m >>= 1) vs += __shfl_xor(vs, m);
    float r = rsqrtf(vs * (1.f / 128.f) + 1e-5f);
    float2 gv = ((const float2*)g)[lane];
    float2 bev = ((const float2*)be)[lane];
    float2 o;
    o.x = d0 * r * gv.x + bev.x;
    o.y = d1 * r * gv.y + bev.y;
    ((float2*)(out + (size_t)row * DIM))[lane] = o;
}

extern "C" void kernel_launch(void* const* d_in, const int* in_sizes, int n_in,
                              void* d_out, int out_size, void* d_ws, size_t ws_size,
                              hipStream_t stream) {
    const float* x    = (const float*)d_in[0];
    const int*   ei   = (const int*)d_in[1];
    const float* sec  = (const float*)d_in[2];
    const float* W1   = (const float*)d_in[3];
    const float* b1   = (const float*)d_in[4];
    const float* W2   = (const float*)d_in[5];
    const float* b2   = (const float*)d_in[6];
    const float* Wq   = (const float*)d_in[7];
    const float* bq   = (const float*)d_in[8];
    const float* Wk   = (const float*)d_in[9];
    const float* bk   = (const float*)d_in[10];
    const float* Wv   = (const float*)d_in[11];
    const float* bvp  = (const float*)d_in[12];
    const float* Wsec = (const float*)d_in[13];
    const float* bsec = (const float*)d_in[14];
    const float* Wo   = (const float*)d_in[15];
    const float* bo   = (const float*)d_in[16];
    const float* g1   = (const float*)d_in[17];
    const float* be1  = (const float*)d_in[18];
    const float* g2   = (const float*)d_in[19];
    const float* be2  = (const float*)d_in[20];

    const int* srcp = ei;             // edge_index[0]
    const int* dstp = ei + N_EDGES;   // edge_index[1]

    float* ws = (float*)d_ws;
    float* h    = ws;                   // N*128
    float* q    = ws + 6400000;         // N*128
    float* kbuf = ws + 12800000;        // N*128 (later reused: attended)
    float* v    = ws + 19200000;        // N*128 (later reused: relu branch)
    float* agg  = ws + 25600000;        // N*128
    float* secb = ws + 32000000;        // N*8
    unsigned* menc = (unsigned*)(ws + 32400000); // N*8
    float* ssum = ws + 32800000;        // N*8   -> total 33.2M floats (~133MB)

    float* outp = (float*)d_out;              // [N,128]
    float* attn = outp + (size_t)N_NODES * DIM; // [E,8] (staged as scores, then exp, then attn)

    dim3 blk(256);
    const int gemm_grid = (N_NODES + 63) / 64;
    const int egrid = (N_EDGES * NHEAD + 255) / 256;

    init_kernel<<<(N_NODES * DIM + 255) / 256, blk, 0, stream>>>(menc, ssum, agg);

    gemm128_kernel<1><<<gemm_grid, blk, 0, stream>>>(x, W1, b1, h, N_NODES);
    gemm128_kernel<0><<<gemm_grid, blk, 0, stream>>>(h, Wq, bq, q, N_NODES);
    gemm128_kernel<0><<<gemm_grid, blk, 0, stream>>>(h, Wk, bk, kbuf, N_NODES);
    gemm128_kernel<0><<<gemm_grid, blk, 0, stream>>>(h, Wv, bvp, v, N_NODES);
    secbias_kernel<<<(N_NODES * NHEAD + 255) / 256, blk, 0, stream>>>(sec, Wsec, bsec, secb);

    scores_kernel<<<egrid, blk, 0, stream>>>(q, kbuf, secb, srcp, dstp, attn, menc);
    exp_kernel<<<egrid, blk, 0, stream>>>(attn, dstp, menc, ssum);
    normscatter_kernel<<<egrid, blk, 0, stream>>>(attn, srcp, dstp, ssum, v, agg);

    gemm128_kernel<0><<<gemm_grid, blk, 0, stream>>>(agg, Wo, bo, kbuf, N_NODES);   // attended
    ln_add_kernel<<<(N_NODES + 3) / 4, blk, 0, stream>>>(h, kbuf, g1, be1, q);      // out_mid
    gemm128_kernel<1><<<gemm_grid, blk, 0, stream>>>(q, W2, b2, v, N_NODES);        // relu branch
    ln_add_kernel<<<(N_NODES + 3) / 4, blk, 0, stream>>>(q, v, g2, be2, outp);      // final out
}

// Round 2
// 706.287 us; speedup vs baseline: 8.7264x; 8.7264x over previous
//
#include <hip/hip_runtime.h>
#include <hip/hip_bf16.h>
#include <math.h>

#define N_NODES 50000
#define N_EDGES 800000
#define DIM 128
#define NHEAD 8
#define DHEAD 16
#define SDIM 10

// ---------- f32 GEMM: C[n,128] = A[n,128] @ W[128,128] + bias (opt relu) ----
// Block: 256 threads. Per block: 64 rows in two 32-row chunks.
// W fully staged in LDS (64KB); X chunk staged (16KB). 4x4 register blocking.
// NOTE: safe for in-place C==A (each 32-row chunk is fully staged to LDS
// before any of its C rows are written; blocks own disjoint rows).
template <int RELU>
__global__ __launch_bounds__(256) void gemm128_kernel(
    const float* __restrict__ A, const float* __restrict__ W,
    const float* __restrict__ bias, float* __restrict__ C, int nrows) {
    __shared__ float Wl[128 * 128];
    __shared__ float Xl[32 * 128];
    const int t = threadIdx.x;
    {
        const float4* W4 = (const float4*)W;
        float4* Wl4 = (float4*)Wl;
#pragma unroll
        for (int i = 0; i < 16; ++i) Wl4[t + 256 * i] = W4[t + 256 * i];
    }
    const int tc = t & 31;   // column group: cols 4*tc .. 4*tc+3
    const int tr = t >> 5;   // row group: rows 4*tr .. 4*tr+3 within chunk
    const float4 bv = ((const float4*)bias)[tc];
    const int row0 = blockIdx.x * 64;

    for (int chunk = 0; chunk < 64; chunk += 32) {
        const int rbase = row0 + chunk;
        __syncthreads();   // W visible (1st iter) / Xl reuse safe (2nd iter)
#pragma unroll
        for (int i = 0; i < 4; ++i) {
            int idx = t + 256 * i;          // float4 slot in 32x128 tile
            int r = idx >> 5, cc = idx & 31;
            float4 val = {0.f, 0.f, 0.f, 0.f};
            if (rbase + r < nrows) val = ((const float4*)A)[(size_t)(rbase + r) * 32 + cc];
            ((float4*)Xl)[idx] = val;
        }
        __syncthreads();

        float acc[4][4] = {};
#pragma unroll 8
        for (int k = 0; k < 128; ++k) {
            float4 w = *(const float4*)&Wl[k * 128 + tc * 4];
#pragma unroll
            for (int i = 0; i < 4; ++i) {
                float xv = Xl[(tr * 4 + i) * 128 + k];
                acc[i][0] = fmaf(xv, w.x, acc[i][0]);
                acc[i][1] = fmaf(xv, w.y, acc[i][1]);
                acc[i][2] = fmaf(xv, w.z, acc[i][2]);
                acc[i][3] = fmaf(xv, w.w, acc[i][3]);
            }
        }
#pragma unroll
        for (int i = 0; i < 4; ++i) {
            int r = rbase + tr * 4 + i;
            if (r < nrows) {
                float4 o;
                o.x = acc[i][0] + bv.x;
                o.y = acc[i][1] + bv.y;
                o.z = acc[i][2] + bv.z;
                o.w = acc[i][3] + bv.w;
                if (RELU) {
                    o.x = fmaxf(o.x, 0.f); o.y = fmaxf(o.y, 0.f);
                    o.z = fmaxf(o.z, 0.f); o.w = fmaxf(o.w, 0.f);
                }
                ((float4*)C)[(size_t)r * 32 + tc] = o;
            }
        }
    }
}

// ---------- sec_bias[n,h] = security_features[n,:] @ Wsec + bsec ----------
__global__ __launch_bounds__(256) void secbias_kernel(
    const float* __restrict__ sec, const float* __restrict__ Wsec,
    const float* __restrict__ bsec, float* __restrict__ secb) {
    int idx = blockIdx.x * 256 + threadIdx.x;
    if (idx >= N_NODES * NHEAD) return;
    int n = idx >> 3, h = idx & 7;
    float acc = bsec[h];
#pragma unroll
    for (int j = 0; j < SDIM; ++j) acc = fmaf(sec[n * SDIM + j], Wsec[j * NHEAD + h], acc);
    secb[idx] = acc;
}

// ---------- edge-parallel raw scores (no atomics) ----------
__global__ __launch_bounds__(256) void scores_kernel(
    const float* __restrict__ q, const float* __restrict__ k,
    const float* __restrict__ secb, const int* __restrict__ src,
    const int* __restrict__ dst, float* __restrict__ scores) {
    int idx = blockIdx.x * 256 + threadIdx.x;
    if (idx >= N_EDGES * NHEAD) return;
    int e = idx >> 3, h = idx & 7;
    int s = src[e], d = dst[e];
    const float4* qr = (const float4*)(q + (size_t)d * DIM + h * DHEAD);
    const float4* kr = (const float4*)(k + (size_t)s * DIM + h * DHEAD);
    float acc = 0.f;
#pragma unroll
    for (int i = 0; i < 4; ++i) {
        float4 a = qr[i], b = kr[i];
        acc += a.x * b.x + a.y * b.y + a.z * b.z + a.w * b.w;
    }
    scores[idx] = acc * 0.25f + secb[s * NHEAD + h];   // 1/sqrt(16) = 0.25
}

// ---------- CSR build ----------
__global__ __launch_bounds__(256) void zero_int2_kernel(int* __restrict__ a,
                                                        int* __restrict__ b) {
    int idx = blockIdx.x * 256 + threadIdx.x;
    if (idx < N_NODES) { a[idx] = 0; b[idx] = 0; }
}

__global__ __launch_bounds__(256) void count_deg_kernel(const int* __restrict__ dst,
                                                        int* __restrict__ deg) {
    int e = blockIdx.x * 256 + threadIdx.x;
    if (e < N_EDGES) atomicAdd(&deg[dst[e]], 1);
}

// single-block exclusive scan over N_NODES degrees -> rowstart[N+1]
__global__ __launch_bounds__(256) void scan_kernel(const int* __restrict__ deg,
                                                   int* __restrict__ rowstart) {
    __shared__ int sums[256];
    const int t = threadIdx.x;
    const int CH = (N_NODES + 255) / 256;
    const int base = t * CH;
    int s = 0;
    for (int i = 0; i < CH; ++i) {
        int idx = base + i;
        if (idx < N_NODES) s += deg[idx];
    }
    sums[t] = s;
    __syncthreads();
    if (t == 0) {
        int run = 0;
        for (int i = 0; i < 256; ++i) { int tmp = sums[i]; sums[i] = run; run += tmp; }
        rowstart[N_NODES] = run;
    }
    __syncthreads();
    int run = sums[t];
    for (int i = 0; i < CH; ++i) {
        int idx = base + i;
        if (idx < N_NODES) { rowstart[idx] = run; run += deg[idx]; }
    }
}

__global__ __launch_bounds__(256) void fill_csr_kernel(
    const int* __restrict__ dst, const int* __restrict__ rowstart,
    int* __restrict__ ctr, int* __restrict__ eidx) {
    int e = blockIdx.x * 256 + threadIdx.x;
    if (e >= N_EDGES) return;
    int d = dst[e];
    int pos = atomicAdd(&ctr[d], 1);
    eidx[rowstart[d] + pos] = e;
}

// ---------- per-node softmax + aggregation (wave per destination node) ----
// scores: [E,8] raw scores (lives in the attn slice of d_out; overwritten
// in place with the normalized attn at the end — each edge is owned by
// exactly one node's wave, and within a lane the read precedes the write).
__global__ __launch_bounds__(256) void node_attn_kernel(
    float* __restrict__ scores, const int* __restrict__ eidx,
    const int* __restrict__ rowstart, const int* __restrict__ src,
    const float* __restrict__ v, float* __restrict__ agg) {
    int node = blockIdx.x * 4 + (threadIdx.x >> 6);
    if (node >= N_NODES) return;
    const int lane = threadIdx.x & 63;
    const int start = rowstart[node];
    const int deg = rowstart[node + 1] - start;
    if (deg == 0) {
        float2 z = {0.f, 0.f};
        ((float2*)(agg + (size_t)node * DIM))[lane] = z;
        return;
    }
    const int h = lane & 7;     // head (phase A/B/D mapping)
    const int le = lane >> 3;   // edge slot 0..7
    const int hc = lane >> 3;   // head (phase C mapping: 8 lanes per head)

    // Phase A: per-head max over incoming edges
    float m = -INFINITY;
    for (int j = 0; j < deg; j += 8) {
        int jj = j + le;
        float scv = -INFINITY;
        if (jj < deg) {
            int e = eidx[start + jj];
            scv = scores[(size_t)e * NHEAD + h];
        }
        m = fmaxf(m, scv);
    }
    m = fmaxf(m, __shfl_xor(m, 8));
    m = fmaxf(m, __shfl_xor(m, 16));
    m = fmaxf(m, __shfl_xor(m, 32));
    // every lane now holds max for head (lane&7)

    // Phase B/C: unnormalized aggregation + sum of exp
    float ssum = 0.f;
    float2 acc = {0.f, 0.f};
    for (int j = 0; j < deg; j += 8) {
        int jj = j + le;
        float ev = 0.f;
        if (jj < deg) {
            int e = eidx[start + jj];
            ev = expf(scores[(size_t)e * NHEAD + h] - m);
        }
        ssum += ev;
        int lim = deg - j; if (lim > 8) lim = 8;
        for (int le2 = 0; le2 < lim; ++le2) {
            float evd = __shfl(ev, le2 * 8 + hc);     // exp for (edge j+le2, head hc)
            int e = eidx[start + j + le2];            // wave-uniform
            int s = src[e];
            float2 vv = ((const float2*)(v + (size_t)s * DIM))[lane];
            acc.x = fmaf(evd, vv.x, acc.x);
            acc.y = fmaf(evd, vv.y, acc.y);
        }
    }
    ssum += __shfl_xor(ssum, 8);
    ssum += __shfl_xor(ssum, 16);
    ssum += __shfl_xor(ssum, 32);
    const float rinv = 1.f / (ssum + 1e-9f);      // for head (lane&7)
    const float rinv_c = __shfl(rinv, hc);        // for head (lane>>3)

    acc.x *= rinv_c;
    acc.y *= rinv_c;
    ((float2*)(agg + (size_t)node * DIM))[lane] = acc;

    // Phase D: write normalized attn (recompute exp; same-lane read->write)
    for (int j = 0; j < deg; j += 8) {
        int jj = j + le;
        if (jj < deg) {
            int e = eidx[start + jj];
            float a = expf(scores[(size_t)e * NHEAD + h] - m) * rinv;
            scores[(size_t)e * NHEAD + h] = a;
        }
    }
}

// ---------- fused residual-add + LayerNorm (wave per row) ----------
__global__ __launch_bounds__(256) void ln_add_kernel(
    const float* __restrict__ A, const float* __restrict__ B,
    const float* __restrict__ g, const float* __restrict__ be,
    float* __restrict__ out) {
    int row = blockIdx.x * 4 + (threadIdx.x >> 6);
    int lane = threadIdx.x & 63;
    if (row >= N_NODES) return;
    float2 av = ((const float2*)(A + (size_t)row * DIM))[lane];
    float2 bvv = ((const float2*)(B + (size_t)row * DIM))[lane];
    float x0 = av.x + bvv.x, x1 = av.y + bvv.y;
    float s = x0 + x1;
#pragma unroll
    for (int m = 32; m; m >>= 1) s += __shfl_xor(s, m);
    float mean = s * (1.f / 128.f);
    float d0 = x0 - mean, d1 = x1 - mean;
    float vs = d0 * d0 + d1 * d1;
#pragma unroll
    for (int m = 32; m; m >>= 1) vs += __shfl_xor(vs, m);
    float r = rsqrtf(vs * (1.f / 128.f) + 1e-5f);
    float2 gv = ((const float2*)g)[lane];
    float2 bev = ((const float2*)be)[lane];
    float2 o;
    o.x = d0 * r * gv.x + bev.x;
    o.y = d1 * r * gv.y + bev.y;
    ((float2*)(out + (size_t)row * DIM))[lane] = o;
}

extern "C" void kernel_launch(void* const* d_in, const int* in_sizes, int n_in,
                              void* d_out, int out_size, void* d_ws, size_t ws_size,
                              hipStream_t stream) {
    const float* x    = (const float*)d_in[0];
    const int*   ei   = (const int*)d_in[1];
    const float* sec  = (const float*)d_in[2];
    const float* W1   = (const float*)d_in[3];
    const float* b1   = (const float*)d_in[4];
    const float* W2   = (const float*)d_in[5];
    const float* b2   = (const float*)d_in[6];
    const float* Wq   = (const float*)d_in[7];
    const float* bq   = (const float*)d_in[8];
    const float* Wk   = (const float*)d_in[9];
    const float* bk   = (const float*)d_in[10];
    const float* Wv   = (const float*)d_in[11];
    const float* bvp  = (const float*)d_in[12];
    const float* Wsec = (const float*)d_in[13];
    const float* bsec = (const float*)d_in[14];
    const float* Wo   = (const float*)d_in[15];
    const float* bo   = (const float*)d_in[16];
    const float* g1   = (const float*)d_in[17];
    const float* be1  = (const float*)d_in[18];
    const float* g2   = (const float*)d_in[19];
    const float* be2  = (const float*)d_in[20];

    const int* srcp = ei;             // edge_index[0]
    const int* dstp = ei + N_EDGES;   // edge_index[1]

    float* ws = (float*)d_ws;
    float* h    = ws;                   // N*128
    float* q    = ws + 6400000;         // N*128
    float* kbuf = ws + 12800000;        // N*128 (k; region reused for CSR ints)
    float* v    = ws + 19200000;        // N*128 (later reused: relu branch)
    float* agg  = ws + 25600000;        // N*128 (attended written in place)
    float* secb = ws + 32000000;        // N*8   -> 32.4M floats (~130MB)

    // CSR integer arrays overlay the k buffer (k's lifetime ends at scores)
    int* ibase    = (int*)kbuf;
    int* deg      = ibase;                 // N
    int* ctr      = ibase + 50048;         // N
    int* rowstart = ibase + 100096;        // N+1
    int* eidxb    = ibase + 150160;        // E

    float* outp = (float*)d_out;                 // [N,128]
    float* attn = outp + (size_t)N_NODES * DIM;  // [E,8] (raw scores -> normalized attn)

    dim3 blk(256);
    const int gemm_grid = (N_NODES + 63) / 64;
    const int egrid8 = (N_EDGES * NHEAD + 255) / 256;
    const int egrid  = (N_EDGES + 255) / 256;
    const int ngrid  = (N_NODES + 255) / 256;

    gemm128_kernel<1><<<gemm_grid, blk, 0, stream>>>(x, W1, b1, h, N_NODES);
    gemm128_kernel<0><<<gemm_grid, blk, 0, stream>>>(h, Wq, bq, q, N_NODES);
    gemm128_kernel<0><<<gemm_grid, blk, 0, stream>>>(h, Wk, bk, kbuf, N_NODES);
    gemm128_kernel<0><<<gemm_grid, blk, 0, stream>>>(h, Wv, bvp, v, N_NODES);
    secbias_kernel<<<(N_NODES * NHEAD + 255) / 256, blk, 0, stream>>>(sec, Wsec, bsec, secb);

    scores_kernel<<<egrid8, blk, 0, stream>>>(q, kbuf, secb, srcp, dstp, attn);

    // CSR build (k buffer is dead from here; ints overlay it)
    zero_int2_kernel<<<ngrid, blk, 0, stream>>>(deg, ctr);
    count_deg_kernel<<<egrid, blk, 0, stream>>>(dstp, deg);
    scan_kernel<<<1, blk, 0, stream>>>(deg, rowstart);
    fill_csr_kernel<<<egrid, blk, 0, stream>>>(dstp, rowstart, ctr, eidxb);

    node_attn_kernel<<<(N_NODES + 3) / 4, blk, 0, stream>>>(attn, eidxb, rowstart, srcp, v, agg);

    gemm128_kernel<0><<<gemm_grid, blk, 0, stream>>>(agg, Wo, bo, agg, N_NODES);  // attended (in place)
    ln_add_kernel<<<(N_NODES + 3) / 4, blk, 0, stream>>>(h, agg, g1, be1, q);     // out_mid
    gemm128_kernel<1><<<gemm_grid, blk, 0, stream>>>(q, W2, b2, v, N_NODES);      // relu branch
    ln_add_kernel<<<(N_NODES + 3) / 4, blk, 0, stream>>>(q, v, g2, be2, outp);    // final out
}

// Round 3
// 486.666 us; speedup vs baseline: 12.6644x; 1.4513x over previous
//
#include <hip/hip_runtime.h>
#include <hip/hip_bf16.h>
#include <math.h>

#define N_NODES 50000
#define N_EDGES 800000
#define DIM 128
#define NHEAD 8
#define DHEAD 16
#define SDIM 10

typedef __attribute__((ext_vector_type(8))) short bf16x8;
typedef __attribute__((ext_vector_type(4))) float f32x4;

__device__ __forceinline__ float bf2f(unsigned short u) {
    return __uint_as_float(((unsigned)u) << 16);
}
__device__ __forceinline__ unsigned short f2bf(float f) {
    unsigned u = __float_as_uint(f);
    return (unsigned short)((u + 0x7FFFu + ((u >> 16) & 1u)) >> 16);
}

// ---------- one-time weight prep: Wt[n][k] = bf16(W[k][n]), 6 matrices ------
__global__ __launch_bounds__(256) void prep_w_kernel(
    const float* __restrict__ W1, const float* __restrict__ Wq,
    const float* __restrict__ Wk, const float* __restrict__ Wv,
    const float* __restrict__ Wo, const float* __restrict__ W2,
    unsigned short* __restrict__ Wt) {
    const float* W = (blockIdx.x == 0) ? W1 : (blockIdx.x == 1) ? Wq :
                     (blockIdx.x == 2) ? Wk : (blockIdx.x == 3) ? Wv :
                     (blockIdx.x == 4) ? Wo : W2;
    unsigned short* o = Wt + blockIdx.x * 16384;
    const int t = threadIdx.x;
    for (int i = 0; i < 64; ++i) {
        int idx = t + 256 * i;          // k-major element index
        int k = idx >> 7, n = idx & 127;
        o[n * 128 + k] = f2bf(W[idx]);
    }
}

// ---------- x (f32) -> xb (bf16) ----------
__global__ __launch_bounds__(256) void x2bf_kernel(const float* __restrict__ x,
                                                   unsigned short* __restrict__ xb) {
    int idx = blockIdx.x * 256 + threadIdx.x;   // float4 index
    if (idx >= N_NODES * DIM / 4) return;
    float4 v = ((const float4*)x)[idx];
    uint2 o;
    o.x = (unsigned)f2bf(v.x) | ((unsigned)f2bf(v.y) << 16);
    o.y = (unsigned)f2bf(v.z) | ((unsigned)f2bf(v.w) << 16);
    ((uint2*)xb)[idx] = o;
}

// ---------- bf16 MFMA GEMM: C[n,128] = A[n,128] @ W[128,128] + bias --------
// A bf16 row-major; Wt bf16 transposed [n][k]. Block 256 = 4 waves;
// block computes 64 rows; wave w computes rows +w*16, all 128 cols.
// Wt staged in LDS with XOR-16B swizzle (T2) for conflict-free ds_read_b128.
template <int RELU, int OUT_BF16>
__global__ __launch_bounds__(256) void gemm_mfma_kernel(
    const unsigned short* __restrict__ A, const unsigned short* __restrict__ Wt,
    const float* __restrict__ bias, void* __restrict__ Cout, int nrows) {
    __shared__ alignas(16) unsigned char Wl[32768];
    const int t = threadIdx.x;
#pragma unroll
    for (int i = 0; i < 8; ++i) {
        int c = t + 256 * i;            // 16B chunk id (2048 total)
        int n = c >> 4, s = c & 15;     // row n, 16B slot s
        bf16x8 val = *(const bf16x8*)(Wt + c * 8);
        *(bf16x8*)(Wl + n * 256 + ((s * 16) ^ ((n & 7) << 4))) = val;
    }
    __syncthreads();

    const int l = t & 63, wave = t >> 6;
    const int l15 = l & 15, lg = l >> 4;          // lane row/col sel, k-group
    const int r0 = blockIdx.x * 64 + wave * 16;
    const int arow = r0 + l15;
    const bool aok = arow < nrows;

    f32x4 acc[8];
#pragma unroll
    for (int n = 0; n < 8; ++n) acc[n] = (f32x4){0.f, 0.f, 0.f, 0.f};

#pragma unroll
    for (int k0 = 0; k0 < 4; ++k0) {
        bf16x8 af = (bf16x8){0, 0, 0, 0, 0, 0, 0, 0};
        if (aok) af = *(const bf16x8*)(A + (size_t)arow * DIM + k0 * 32 + lg * 8);
#pragma unroll
        for (int n = 0; n < 8; ++n) {
            int row = n * 16 + l15;
            int kb = (k0 * 64 + lg * 16) ^ ((row & 7) << 4);
            bf16x8 bfr = *(const bf16x8*)(Wl + row * 256 + kb);
            acc[n] = __builtin_amdgcn_mfma_f32_16x16x32_bf16(af, bfr, acc[n], 0, 0, 0);
        }
    }

    const int orow0 = r0 + lg * 4;
#pragma unroll
    for (int n = 0; n < 8; ++n) {
        int col = n * 16 + l15;
        float bv = bias[col];
#pragma unroll
        for (int i = 0; i < 4; ++i) {
            int r = orow0 + i;
            if (r < nrows) {
                float val = acc[n][i] + bv;
                if (RELU) val = fmaxf(val, 0.f);
                if (OUT_BF16) ((unsigned short*)Cout)[(size_t)r * DIM + col] = f2bf(val);
                else          ((float*)Cout)[(size_t)r * DIM + col] = val;
            }
        }
    }
}

// ---------- sec_bias[n,h] ----------
__global__ __launch_bounds__(256) void secbias_kernel(
    const float* __restrict__ sec, const float* __restrict__ Wsec,
    const float* __restrict__ bsec, float* __restrict__ secb) {
    int idx = blockIdx.x * 256 + threadIdx.x;
    if (idx >= N_NODES * NHEAD) return;
    int n = idx >> 3, h = idx & 7;
    float acc = bsec[h];
#pragma unroll
    for (int j = 0; j < SDIM; ++j) acc = fmaf(sec[n * SDIM + j], Wsec[j * NHEAD + h], acc);
    secb[idx] = acc;
}

// ---------- CSR build ----------
__global__ __launch_bounds__(256) void zero_int2_kernel(int* __restrict__ a,
                                                        int* __restrict__ b) {
    int idx = blockIdx.x * 256 + threadIdx.x;
    if (idx < N_NODES) { a[idx] = 0; b[idx] = 0; }
}

__global__ __launch_bounds__(256) void count_deg_kernel(const int* __restrict__ dst,
                                                        int* __restrict__ deg) {
    int e = blockIdx.x * 256 + threadIdx.x;
    if (e < N_EDGES) atomicAdd(&deg[dst[e]], 1);
}

__global__ __launch_bounds__(256) void scan_kernel(const int* __restrict__ deg,
                                                   int* __restrict__ rowstart) {
    __shared__ int sums[256];
    const int t = threadIdx.x;
    const int CH = (N_NODES + 255) / 256;
    const int base = t * CH;
    int s = 0;
    for (int i = 0; i < CH; ++i) {
        int idx = base + i;
        if (idx < N_NODES) s += deg[idx];
    }
    sums[t] = s;
    __syncthreads();
    if (t == 0) {
        int run = 0;
        for (int i = 0; i < 256; ++i) { int tmp = sums[i]; sums[i] = run; run += tmp; }
        rowstart[N_NODES] = run;
    }
    __syncthreads();
    int run = sums[t];
    for (int i = 0; i < CH; ++i) {
        int idx = base + i;
        if (idx < N_NODES) { rowstart[idx] = run; run += deg[idx]; }
    }
}

__global__ __launch_bounds__(256) void fill_csr_kernel(
    const int* __restrict__ dst, const int* __restrict__ rowstart,
    int* __restrict__ ctr, int* __restrict__ eidx) {
    int e = blockIdx.x * 256 + threadIdx.x;
    if (e >= N_EDGES) return;
    int d = dst[e];
    int pos = atomicAdd(&ctr[d], 1);
    eidx[rowstart[d] + pos] = e;
}

// ---------- fused scores + softmax + aggregation (wave per dst node) -------
// Phase A: score = q[node].k[src]/4 + secb[src]  (k gathered bf16), write raw
//          score to the attn slice of d_out, track per-head max.
// Phase B: ev = exp(sc-m) (stored back), ssum, acc += ev * v[src] (bf16).
// Write agg row (bf16). Phase D: attn = ev * rinv in place.
__global__ __launch_bounds__(256) void node_attn_kernel(
    const unsigned short* __restrict__ qb, const unsigned short* __restrict__ kb,
    const unsigned short* __restrict__ vb, const float* __restrict__ secb,
    const int* __restrict__ eidx, const int* __restrict__ rowstart,
    const int* __restrict__ src, float* __restrict__ scores,
    unsigned short* __restrict__ aggb) {
    int node = blockIdx.x * 4 + (threadIdx.x >> 6);
    if (node >= N_NODES) return;
    const int lane = threadIdx.x & 63;
    const int start = rowstart[node];
    const int deg = rowstart[node + 1] - start;
    if (deg == 0) {
        ((unsigned*)(aggb + (size_t)node * DIM))[lane] = 0u;
        return;
    }
    const int h = lane & 7;     // head (phases A/B/D)
    const int le = lane >> 3;   // edge slot 0..7
    const int hc = lane >> 3;   // head (aggregation mapping)

    float qv[16];
    {
        const bf16x8* qp = (const bf16x8*)(qb + (size_t)node * DIM + h * DHEAD);
        bf16x8 q0 = qp[0], q1 = qp[1];
#pragma unroll
        for (int i = 0; i < 8; ++i) {
            qv[i] = bf2f((unsigned short)q0[i]);
            qv[8 + i] = bf2f((unsigned short)q1[i]);
        }
    }

    // Phase A
    float m = -INFINITY;
    for (int j = 0; j < deg; j += 8) {
        int jj = j + le;
        float sc = -INFINITY;
        if (jj < deg) {
            int e = eidx[start + jj];
            int s = src[e];
            const bf16x8* kp = (const bf16x8*)(kb + (size_t)s * DIM + h * DHEAD);
            bf16x8 k0 = kp[0], k1 = kp[1];
            float acc = 0.f;
#pragma unroll
            for (int i = 0; i < 8; ++i) {
                acc = fmaf(qv[i], bf2f((unsigned short)k0[i]), acc);
                acc = fmaf(qv[8 + i], bf2f((unsigned short)k1[i]), acc);
            }
            sc = acc * 0.25f + secb[s * NHEAD + h];
            scores[(size_t)e * NHEAD + h] = sc;
        }
        m = fmaxf(m, sc);
    }
    m = fmaxf(m, __shfl_xor(m, 8));
    m = fmaxf(m, __shfl_xor(m, 16));
    m = fmaxf(m, __shfl_xor(m, 32));

    // Phase B
    float ssum = 0.f;
    float2 acc2 = {0.f, 0.f};
    for (int j = 0; j < deg; j += 8) {
        int jj = j + le;
        float ev = 0.f;
        if (jj < deg) {
            int e = eidx[start + jj];
            ev = __expf(scores[(size_t)e * NHEAD + h] - m);
            scores[(size_t)e * NHEAD + h] = ev;
        }
        ssum += ev;
        int lim = deg - j; if (lim > 8) lim = 8;
        for (int le2 = 0; le2 < lim; ++le2) {
            float evd = __shfl(ev, le2 * 8 + hc);
            int e = eidx[start + j + le2];          // wave-uniform
            int s = src[e];
            unsigned vv = ((const unsigned*)(vb + (size_t)s * DIM))[lane];
            acc2.x = fmaf(evd, bf2f((unsigned short)(vv & 0xFFFFu)), acc2.x);
            acc2.y = fmaf(evd, bf2f((unsigned short)(vv >> 16)), acc2.y);
        }
    }
    ssum += __shfl_xor(ssum, 8);
    ssum += __shfl_xor(ssum, 16);
    ssum += __shfl_xor(ssum, 32);
    const float rinv = 1.f / (ssum + 1e-9f);       // head (lane&7)
    const float rinv_c = __shfl(rinv, hc);         // head (lane>>3)

    {
        unsigned short o0 = f2bf(acc2.x * rinv_c);
        unsigned short o1 = f2bf(acc2.y * rinv_c);
        ((unsigned*)(aggb + (size_t)node * DIM))[lane] =
            (unsigned)o0 | ((unsigned)o1 << 16);
    }

    // Phase D
    for (int j = 0; j < deg; j += 8) {
        int jj = j + le;
        if (jj < deg) {
            int e = eidx[start + jj];
            scores[(size_t)e * NHEAD + h] *= rinv;
        }
    }
}

// ---------- fused residual-add + LayerNorm (wave per row) ----------
template <int OUT_BF16>
__global__ __launch_bounds__(256) void ln_add_kernel(
    const unsigned short* __restrict__ Ab, const float* __restrict__ B,
    const float* __restrict__ g, const float* __restrict__ be,
    void* __restrict__ out) {
    int row = blockIdx.x * 4 + (threadIdx.x >> 6);
    int lane = threadIdx.x & 63;
    if (row >= N_NODES) return;
    unsigned av = ((const unsigned*)Ab)[(size_t)row * 64 + lane];
    float2 bv = ((const float2*)B)[(size_t)row * 64 + lane];
    float x0 = bf2f((unsigned short)(av & 0xFFFFu)) + bv.x;
    float x1 = bf2f((unsigned short)(av >> 16)) + bv.y;
    float s = x0 + x1;
#pragma unroll
    for (int m = 32; m; m >>= 1) s += __shfl_xor(s, m);
    float mean = s * (1.f / 128.f);
    float d0 = x0 - mean, d1 = x1 - mean;
    float vs = d0 * d0 + d1 * d1;
#pragma unroll
    for (int m = 32; m; m >>= 1) vs += __shfl_xor(vs, m);
    float r = rsqrtf(vs * (1.f / 128.f) + 1e-5f);
    float2 gv = ((const float2*)g)[lane];
    float2 bev = ((const float2*)be)[lane];
    float o0 = d0 * r * gv.x + bev.x;
    float o1 = d1 * r * gv.y + bev.y;
    if (OUT_BF16) {
        ((unsigned*)out)[(size_t)row * 64 + lane] =
            (unsigned)f2bf(o0) | ((unsigned)f2bf(o1) << 16);
    } else {
        float2 o; o.x = o0; o.y = o1;
        ((float2*)out)[(size_t)row * 64 + lane] = o;
    }
}

extern "C" void kernel_launch(void* const* d_in, const int* in_sizes, int n_in,
                              void* d_out, int out_size, void* d_ws, size_t ws_size,
                              hipStream_t stream) {
    const float* x    = (const float*)d_in[0];
    const int*   ei   = (const int*)d_in[1];
    const float* sec  = (const float*)d_in[2];
    const float* W1   = (const float*)d_in[3];
    const float* b1   = (const float*)d_in[4];
    const float* W2   = (const float*)d_in[5];
    const float* b2   = (const float*)d_in[6];
    const float* Wq   = (const float*)d_in[7];
    const float* bq   = (const float*)d_in[8];
    const float* Wk   = (const float*)d_in[9];
    const float* bk   = (const float*)d_in[10];
    const float* Wv   = (const float*)d_in[11];
    const float* bvp  = (const float*)d_in[12];
    const float* Wsec = (const float*)d_in[13];
    const float* bsec = (const float*)d_in[14];
    const float* Wo   = (const float*)d_in[15];
    const float* bo   = (const float*)d_in[16];
    const float* g1   = (const float*)d_in[17];
    const float* be1  = (const float*)d_in[18];
    const float* g2   = (const float*)d_in[19];
    const float* be2  = (const float*)d_in[20];

    const int* srcp = ei;             // edge_index[0]
    const int* dstp = ei + N_EDGES;   // edge_index[1]

    char* wsb = (char*)d_ws;
    unsigned short* xb   = (unsigned short*)(wsb);              // 12.8MB
    unsigned short* hb   = (unsigned short*)(wsb + 12800000);   // 12.8MB
    unsigned short* qbu  = (unsigned short*)(wsb + 25600000);   // 12.8MB
    unsigned short* kbu  = (unsigned short*)(wsb + 38400000);   // 12.8MB
    unsigned short* vbu  = (unsigned short*)(wsb + 51200000);   // 12.8MB
    unsigned short* aggb = (unsigned short*)(wsb + 64000000);   // 12.8MB
    float* att           = (float*)(wsb + 76800000);            // 25.6MB
    unsigned short* midb = (unsigned short*)(wsb + 102400000);  // 12.8MB
    float* relu2         = (float*)(wsb);        // overlays xb+hb (both dead)
    float* secb          = (float*)(wsb + 115200000);           // 1.6MB
    unsigned short* Wt   = (unsigned short*)(wsb + 116800000);  // 192KB
    int* deg             = (int*)(wsb + 117200000);
    int* ctr             = (int*)(wsb + 117400000);
    int* rowstart        = (int*)(wsb + 117600000);
    int* eidxb           = (int*)(wsb + 117800192);             // 3.2MB

    float* outp = (float*)d_out;                 // [N,128]
    float* attn = outp + (size_t)N_NODES * DIM;  // [E,8]

    dim3 blk(256);
    const int gemm_grid = (N_NODES + 63) / 64;
    const int egrid = (N_EDGES + 255) / 256;
    const int ngrid = (N_NODES + 255) / 256;
    const int wgrid = (N_NODES + 3) / 4;

    prep_w_kernel<<<6, blk, 0, stream>>>(W1, Wq, Wk, Wv, Wo, W2, Wt);
    x2bf_kernel<<<(N_NODES * DIM / 4 + 255) / 256, blk, 0, stream>>>(x, xb);

    zero_int2_kernel<<<ngrid, blk, 0, stream>>>(deg, ctr);
    count_deg_kernel<<<egrid, blk, 0, stream>>>(dstp, deg);
    scan_kernel<<<1, blk, 0, stream>>>(deg, rowstart);
    fill_csr_kernel<<<egrid, blk, 0, stream>>>(dstp, rowstart, ctr, eidxb);
    secbias_kernel<<<(N_NODES * NHEAD + 255) / 256, blk, 0, stream>>>(sec, Wsec, bsec, secb);

    gemm_mfma_kernel<1, 1><<<gemm_grid, blk, 0, stream>>>(xb, Wt,          b1,  hb,   N_NODES);
    gemm_mfma_kernel<0, 1><<<gemm_grid, blk, 0, stream>>>(hb, Wt + 16384,  bq,  qbu,  N_NODES);
    gemm_mfma_kernel<0, 1><<<gemm_grid, blk, 0, stream>>>(hb, Wt + 32768,  bk,  kbu,  N_NODES);
    gemm_mfma_kernel<0, 1><<<gemm_grid, blk, 0, stream>>>(hb, Wt + 49152,  bvp, vbu,  N_NODES);

    node_attn_kernel<<<wgrid, blk, 0, stream>>>(qbu, kbu, vbu, secb, eidxb, rowstart,
                                                srcp, attn, aggb);

    gemm_mfma_kernel<0, 0><<<gemm_grid, blk, 0, stream>>>(aggb, Wt + 65536, bo, att,   N_NODES);
    ln_add_kernel<1><<<wgrid, blk, 0, stream>>>(hb, att, g1, be1, midb);
    gemm_mfma_kernel<1, 0><<<gemm_grid, blk, 0, stream>>>(midb, Wt + 81920, b2, relu2, N_NODES);
    ln_add_kernel<0><<<wgrid, blk, 0, stream>>>(midb, relu2, g2, be2, outp);
}

// Round 5
// 334.091 us; speedup vs baseline: 18.4482x; 1.4567x over previous
//
#include <hip/hip_runtime.h>
#include <hip/hip_bf16.h>
#include <math.h>

#define N_NODES 50000
#define N_EDGES 800000
#define DIM 128
#define NHEAD 8
#define DHEAD 16
#define SDIM 10

typedef __attribute__((ext_vector_type(8))) short bf16x8;
typedef __attribute__((ext_vector_type(4))) float f32x4;

__device__ __forceinline__ float bf2f(unsigned short u) {
    return __uint_as_float(((unsigned)u) << 16);
}
__device__ __forceinline__ unsigned short f2bf(float f) {
    unsigned u = __float_as_uint(f);
    return (unsigned short)((u + 0x7FFFu + ((u >> 16) & 1u)) >> 16);
}

// ===== setup: prep Wt (6 transposed bf16 weights) + zero deg/ctr + secbias ==
__global__ __launch_bounds__(256) void setup_kernel(
    const float* __restrict__ W1, const float* __restrict__ Wq,
    const float* __restrict__ Wk, const float* __restrict__ Wv,
    const float* __restrict__ Wo, const float* __restrict__ W2,
    unsigned short* __restrict__ Wt, int* __restrict__ deg, int* __restrict__ ctr,
    const float* __restrict__ sec, const float* __restrict__ Wsec,
    const float* __restrict__ bsec, float* __restrict__ secb) {
    const int b = blockIdx.x, t = threadIdx.x;
    if (b < 6) {
        const float* W = (b == 0) ? W1 : (b == 1) ? Wq : (b == 2) ? Wk :
                         (b == 3) ? Wv : (b == 4) ? Wo : W2;
        unsigned short* o = Wt + b * 16384;
        for (int i = 0; i < 64; ++i) {
            int idx = t + 256 * i;          // k-major element index
            int k = idx >> 7, n = idx & 127;
            o[n * 128 + k] = f2bf(W[idx]);
        }
    } else if (b < 202) {                   // 196 blocks: zero deg+ctr
        int idx = (b - 6) * 256 + t;
        if (idx < N_NODES) { deg[idx] = 0; ctr[idx] = 0; }
    } else {                                // 1563 blocks: secbias
        int idx = (b - 202) * 256 + t;
        if (idx < N_NODES * NHEAD) {
            int n = idx >> 3, h = idx & 7;
            float acc = bsec[h];
#pragma unroll
            for (int j = 0; j < SDIM; ++j)
                acc = fmaf(sec[n * SDIM + j], Wsec[j * NHEAD + h], acc);
            secb[idx] = acc;
        }
    }
}

// ===== CSR build =====
__global__ __launch_bounds__(256) void count_deg_kernel(const int* __restrict__ dst,
                                                        int* __restrict__ deg) {
    int e = blockIdx.x * 256 + threadIdx.x;
    if (e < N_EDGES) atomicAdd(&deg[dst[e]], 1);
}

__global__ __launch_bounds__(256) void scan_kernel(const int* __restrict__ deg,
                                                   int* __restrict__ rowstart) {
    __shared__ int sums[256];
    const int t = threadIdx.x;
    const int CH = (N_NODES + 255) / 256;
    const int base = t * CH;
    int s = 0;
    for (int i = 0; i < CH; ++i) {
        int idx = base + i;
        if (idx < N_NODES) s += deg[idx];
    }
    sums[t] = s;
    __syncthreads();
    if (t == 0) {
        int run = 0;
        for (int i = 0; i < 256; ++i) { int tmp = sums[i]; sums[i] = run; run += tmp; }
        rowstart[N_NODES] = run;
    }
    __syncthreads();
    int run = sums[t];
    for (int i = 0; i < CH; ++i) {
        int idx = base + i;
        if (idx < N_NODES) { rowstart[idx] = run; run += deg[idx]; }
    }
}

__global__ __launch_bounds__(256) void fill_csr_kernel(
    const int* __restrict__ src, const int* __restrict__ dst,
    const int* __restrict__ rowstart, int* __restrict__ ctr,
    int* __restrict__ eidx, int* __restrict__ esrc) {
    int e = blockIdx.x * 256 + threadIdx.x;
    if (e >= N_EDGES) return;
    int d = dst[e];
    int pos = atomicAdd(&ctr[d], 1);
    int slot = rowstart[d] + pos;
    eidx[slot] = e;
    esrc[slot] = src[e];
}

// ===== GEMM1: hb = relu(x(f32) @ W1 + b1) -> bf16 =====
__global__ __launch_bounds__(256) void gemm_x_kernel(
    const float* __restrict__ A, const unsigned short* __restrict__ Wt,
    const float* __restrict__ bias, unsigned short* __restrict__ C, int nrows) {
    __shared__ alignas(16) unsigned char Wl[32768];
    const int t = threadIdx.x;
#pragma unroll
    for (int i = 0; i < 8; ++i) {
        int c = t + 256 * i;
        int n = c >> 4, s = c & 15;
        bf16x8 val = *(const bf16x8*)(Wt + c * 8);
        *(bf16x8*)(Wl + n * 256 + ((s * 16) ^ ((n & 7) << 4))) = val;
    }
    const int l = t & 63, wave = t >> 6;
    const int l15 = l & 15, lg = l >> 4;
    const int r0 = blockIdx.x * 64 + wave * 16;
    const int arow = r0 + l15;
    const bool aok = arow < nrows;

    bf16x8 af[4];
#pragma unroll
    for (int k0 = 0; k0 < 4; ++k0) {
        float4 a0 = {0.f, 0.f, 0.f, 0.f}, a1 = {0.f, 0.f, 0.f, 0.f};
        if (aok) {
            const float4* ap = (const float4*)(A + (size_t)arow * DIM + k0 * 32 + lg * 8);
            a0 = ap[0]; a1 = ap[1];
        }
        bf16x8 f;
        f[0] = (short)f2bf(a0.x); f[1] = (short)f2bf(a0.y);
        f[2] = (short)f2bf(a0.z); f[3] = (short)f2bf(a0.w);
        f[4] = (short)f2bf(a1.x); f[5] = (short)f2bf(a1.y);
        f[6] = (short)f2bf(a1.z); f[7] = (short)f2bf(a1.w);
        af[k0] = f;
    }
    __syncthreads();

    f32x4 acc[8];
#pragma unroll
    for (int n = 0; n < 8; ++n) acc[n] = (f32x4){0.f, 0.f, 0.f, 0.f};
#pragma unroll
    for (int k0 = 0; k0 < 4; ++k0) {
#pragma unroll
        for (int n = 0; n < 8; ++n) {
            int row = n * 16 + l15;
            int kb = (k0 * 64 + lg * 16) ^ ((row & 7) << 4);
            bf16x8 bfr = *(bf16x8*)(Wl + row * 256 + kb);
            acc[n] = __builtin_amdgcn_mfma_f32_16x16x32_bf16(af[k0], bfr, acc[n], 0, 0, 0);
        }
    }
    const int orow0 = r0 + lg * 4;
#pragma unroll
    for (int n = 0; n < 8; ++n) {
        int col = n * 16 + l15;
        float bv = bias[col];
#pragma unroll
        for (int i = 0; i < 4; ++i) {
            int r = orow0 + i;
            if (r < nrows) C[(size_t)r * DIM + col] = f2bf(fmaxf(acc[n][i] + bv, 0.f));
        }
    }
}

// ===== GEMM q/k/v fused: A bf16 read once, Wq+Wk staged then Wv restaged ====
__global__ __launch_bounds__(512) void gemm_qkv_kernel(
    const unsigned short* __restrict__ A, const unsigned short* __restrict__ W3,
    const float* __restrict__ bq, const float* __restrict__ bk,
    const float* __restrict__ bv, unsigned short* __restrict__ qo,
    unsigned short* __restrict__ ko, unsigned short* __restrict__ vo, int nrows) {
    __shared__ alignas(16) unsigned char Wl[65536];
    const int t = threadIdx.x;
    const int l = t & 63, wave = t >> 6;
    const int l15 = l & 15, lg = l >> 4;
    const int r0 = blockIdx.x * 128 + wave * 16;
    const int arow = r0 + l15;
    const bool aok = arow < nrows;

    // stage Wq (slot 0) + Wk (slot 1)
#pragma unroll
    for (int i = 0; i < 8; ++i) {
        int c = t + 512 * i;                 // 4096 chunks
        int mtx = c >> 11, cc = c & 2047;
        int n = cc >> 4, s = cc & 15;
        bf16x8 val = *(const bf16x8*)(W3 + c * 8);
        *(bf16x8*)(Wl + mtx * 32768 + n * 256 + ((s * 16) ^ ((n & 7) << 4))) = val;
    }
    bf16x8 af[4];
#pragma unroll
    for (int k0 = 0; k0 < 4; ++k0) {
        bf16x8 z = (bf16x8){0, 0, 0, 0, 0, 0, 0, 0};
        af[k0] = aok ? *(const bf16x8*)(A + (size_t)arow * DIM + k0 * 32 + lg * 8) : z;
    }
    __syncthreads();

    const int orow0 = r0 + lg * 4;
#pragma unroll
    for (int m = 0; m < 2; ++m) {
        const float* bias = (m == 0) ? bq : bk;
        unsigned short* out = (m == 0) ? qo : ko;
        f32x4 acc[8];
#pragma unroll
        for (int n = 0; n < 8; ++n) acc[n] = (f32x4){0.f, 0.f, 0.f, 0.f};
#pragma unroll
        for (int k0 = 0; k0 < 4; ++k0) {
#pragma unroll
            for (int n = 0; n < 8; ++n) {
                int row = n * 16 + l15;
                int kb = (k0 * 64 + lg * 16) ^ ((row & 7) << 4);
                bf16x8 bfr = *(bf16x8*)(Wl + m * 32768 + row * 256 + kb);
                acc[n] = __builtin_amdgcn_mfma_f32_16x16x32_bf16(af[k0], bfr, acc[n], 0, 0, 0);
            }
        }
#pragma unroll
        for (int n = 0; n < 8; ++n) {
            int col = n * 16 + l15;
            float bvv = bias[col];
#pragma unroll
            for (int i = 0; i < 4; ++i) {
                int r = orow0 + i;
                if (r < nrows) out[(size_t)r * DIM + col] = f2bf(acc[n][i] + bvv);
            }
        }
    }
    // restage Wv into slot 0 (Wv is the 3rd matrix: W3 + 2*16384 = W3 + 32768)
    __syncthreads();
#pragma unroll
    for (int i = 0; i < 4; ++i) {
        int c = t + 512 * i;                 // 2048 chunks
        int n = c >> 4, s = c & 15;
        bf16x8 val = *(const bf16x8*)(W3 + 32768 + c * 8);
        *(bf16x8*)(Wl + n * 256 + ((s * 16) ^ ((n & 7) << 4))) = val;
    }
    __syncthreads();
    {
        f32x4 acc[8];
#pragma unroll
        for (int n = 0; n < 8; ++n) acc[n] = (f32x4){0.f, 0.f, 0.f, 0.f};
#pragma unroll
        for (int k0 = 0; k0 < 4; ++k0) {
#pragma unroll
            for (int n = 0; n < 8; ++n) {
                int row = n * 16 + l15;
                int kb = (k0 * 64 + lg * 16) ^ ((row & 7) << 4);
                bf16x8 bfr = *(bf16x8*)(Wl + row * 256 + kb);
                acc[n] = __builtin_amdgcn_mfma_f32_16x16x32_bf16(af[k0], bfr, acc[n], 0, 0, 0);
            }
        }
#pragma unroll
        for (int n = 0; n < 8; ++n) {
            int col = n * 16 + l15;
            float bvv = bv[col];
#pragma unroll
            for (int i = 0; i < 4; ++i) {
                int r = orow0 + i;
                if (r < nrows) vo[(size_t)r * DIM + col] = f2bf(acc[n][i] + bvv);
            }
        }
    }
}

// ===== fused scores + softmax + aggregation (wave per dst node) ============
// Fast path (deg<=64): scores/ev live entirely in registers; the attn slice
// of d_out is written exactly once (final normalized attn).
__global__ __launch_bounds__(256) void node_attn_kernel(
    const unsigned short* __restrict__ qb, const unsigned short* __restrict__ kb,
    const unsigned short* __restrict__ vb, const float* __restrict__ secb,
    const int* __restrict__ eidx, const int* __restrict__ esrc,
    const int* __restrict__ rowstart, float* __restrict__ attn_out,
    unsigned short* __restrict__ aggb) {
    int node = blockIdx.x * 4 + (threadIdx.x >> 6);
    if (node >= N_NODES) return;
    const int lane = threadIdx.x & 63;
    const int start = rowstart[node];
    const int deg = rowstart[node + 1] - start;
    if (deg == 0) {
        ((unsigned*)(aggb + (size_t)node * DIM))[lane] = 0u;
        return;
    }
    const int h = lane & 7;     // head (score phases)
    const int le = lane >> 3;   // edge slot 0..7
    const int hc = le;          // head (aggregation mapping)

    float qv[16];
    {
        const bf16x8* qp = (const bf16x8*)(qb + (size_t)node * DIM + h * DHEAD);
        bf16x8 q0 = qp[0], q1 = qp[1];
#pragma unroll
        for (int i = 0; i < 8; ++i) {
            qv[i] = bf2f((unsigned short)q0[i]);
            qv[8 + i] = bf2f((unsigned short)q1[i]);
        }
    }

    if (deg <= 64) {
        // ---------- fast path: register-resident scores ----------
        float sc[8];
        float m = -INFINITY;
#pragma unroll
        for (int t = 0; t < 8; ++t) {
            sc[t] = -INFINITY;
            if (t * 8 < deg) {                       // wave-uniform
                int jj = t * 8 + le;
                bool valid = jj < deg;
                int idx = start + (valid ? jj : deg - 1);
                int s = esrc[idx];
                const bf16x8* kp = (const bf16x8*)(kb + (size_t)s * DIM + h * DHEAD);
                bf16x8 k0 = kp[0], k1 = kp[1];
                float acc = 0.f;
#pragma unroll
                for (int i = 0; i < 8; ++i) {
                    acc = fmaf(qv[i], bf2f((unsigned short)k0[i]), acc);
                    acc = fmaf(qv[8 + i], bf2f((unsigned short)k1[i]), acc);
                }
                if (valid) sc[t] = acc * 0.25f + secb[s * NHEAD + h];
            }
            m = fmaxf(m, sc[t]);
        }
        m = fmaxf(m, __shfl_xor(m, 8));
        m = fmaxf(m, __shfl_xor(m, 16));
        m = fmaxf(m, __shfl_xor(m, 32));

        float ev[8];
        float ssum = 0.f;
#pragma unroll
        for (int t = 0; t < 8; ++t) {
            ev[t] = (t * 8 + le < deg) ? __expf(sc[t] - m) : 0.f;
            ssum += ev[t];
        }
        ssum += __shfl_xor(ssum, 8);
        ssum += __shfl_xor(ssum, 16);
        ssum += __shfl_xor(ssum, 32);
        const float rinv = 1.f / (ssum + 1e-9f);     // head (lane&7)

        float2 acc2 = {0.f, 0.f};
#pragma unroll
        for (int t = 0; t < 8; ++t) {
            if (t * 8 < deg) {                       // wave-uniform
#pragma unroll
                for (int le2 = 0; le2 < 8; ++le2) {
                    int jj = t * 8 + le2;            // uniform
                    int idx = start + (jj < deg ? jj : deg - 1);
                    int s = esrc[idx];               // uniform load
                    float evd = __shfl(ev[t], le2 * 8 + hc);
                    unsigned vv = ((const unsigned*)(vb + (size_t)s * DIM))[lane];
                    acc2.x = fmaf(evd, bf2f((unsigned short)(vv & 0xFFFFu)), acc2.x);
                    acc2.y = fmaf(evd, bf2f((unsigned short)(vv >> 16)), acc2.y);
                }
            }
        }
        const float rinv_c = __shfl(rinv, hc);       // head (lane>>3)
        unsigned short o0 = f2bf(acc2.x * rinv_c);
        unsigned short o1 = f2bf(acc2.y * rinv_c);
        ((unsigned*)(aggb + (size_t)node * DIM))[lane] =
            (unsigned)o0 | ((unsigned)o1 << 16);

#pragma unroll
        for (int t = 0; t < 8; ++t) {
            int jj = t * 8 + le;
            if (jj < deg) {
                int e = eidx[start + jj];
                attn_out[(size_t)e * NHEAD + h] = ev[t] * rinv;
            }
        }
        return;
    }

    // ---------- slow path (deg > 64): memory-staged, always correct ----------
    float m = -INFINITY;
    for (int j = 0; j < deg; j += 8) {
        int jj = j + le;
        float sc = -INFINITY;
        if (jj < deg) {
            int idx = start + jj;
            int s = esrc[idx];
            const bf16x8* kp = (const bf16x8*)(kb + (size_t)s * DIM + h * DHEAD);
            bf16x8 k0 = kp[0], k1 = kp[1];
            float acc = 0.f;
#pragma unroll
            for (int i = 0; i < 8; ++i) {
                acc = fmaf(qv[i], bf2f((unsigned short)k0[i]), acc);
                acc = fmaf(qv[8 + i], bf2f((unsigned short)k1[i]), acc);
            }
            sc = acc * 0.25f + secb[s * NHEAD + h];
            int e = eidx[idx];
            attn_out[(size_t)e * NHEAD + h] = sc;
        }
        m = fmaxf(m, sc);
    }
    m = fmaxf(m, __shfl_xor(m, 8));
    m = fmaxf(m, __shfl_xor(m, 16));
    m = fmaxf(m, __shfl_xor(m, 32));

    float ssum = 0.f;
    float2 acc2 = {0.f, 0.f};
    for (int j = 0; j < deg; j += 8) {
        int jj = j + le;
        float ev = 0.f;
        if (jj < deg) {
            int e = eidx[start + jj];
            ev = __expf(attn_out[(size_t)e * NHEAD + h] - m);
        }
        ssum += ev;
        int lim = deg - j; if (lim > 8) lim = 8;
        for (int le2 = 0; le2 < lim; ++le2) {
            float evd = __shfl(ev, le2 * 8 + hc);
            int s = esrc[start + j + le2];
            unsigned vv = ((const unsigned*)(vb + (size_t)s * DIM))[lane];
            acc2.x = fmaf(evd, bf2f((unsigned short)(vv & 0xFFFFu)), acc2.x);
            acc2.y = fmaf(evd, bf2f((unsigned short)(vv >> 16)), acc2.y);
        }
    }
    ssum += __shfl_xor(ssum, 8);
    ssum += __shfl_xor(ssum, 16);
    ssum += __shfl_xor(ssum, 32);
    const float rinv = 1.f / (ssum + 1e-9f);
    const float rinv_c = __shfl(rinv, hc);

    unsigned short o0 = f2bf(acc2.x * rinv_c);
    unsigned short o1 = f2bf(acc2.y * rinv_c);
    ((unsigned*)(aggb + (size_t)node * DIM))[lane] =
        (unsigned)o0 | ((unsigned)o1 << 16);

    for (int j = 0; j < deg; j += 8) {
        int jj = j + le;
        if (jj < deg) {
            int e = eidx[start + jj];
            float sc = attn_out[(size_t)e * NHEAD + h];
            attn_out[(size_t)e * NHEAD + h] = __expf(sc - m) * rinv;
        }
    }
}

// ===== GEMM + residual-add + LayerNorm fused =====
// out = LN( resid + [relu?](A @ W + bias) ) ; wave owns 16 complete rows.
template <int RELU, int OUT_BF16>
__global__ __launch_bounds__(256) void gemm_ln_kernel(
    const unsigned short* __restrict__ A, const unsigned short* __restrict__ Wt,
    const float* __restrict__ bias, const unsigned short* __restrict__ resid,
    const float* __restrict__ g, const float* __restrict__ be,
    void* __restrict__ out, int nrows) {
    __shared__ alignas(16) unsigned char Wl[32768];
    const int t = threadIdx.x;
#pragma unroll
    for (int i = 0; i < 8; ++i) {
        int c = t + 256 * i;
        int n = c >> 4, s = c & 15;
        bf16x8 val = *(const bf16x8*)(Wt + c * 8);
        *(bf16x8*)(Wl + n * 256 + ((s * 16) ^ ((n & 7) << 4))) = val;
    }
    const int l = t & 63, wave = t >> 6;
    const int l15 = l & 15, lg = l >> 4;
    const int r0 = blockIdx.x * 64 + wave * 16;
    const int arow = r0 + l15;
    const bool aok = arow < nrows;

    bf16x8 af[4];
#pragma unroll
    for (int k0 = 0; k0 < 4; ++k0) {
        bf16x8 z = (bf16x8){0, 0, 0, 0, 0, 0, 0, 0};
        af[k0] = aok ? *(const bf16x8*)(A + (size_t)arow * DIM + k0 * 32 + lg * 8) : z;
    }
    __syncthreads();

    f32x4 acc[8];
#pragma unroll
    for (int n = 0; n < 8; ++n) acc[n] = (f32x4){0.f, 0.f, 0.f, 0.f};
#pragma unroll
    for (int k0 = 0; k0 < 4; ++k0) {
#pragma unroll
        for (int n = 0; n < 8; ++n) {
            int row = n * 16 + l15;
            int kb = (k0 * 64 + lg * 16) ^ ((row & 7) << 4);
            bf16x8 bfr = *(bf16x8*)(Wl + row * 256 + kb);
            acc[n] = __builtin_amdgcn_mfma_f32_16x16x32_bf16(af[k0], bfr, acc[n], 0, 0, 0);
        }
    }

    float bv[8], gv[8], bev[8];
#pragma unroll
    for (int n = 0; n < 8; ++n) {
        int col = n * 16 + l15;
        bv[n] = bias[col]; gv[n] = g[col]; bev[n] = be[col];
    }
    // NOTE: nrows % 16 == 0 here, so row-validity is wave-uniform (shfl-safe).
#pragma unroll
    for (int i = 0; i < 4; ++i) {
        int r = r0 + lg * 4 + i;
        if (r >= nrows) continue;
        float xv[8];
        float s = 0.f;
#pragma unroll
        for (int n = 0; n < 8; ++n) {
            float val = acc[n][i] + bv[n];
            if (RELU) val = fmaxf(val, 0.f);
            val += bf2f(resid[(size_t)r * DIM + n * 16 + l15]);
            xv[n] = val;
            s += val;
        }
        s += __shfl_xor(s, 1); s += __shfl_xor(s, 2);
        s += __shfl_xor(s, 4); s += __shfl_xor(s, 8);
        float mean = s * (1.f / 128.f);
        float var = 0.f;
#pragma unroll
        for (int n = 0; n < 8; ++n) {
            float d = xv[n] - mean;
            var += d * d;
        }
        var += __shfl_xor(var, 1); var += __shfl_xor(var, 2);
        var += __shfl_xor(var, 4); var += __shfl_xor(var, 8);
        float rstd = rsqrtf(var * (1.f / 128.f) + 1e-5f);
#pragma unroll
        for (int n = 0; n < 8; ++n) {
            float o = (xv[n] - mean) * rstd * gv[n] + bev[n];
            int col = n * 16 + l15;
            if (OUT_BF16) ((unsigned short*)out)[(size_t)r * DIM + col] = f2bf(o);
            else          ((float*)out)[(size_t)r * DIM + col] = o;
        }
    }
}

extern "C" void kernel_launch(void* const* d_in, const int* in_sizes, int n_in,
                              void* d_out, int out_size, void* d_ws, size_t ws_size,
                              hipStream_t stream) {
    const float* x    = (const float*)d_in[0];
    const int*   ei   = (const int*)d_in[1];
    const float* sec  = (const float*)d_in[2];
    const float* W1   = (const float*)d_in[3];
    const float* b1   = (const float*)d_in[4];
    const float* W2   = (const float*)d_in[5];
    const float* b2   = (const float*)d_in[6];
    const float* Wq   = (const float*)d_in[7];
    const float* bq   = (const float*)d_in[8];
    const float* Wk   = (const float*)d_in[9];
    const float* bk   = (const float*)d_in[10];
    const float* Wv   = (const float*)d_in[11];
    const float* bvp  = (const float*)d_in[12];
    const float* Wsec = (const float*)d_in[13];
    const float* bsec = (const float*)d_in[14];
    const float* Wo   = (const float*)d_in[15];
    const float* bo   = (const float*)d_in[16];
    const float* g1   = (const float*)d_in[17];
    const float* be1  = (const float*)d_in[18];
    const float* g2   = (const float*)d_in[19];
    const float* be2  = (const float*)d_in[20];

    const int* srcp = ei;             // edge_index[0]
    const int* dstp = ei + N_EDGES;   // edge_index[1]

    char* wsb = (char*)d_ws;
    unsigned short* hb   = (unsigned short*)(wsb);              // 12.8MB
    unsigned short* qbu  = (unsigned short*)(wsb + 12800000);
    unsigned short* kbu  = (unsigned short*)(wsb + 25600000);
    unsigned short* vbu  = (unsigned short*)(wsb + 38400000);
    unsigned short* aggb = (unsigned short*)(wsb + 51200000);
    unsigned short* midb = (unsigned short*)(wsb + 64000000);
    float* secb          = (float*)(wsb + 76800000);            // 1.6MB
    unsigned short* Wt   = (unsigned short*)(wsb + 78400000);   // 192KB
    int* deg             = (int*)(wsb + 78600000);              // 200KB
    int* ctr             = (int*)(wsb + 78800000);              // 200KB
    int* rowstart        = (int*)(wsb + 79000000);              // 200KB+4
    int* eidxb           = (int*)(wsb + 79200256);              // 3.2MB
    int* esrcb           = (int*)(wsb + 82400256);              // 3.2MB

    float* outp = (float*)d_out;                 // [N,128]
    float* attn = outp + (size_t)N_NODES * DIM;  // [E,8]

    dim3 blk(256);
    const int gemm_grid = (N_NODES + 63) / 64;       // 782
    const int qkv_grid  = (N_NODES + 127) / 128;     // 391
    const int egrid = (N_EDGES + 255) / 256;         // 3125
    const int wgrid = (N_NODES + 3) / 4;             // 12500

    setup_kernel<<<6 + 196 + 1563, blk, 0, stream>>>(W1, Wq, Wk, Wv, Wo, W2, Wt,
                                                     deg, ctr, sec, Wsec, bsec, secb);
    count_deg_kernel<<<egrid, blk, 0, stream>>>(dstp, deg);
    scan_kernel<<<1, blk, 0, stream>>>(deg, rowstart);
    fill_csr_kernel<<<egrid, blk, 0, stream>>>(srcp, dstp, rowstart, ctr, eidxb, esrcb);

    gemm_x_kernel<<<gemm_grid, blk, 0, stream>>>(x, Wt, b1, hb, N_NODES);
    gemm_qkv_kernel<<<qkv_grid, dim3(512), 0, stream>>>(hb, Wt + 16384, bq, bk, bvp,
                                                        qbu, kbu, vbu, N_NODES);

    node_attn_kernel<<<wgrid, blk, 0, stream>>>(qbu, kbu, vbu, secb, eidxb, esrcb,
                                                rowstart, attn, aggb);

    gemm_ln_kernel<0, 1><<<gemm_grid, blk, 0, stream>>>(aggb, Wt + 65536, bo, hb,
                                                        g1, be1, midb, N_NODES);
    gemm_ln_kernel<1, 0><<<gemm_grid, blk, 0, stream>>>(midb, Wt + 81920, b2, midb,
                                                        g2, be2, outp, N_NODES);
}

// Round 6
// 254.587 us; speedup vs baseline: 24.2092x; 1.3123x over previous
//
#include <hip/hip_runtime.h>
#include <hip/hip_bf16.h>
#include <math.h>

#define N_NODES 50000
#define N_EDGES 800000
#define DIM 128
#define NHEAD 8
#define DHEAD 16
#define SDIM 10
#define NSCAN_BLK 196   // ceil(N_NODES/256)

typedef __attribute__((ext_vector_type(8))) short bf16x8;
typedef __attribute__((ext_vector_type(4))) float f32x4;

__device__ __forceinline__ float bf2f(unsigned short u) {
    return __uint_as_float(((unsigned)u) << 16);
}
__device__ __forceinline__ unsigned short f2bf(float f) {
    unsigned u = __float_as_uint(f);
    return (unsigned short)((u + 0x7FFFu + ((u >> 16) & 1u)) >> 16);
}

// ===== setup: prep Wt (6 transposed bf16 weights) + zero deg/ctr + secbias ==
__global__ __launch_bounds__(256) void setup_kernel(
    const float* __restrict__ W1, const float* __restrict__ Wq,
    const float* __restrict__ Wk, const float* __restrict__ Wv,
    const float* __restrict__ Wo, const float* __restrict__ W2,
    unsigned short* __restrict__ Wt, int* __restrict__ deg, int* __restrict__ ctr,
    const float* __restrict__ sec, const float* __restrict__ Wsec,
    const float* __restrict__ bsec, float* __restrict__ secb) {
    const int b = blockIdx.x, t = threadIdx.x;
    if (b < 6) {
        const float* W = (b == 0) ? W1 : (b == 1) ? Wq : (b == 2) ? Wk :
                         (b == 3) ? Wv : (b == 4) ? Wo : W2;
        unsigned short* o = Wt + b * 16384;
        for (int i = 0; i < 64; ++i) {
            int idx = t + 256 * i;          // k-major element index
            int k = idx >> 7, n = idx & 127;
            o[n * 128 + k] = f2bf(W[idx]);
        }
    } else if (b < 202) {                   // 196 blocks: zero deg+ctr
        int idx = (b - 6) * 256 + t;
        if (idx < N_NODES) { deg[idx] = 0; ctr[idx] = 0; }
    } else {                                // 1563 blocks: secbias
        int idx = (b - 202) * 256 + t;
        if (idx < N_NODES * NHEAD) {
            int n = idx >> 3, h = idx & 7;
            float acc = bsec[h];
#pragma unroll
            for (int j = 0; j < SDIM; ++j)
                acc = fmaf(sec[n * SDIM + j], Wsec[j * NHEAD + h], acc);
            secb[idx] = acc;
        }
    }
}

// ===== CSR build =====
__global__ __launch_bounds__(256) void count_deg_kernel(const int* __restrict__ dst,
                                                        int* __restrict__ deg) {
    int e = blockIdx.x * 256 + threadIdx.x;
    if (e < N_EDGES) atomicAdd(&deg[dst[e]], 1);
}

// --- hierarchical scan: per-block reduce -> scan block sums -> per-block scan
__global__ __launch_bounds__(256) void blocksum_kernel(const int* __restrict__ deg,
                                                       int* __restrict__ bsum) {
    const int t = threadIdx.x;
    int idx = blockIdx.x * 256 + t;
    int v = (idx < N_NODES) ? deg[idx] : 0;
#pragma unroll
    for (int m = 32; m; m >>= 1) v += __shfl_xor(v, m);
    __shared__ int ws[4];
    if ((t & 63) == 0) ws[t >> 6] = v;
    __syncthreads();
    if (t == 0) bsum[blockIdx.x] = ws[0] + ws[1] + ws[2] + ws[3];
}

__global__ __launch_bounds__(256) void scanb_kernel(const int* __restrict__ bsum,
                                                    int* __restrict__ bexc,
                                                    int* __restrict__ rowstart) {
    const int t = threadIdx.x;
    __shared__ int s[256];
    int v = (t < NSCAN_BLK) ? bsum[t] : 0;
    s[t] = v;
    __syncthreads();
#pragma unroll
    for (int off = 1; off < 256; off <<= 1) {
        int x = (t >= off) ? s[t - off] : 0;
        __syncthreads();
        s[t] += x;
        __syncthreads();
    }
    if (t < NSCAN_BLK) bexc[t] = s[t] - v;          // exclusive block offset
    if (t == 255) rowstart[N_NODES] = s[255];       // grand total (== N_EDGES)
}

__global__ __launch_bounds__(256) void scanfin_kernel(const int* __restrict__ deg,
                                                      const int* __restrict__ bexc,
                                                      int* __restrict__ rowstart) {
    const int t = threadIdx.x;
    int idx = blockIdx.x * 256 + t;
    int v = (idx < N_NODES) ? deg[idx] : 0;
    __shared__ int s[256];
    s[t] = v;
    __syncthreads();
#pragma unroll
    for (int off = 1; off < 256; off <<= 1) {
        int x = (t >= off) ? s[t - off] : 0;
        __syncthreads();
        s[t] += x;
        __syncthreads();
    }
    if (idx < N_NODES) rowstart[idx] = bexc[blockIdx.x] + s[t] - v;
}

__global__ __launch_bounds__(256) void fill_csr_kernel(
    const int* __restrict__ src, const int* __restrict__ dst,
    const int* __restrict__ rowstart, int* __restrict__ ctr,
    int* __restrict__ eidx, int* __restrict__ esrc) {
    int e = blockIdx.x * 256 + threadIdx.x;
    if (e >= N_EDGES) return;
    int d = dst[e];
    int pos = atomicAdd(&ctr[d], 1);
    int slot = rowstart[d] + pos;
    eidx[slot] = e;
    esrc[slot] = src[e];
}

// ===== GEMM1: hb = relu(x(f32) @ W1 + b1) -> bf16 =====
__global__ __launch_bounds__(256) void gemm_x_kernel(
    const float* __restrict__ A, const unsigned short* __restrict__ Wt,
    const float* __restrict__ bias, unsigned short* __restrict__ C, int nrows) {
    __shared__ alignas(16) unsigned char Wl[32768];
    const int t = threadIdx.x;
#pragma unroll
    for (int i = 0; i < 8; ++i) {
        int c = t + 256 * i;
        int n = c >> 4, s = c & 15;
        bf16x8 val = *(const bf16x8*)(Wt + c * 8);
        *(bf16x8*)(Wl + n * 256 + ((s * 16) ^ ((n & 7) << 4))) = val;
    }
    const int l = t & 63, wave = t >> 6;
    const int l15 = l & 15, lg = l >> 4;
    const int r0 = blockIdx.x * 64 + wave * 16;
    const int arow = r0 + l15;
    const bool aok = arow < nrows;

    bf16x8 af[4];
#pragma unroll
    for (int k0 = 0; k0 < 4; ++k0) {
        float4 a0 = {0.f, 0.f, 0.f, 0.f}, a1 = {0.f, 0.f, 0.f, 0.f};
        if (aok) {
            const float4* ap = (const float4*)(A + (size_t)arow * DIM + k0 * 32 + lg * 8);
            a0 = ap[0]; a1 = ap[1];
        }
        bf16x8 f;
        f[0] = (short)f2bf(a0.x); f[1] = (short)f2bf(a0.y);
        f[2] = (short)f2bf(a0.z); f[3] = (short)f2bf(a0.w);
        f[4] = (short)f2bf(a1.x); f[5] = (short)f2bf(a1.y);
        f[6] = (short)f2bf(a1.z); f[7] = (short)f2bf(a1.w);
        af[k0] = f;
    }
    __syncthreads();

    f32x4 acc[8];
#pragma unroll
    for (int n = 0; n < 8; ++n) acc[n] = (f32x4){0.f, 0.f, 0.f, 0.f};
#pragma unroll
    for (int k0 = 0; k0 < 4; ++k0) {
#pragma unroll
        for (int n = 0; n < 8; ++n) {
            int row = n * 16 + l15;
            int kb = (k0 * 64 + lg * 16) ^ ((row & 7) << 4);
            bf16x8 bfr = *(bf16x8*)(Wl + row * 256 + kb);
            acc[n] = __builtin_amdgcn_mfma_f32_16x16x32_bf16(af[k0], bfr, acc[n], 0, 0, 0);
        }
    }
    const int orow0 = r0 + lg * 4;
#pragma unroll
    for (int n = 0; n < 8; ++n) {
        int col = n * 16 + l15;
        float bv = bias[col];
#pragma unroll
        for (int i = 0; i < 4; ++i) {
            int r = orow0 + i;
            if (r < nrows) C[(size_t)r * DIM + col] = f2bf(fmaxf(acc[n][i] + bv, 0.f));
        }
    }
}

// ===== GEMM q/k/v fused: A bf16 read once, Wq+Wk staged then Wv restaged ====
__global__ __launch_bounds__(512) void gemm_qkv_kernel(
    const unsigned short* __restrict__ A, const unsigned short* __restrict__ W3,
    const float* __restrict__ bq, const float* __restrict__ bk,
    const float* __restrict__ bv, unsigned short* __restrict__ qo,
    unsigned short* __restrict__ ko, unsigned short* __restrict__ vo, int nrows) {
    __shared__ alignas(16) unsigned char Wl[65536];
    const int t = threadIdx.x;
    const int l = t & 63, wave = t >> 6;
    const int l15 = l & 15, lg = l >> 4;
    const int r0 = blockIdx.x * 128 + wave * 16;
    const int arow = r0 + l15;
    const bool aok = arow < nrows;

    // stage Wq (slot 0) + Wk (slot 1)
#pragma unroll
    for (int i = 0; i < 8; ++i) {
        int c = t + 512 * i;                 // 4096 chunks
        int mtx = c >> 11, cc = c & 2047;
        int n = cc >> 4, s = cc & 15;
        bf16x8 val = *(const bf16x8*)(W3 + c * 8);
        *(bf16x8*)(Wl + mtx * 32768 + n * 256 + ((s * 16) ^ ((n & 7) << 4))) = val;
    }
    bf16x8 af[4];
#pragma unroll
    for (int k0 = 0; k0 < 4; ++k0) {
        bf16x8 z = (bf16x8){0, 0, 0, 0, 0, 0, 0, 0};
        af[k0] = aok ? *(const bf16x8*)(A + (size_t)arow * DIM + k0 * 32 + lg * 8) : z;
    }
    __syncthreads();

    const int orow0 = r0 + lg * 4;
#pragma unroll
    for (int m = 0; m < 2; ++m) {
        const float* bias = (m == 0) ? bq : bk;
        unsigned short* out = (m == 0) ? qo : ko;
        f32x4 acc[8];
#pragma unroll
        for (int n = 0; n < 8; ++n) acc[n] = (f32x4){0.f, 0.f, 0.f, 0.f};
#pragma unroll
        for (int k0 = 0; k0 < 4; ++k0) {
#pragma unroll
            for (int n = 0; n < 8; ++n) {
                int row = n * 16 + l15;
                int kb = (k0 * 64 + lg * 16) ^ ((row & 7) << 4);
                bf16x8 bfr = *(bf16x8*)(Wl + m * 32768 + row * 256 + kb);
                acc[n] = __builtin_amdgcn_mfma_f32_16x16x32_bf16(af[k0], bfr, acc[n], 0, 0, 0);
            }
        }
#pragma unroll
        for (int n = 0; n < 8; ++n) {
            int col = n * 16 + l15;
            float bvv = bias[col];
#pragma unroll
            for (int i = 0; i < 4; ++i) {
                int r = orow0 + i;
                if (r < nrows) out[(size_t)r * DIM + col] = f2bf(acc[n][i] + bvv);
            }
        }
    }
    // restage Wv into slot 0 (Wv is the 3rd matrix: W3 + 2*16384 = W3 + 32768)
    __syncthreads();
#pragma unroll
    for (int i = 0; i < 4; ++i) {
        int c = t + 512 * i;                 // 2048 chunks
        int n = c >> 4, s = c & 15;
        bf16x8 val = *(const bf16x8*)(W3 + 32768 + c * 8);
        *(bf16x8*)(Wl + n * 256 + ((s * 16) ^ ((n & 7) << 4))) = val;
    }
    __syncthreads();
    {
        f32x4 acc[8];
#pragma unroll
        for (int n = 0; n < 8; ++n) acc[n] = (f32x4){0.f, 0.f, 0.f, 0.f};
#pragma unroll
        for (int k0 = 0; k0 < 4; ++k0) {
#pragma unroll
            for (int n = 0; n < 8; ++n) {
                int row = n * 16 + l15;
                int kb = (k0 * 64 + lg * 16) ^ ((row & 7) << 4);
                bf16x8 bfr = *(bf16x8*)(Wl + row * 256 + kb);
                acc[n] = __builtin_amdgcn_mfma_f32_16x16x32_bf16(af[k0], bfr, acc[n], 0, 0, 0);
            }
        }
#pragma unroll
        for (int n = 0; n < 8; ++n) {
            int col = n * 16 + l15;
            float bvv = bv[col];
#pragma unroll
            for (int i = 0; i < 4; ++i) {
                int r = orow0 + i;
                if (r < nrows) vo[(size_t)r * DIM + col] = f2bf(acc[n][i] + bvv);
            }
        }
    }
}

// ===== fused scores + softmax + aggregation (wave per dst node) ============
__global__ __launch_bounds__(256) void node_attn_kernel(
    const unsigned short* __restrict__ qb, const unsigned short* __restrict__ kb,
    const unsigned short* __restrict__ vb, const float* __restrict__ secb,
    const int* __restrict__ eidx, const int* __restrict__ esrc,
    const int* __restrict__ rowstart, float* __restrict__ attn_out,
    unsigned short* __restrict__ aggb) {
    int node = blockIdx.x * 4 + (threadIdx.x >> 6);
    if (node >= N_NODES) return;
    const int lane = threadIdx.x & 63;
    const int start = rowstart[node];
    const int deg = rowstart[node + 1] - start;
    if (deg == 0) {
        ((unsigned*)(aggb + (size_t)node * DIM))[lane] = 0u;
        return;
    }
    const int h = lane & 7;     // head (score phases)
    const int le = lane >> 3;   // edge slot 0..7
    const int hc = le;          // head (aggregation mapping)

    float qv[16];
    {
        const bf16x8* qp = (const bf16x8*)(qb + (size_t)node * DIM + h * DHEAD);
        bf16x8 q0 = qp[0], q1 = qp[1];
#pragma unroll
        for (int i = 0; i < 8; ++i) {
            qv[i] = bf2f((unsigned short)q0[i]);
            qv[8 + i] = bf2f((unsigned short)q1[i]);
        }
    }

    if (deg <= 64) {
        // ---------- fast path: register-resident scores ----------
        float sc[8];
        float m = -INFINITY;
#pragma unroll
        for (int t = 0; t < 8; ++t) {
            sc[t] = -INFINITY;
            if (t * 8 < deg) {                       // wave-uniform
                int jj = t * 8 + le;
                bool valid = jj < deg;
                int idx = start + (valid ? jj : deg - 1);
                int s = esrc[idx];
                const bf16x8* kp = (const bf16x8*)(kb + (size_t)s * DIM + h * DHEAD);
                bf16x8 k0 = kp[0], k1 = kp[1];
                float acc = 0.f;
#pragma unroll
                for (int i = 0; i < 8; ++i) {
                    acc = fmaf(qv[i], bf2f((unsigned short)k0[i]), acc);
                    acc = fmaf(qv[8 + i], bf2f((unsigned short)k1[i]), acc);
                }
                if (valid) sc[t] = acc * 0.25f + secb[s * NHEAD + h];
            }
            m = fmaxf(m, sc[t]);
        }
        m = fmaxf(m, __shfl_xor(m, 8));
        m = fmaxf(m, __shfl_xor(m, 16));
        m = fmaxf(m, __shfl_xor(m, 32));

        float ev[8];
        float ssum = 0.f;
#pragma unroll
        for (int t = 0; t < 8; ++t) {
            ev[t] = (t * 8 + le < deg) ? __expf(sc[t] - m) : 0.f;
            ssum += ev[t];
        }
        ssum += __shfl_xor(ssum, 8);
        ssum += __shfl_xor(ssum, 16);
        ssum += __shfl_xor(ssum, 32);
        const float rinv = 1.f / (ssum + 1e-9f);     // head (lane&7)

        float2 acc2 = {0.f, 0.f};
#pragma unroll
        for (int t = 0; t < 8; ++t) {
            if (t * 8 < deg) {                       // wave-uniform
#pragma unroll
                for (int le2 = 0; le2 < 8; ++le2) {
                    int jj = t * 8 + le2;            // uniform
                    int idx = start + (jj < deg ? jj : deg - 1);
                    int s = esrc[idx];               // uniform load
                    float evd = __shfl(ev[t], le2 * 8 + hc);
                    unsigned vv = ((const unsigned*)(vb + (size_t)s * DIM))[lane];
                    acc2.x = fmaf(evd, bf2f((unsigned short)(vv & 0xFFFFu)), acc2.x);
                    acc2.y = fmaf(evd, bf2f((unsigned short)(vv >> 16)), acc2.y);
                }
            }
        }
        const float rinv_c = __shfl(rinv, hc);       // head (lane>>3)
        unsigned short o0 = f2bf(acc2.x * rinv_c);
        unsigned short o1 = f2bf(acc2.y * rinv_c);
        ((unsigned*)(aggb + (size_t)node * DIM))[lane] =
            (unsigned)o0 | ((unsigned)o1 << 16);

#pragma unroll
        for (int t = 0; t < 8; ++t) {
            int jj = t * 8 + le;
            if (jj < deg) {
                int e = eidx[start + jj];
                attn_out[(size_t)e * NHEAD + h] = ev[t] * rinv;
            }
        }
        return;
    }

    // ---------- slow path (deg > 64): memory-staged, always correct ----------
    float m = -INFINITY;
    for (int j = 0; j < deg; j += 8) {
        int jj = j + le;
        float sc = -INFINITY;
        if (jj < deg) {
            int idx = start + jj;
            int s = esrc[idx];
            const bf16x8* kp = (const bf16x8*)(kb + (size_t)s * DIM + h * DHEAD);
            bf16x8 k0 = kp[0], k1 = kp[1];
            float acc = 0.f;
#pragma unroll
            for (int i = 0; i < 8; ++i) {
                acc = fmaf(qv[i], bf2f((unsigned short)k0[i]), acc);
                acc = fmaf(qv[8 + i], bf2f((unsigned short)k1[i]), acc);
            }
            sc = acc * 0.25f + secb[s * NHEAD + h];
            int e = eidx[idx];
            attn_out[(size_t)e * NHEAD + h] = sc;
        }
        m = fmaxf(m, sc);
    }
    m = fmaxf(m, __shfl_xor(m, 8));
    m = fmaxf(m, __shfl_xor(m, 16));
    m = fmaxf(m, __shfl_xor(m, 32));

    float ssum = 0.f;
    float2 acc2 = {0.f, 0.f};
    for (int j = 0; j < deg; j += 8) {
        int jj = j + le;
        float ev = 0.f;
        if (jj < deg) {
            int e = eidx[start + jj];
            ev = __expf(attn_out[(size_t)e * NHEAD + h] - m);
        }
        ssum += ev;
        int lim = deg - j; if (lim > 8) lim = 8;
        for (int le2 = 0; le2 < lim; ++le2) {
            float evd = __shfl(ev, le2 * 8 + hc);
            int s = esrc[start + j + le2];
            unsigned vv = ((const unsigned*)(vb + (size_t)s * DIM))[lane];
            acc2.x = fmaf(evd, bf2f((unsigned short)(vv & 0xFFFFu)), acc2.x);
            acc2.y = fmaf(evd, bf2f((unsigned short)(vv >> 16)), acc2.y);
        }
    }
    ssum += __shfl_xor(ssum, 8);
    ssum += __shfl_xor(ssum, 16);
    ssum += __shfl_xor(ssum, 32);
    const float rinv = 1.f / (ssum + 1e-9f);
    const float rinv_c = __shfl(rinv, hc);

    unsigned short o0 = f2bf(acc2.x * rinv_c);
    unsigned short o1 = f2bf(acc2.y * rinv_c);
    ((unsigned*)(aggb + (size_t)node * DIM))[lane] =
        (unsigned)o0 | ((unsigned)o1 << 16);

    for (int j = 0; j < deg; j += 8) {
        int jj = j + le;
        if (jj < deg) {
            int e = eidx[start + jj];
            float sc = attn_out[(size_t)e * NHEAD + h];
            attn_out[(size_t)e * NHEAD + h] = __expf(sc - m) * rinv;
        }
    }
}

// ===== GEMM + residual-add + LayerNorm fused =====
// out = LN( resid + [relu?](A @ W + bias) ) ; wave owns 16 complete rows.
template <int RELU, int OUT_BF16>
__global__ __launch_bounds__(256) void gemm_ln_kernel(
    const unsigned short* __restrict__ A, const unsigned short* __restrict__ Wt,
    const float* __restrict__ bias, const unsigned short* __restrict__ resid,
    const float* __restrict__ g, const float* __restrict__ be,
    void* __restrict__ out, int nrows) {
    __shared__ alignas(16) unsigned char Wl[32768];
    const int t = threadIdx.x;
#pragma unroll
    for (int i = 0; i < 8; ++i) {
        int c = t + 256 * i;
        int n = c >> 4, s = c & 15;
        bf16x8 val = *(const bf16x8*)(Wt + c * 8);
        *(bf16x8*)(Wl + n * 256 + ((s * 16) ^ ((n & 7) << 4))) = val;
    }
    const int l = t & 63, wave = t >> 6;
    const int l15 = l & 15, lg = l >> 4;
    const int r0 = blockIdx.x * 64 + wave * 16;
    const int arow = r0 + l15;
    const bool aok = arow < nrows;

    bf16x8 af[4];
#pragma unroll
    for (int k0 = 0; k0 < 4; ++k0) {
        bf16x8 z = (bf16x8){0, 0, 0, 0, 0, 0, 0, 0};
        af[k0] = aok ? *(const bf16x8*)(A + (size_t)arow * DIM + k0 * 32 + lg * 8) : z;
    }
    __syncthreads();

    f32x4 acc[8];
#pragma unroll
    for (int n = 0; n < 8; ++n) acc[n] = (f32x4){0.f, 0.f, 0.f, 0.f};
#pragma unroll
    for (int k0 = 0; k0 < 4; ++k0) {
#pragma unroll
        for (int n = 0; n < 8; ++n) {
            int row = n * 16 + l15;
            int kb = (k0 * 64 + lg * 16) ^ ((row & 7) << 4);
            bf16x8 bfr = *(bf16x8*)(Wl + row * 256 + kb);
            acc[n] = __builtin_amdgcn_mfma_f32_16x16x32_bf16(af[k0], bfr, acc[n], 0, 0, 0);
        }
    }

    float bv[8], gv[8], bev[8];
#pragma unroll
    for (int n = 0; n < 8; ++n) {
        int col = n * 16 + l15;
        bv[n] = bias[col]; gv[n] = g[col]; bev[n] = be[col];
    }
    // NOTE: nrows % 16 == 0 here, so row-validity is wave-uniform (shfl-safe).
#pragma unroll
    for (int i = 0; i < 4; ++i) {
        int r = r0 + lg * 4 + i;
        if (r >= nrows) continue;
        float xv[8];
        float s = 0.f;
#pragma unroll
        for (int n = 0; n < 8; ++n) {
            float val = acc[n][i] + bv[n];
            if (RELU) val = fmaxf(val, 0.f);
            val += bf2f(resid[(size_t)r * DIM + n * 16 + l15]);
            xv[n] = val;
            s += val;
        }
        s += __shfl_xor(s, 1); s += __shfl_xor(s, 2);
        s += __shfl_xor(s, 4); s += __shfl_xor(s, 8);
        float mean = s * (1.f / 128.f);
        float var = 0.f;
#pragma unroll
        for (int n = 0; n < 8; ++n) {
            float d = xv[n] - mean;
            var += d * d;
        }
        var += __shfl_xor(var, 1); var += __shfl_xor(var, 2);
        var += __shfl_xor(var, 4); var += __shfl_xor(var, 8);
        float rstd = rsqrtf(var * (1.f / 128.f) + 1e-5f);
#pragma unroll
        for (int n = 0; n < 8; ++n) {
            float o = (xv[n] - mean) * rstd * gv[n] + bev[n];
            int col = n * 16 + l15;
            if (OUT_BF16) ((unsigned short*)out)[(size_t)r * DIM + col] = f2bf(o);
            else          ((float*)out)[(size_t)r * DIM + col] = o;
        }
    }
}

extern "C" void kernel_launch(void* const* d_in, const int* in_sizes, int n_in,
                              void* d_out, int out_size, void* d_ws, size_t ws_size,
                              hipStream_t stream) {
    const float* x    = (const float*)d_in[0];
    const int*   ei   = (const int*)d_in[1];
    const float* sec  = (const float*)d_in[2];
    const float* W1   = (const float*)d_in[3];
    const float* b1   = (const float*)d_in[4];
    const float* W2   = (const float*)d_in[5];
    const float* b2   = (const float*)d_in[6];
    const float* Wq   = (const float*)d_in[7];
    const float* bq   = (const float*)d_in[8];
    const float* Wk   = (const float*)d_in[9];
    const float* bk   = (const float*)d_in[10];
    const float* Wv   = (const float*)d_in[11];
    const float* bvp  = (const float*)d_in[12];
    const float* Wsec = (const float*)d_in[13];
    const float* bsec = (const float*)d_in[14];
    const float* Wo   = (const float*)d_in[15];
    const float* bo   = (const float*)d_in[16];
    const float* g1   = (const float*)d_in[17];
    const float* be1  = (const float*)d_in[18];
    const float* g2   = (const float*)d_in[19];
    const float* be2  = (const float*)d_in[20];

    const int* srcp = ei;             // edge_index[0]
    const int* dstp = ei + N_EDGES;   // edge_index[1]

    char* wsb = (char*)d_ws;
    unsigned short* hb   = (unsigned short*)(wsb);              // 12.8MB
    unsigned short* qbu  = (unsigned short*)(wsb + 12800000);
    unsigned short* kbu  = (unsigned short*)(wsb + 25600000);
    unsigned short* vbu  = (unsigned short*)(wsb + 38400000);
    unsigned short* aggb = (unsigned short*)(wsb + 51200000);
    unsigned short* midb = (unsigned short*)(wsb + 64000000);
    float* secb          = (float*)(wsb + 76800000);            // 1.6MB
    unsigned short* Wt   = (unsigned short*)(wsb + 78400000);   // 192KB
    int* deg             = (int*)(wsb + 78600000);              // 200KB
    int* ctr             = (int*)(wsb + 78800000);              // 200KB
    int* rowstart        = (int*)(wsb + 79000000);              // 200KB+4
    int* eidxb           = (int*)(wsb + 79200256);              // 3.2MB
    int* esrcb           = (int*)(wsb + 82400256);              // 3.2MB
    int* bsum            = (int*)(wsb + 85600256);              // 784B
    int* bexc            = (int*)(wsb + 85601280);              // 784B

    float* outp = (float*)d_out;                 // [N,128]
    float* attn = outp + (size_t)N_NODES * DIM;  // [E,8]

    dim3 blk(256);
    const int gemm_grid = (N_NODES + 63) / 64;       // 782
    const int qkv_grid  = (N_NODES + 127) / 128;     // 391
    const int egrid = (N_EDGES + 255) / 256;         // 3125
    const int wgrid = (N_NODES + 3) / 4;             // 12500

    setup_kernel<<<6 + 196 + 1563, blk, 0, stream>>>(W1, Wq, Wk, Wv, Wo, W2, Wt,
                                                     deg, ctr, sec, Wsec, bsec, secb);
    count_deg_kernel<<<egrid, blk, 0, stream>>>(dstp, deg);
    blocksum_kernel<<<NSCAN_BLK, blk, 0, stream>>>(deg, bsum);
    scanb_kernel<<<1, blk, 0, stream>>>(bsum, bexc, rowstart);
    scanfin_kernel<<<NSCAN_BLK, blk, 0, stream>>>(deg, bexc, rowstart);
    fill_csr_kernel<<<egrid, blk, 0, stream>>>(srcp, dstp, rowstart, ctr, eidxb, esrcb);

    gemm_x_kernel<<<gemm_grid, blk, 0, stream>>>(x, Wt, b1, hb, N_NODES);
    gemm_qkv_kernel<<<qkv_grid, dim3(512), 0, stream>>>(hb, Wt + 16384, bq, bk, bvp,
                                                        qbu, kbu, vbu, N_NODES);

    node_attn_kernel<<<wgrid, blk, 0, stream>>>(qbu, kbu, vbu, secb, eidxb, esrcb,
                                                rowstart, attn, aggb);

    gemm_ln_kernel<0, 1><<<gemm_grid, blk, 0, stream>>>(aggb, Wt + 65536, bo, hb,
                                                        g1, be1, midb, N_NODES);
    gemm_ln_kernel<1, 0><<<gemm_grid, blk, 0, stream>>>(midb, Wt + 81920, b2, midb,
                                                        g2, be2, outp, N_NODES);
}

// Round 8
// 224.338 us; speedup vs baseline: 27.4735x; 1.1348x over previous
//
#include <hip/hip_runtime.h>
#include <hip/hip_bf16.h>
#include <math.h>

#define N_NODES 50000
#define N_EDGES 800000
#define DIM 128
#define NHEAD 8
#define DHEAD 16
#define SDIM 10
#define NSCAN_BLK 196   // ceil(N_NODES/256)

typedef __attribute__((ext_vector_type(8))) short bf16x8;
typedef __attribute__((ext_vector_type(4))) float f32x4;

__device__ __forceinline__ float bf2f(unsigned short u) {
    return __uint_as_float(((unsigned)u) << 16);
}
__device__ __forceinline__ unsigned short f2bf(float f) {
    unsigned u = __float_as_uint(f);
    return (unsigned short)((u + 0x7FFFu + ((u >> 16) & 1u)) >> 16);
}

// ===== setup: prep Wt (6 transposed bf16 weights) + zero deg/ctr + secbias ==
__global__ __launch_bounds__(256) void setup_kernel(
    const float* __restrict__ W1, const float* __restrict__ Wq,
    const float* __restrict__ Wk, const float* __restrict__ Wv,
    const float* __restrict__ Wo, const float* __restrict__ W2,
    unsigned short* __restrict__ Wt, int* __restrict__ deg, int* __restrict__ ctr,
    const float* __restrict__ sec, const float* __restrict__ Wsec,
    const float* __restrict__ bsec, float* __restrict__ secb) {
    const int b = blockIdx.x, t = threadIdx.x;
    if (b < 6) {
        const float* W = (b == 0) ? W1 : (b == 1) ? Wq : (b == 2) ? Wk :
                         (b == 3) ? Wv : (b == 4) ? Wo : W2;
        unsigned short* o = Wt + b * 16384;
        for (int i = 0; i < 64; ++i) {
            int idx = t + 256 * i;          // k-major element index
            int k = idx >> 7, n = idx & 127;
            o[n * 128 + k] = f2bf(W[idx]);
        }
    } else if (b < 202) {                   // 196 blocks: zero deg+ctr
        int idx = (b - 6) * 256 + t;
        if (idx < N_NODES) { deg[idx] = 0; ctr[idx] = 0; }
    } else {                                // 1563 blocks: secbias
        int idx = (b - 202) * 256 + t;
        if (idx < N_NODES * NHEAD) {
            int n = idx >> 3, h = idx & 7;
            float acc = bsec[h];
#pragma unroll
            for (int j = 0; j < SDIM; ++j)
                acc = fmaf(sec[n * SDIM + j], Wsec[j * NHEAD + h], acc);
            secb[idx] = acc;
        }
    }
}

// ===== CSR build =====
__global__ __launch_bounds__(256) void count_deg_kernel(const int* __restrict__ dst,
                                                        int* __restrict__ deg) {
    int e = blockIdx.x * 256 + threadIdx.x;
    if (e < N_EDGES) atomicAdd(&deg[dst[e]], 1);
}

__global__ __launch_bounds__(256) void blocksum_kernel(const int* __restrict__ deg,
                                                       int* __restrict__ bsum) {
    const int t = threadIdx.x;
    int idx = blockIdx.x * 256 + t;
    int v = (idx < N_NODES) ? deg[idx] : 0;
#pragma unroll
    for (int m = 32; m; m >>= 1) v += __shfl_xor(v, m);
    __shared__ int ws[4];
    if ((t & 63) == 0) ws[t >> 6] = v;
    __syncthreads();
    if (t == 0) bsum[blockIdx.x] = ws[0] + ws[1] + ws[2] + ws[3];
}

// per-block: compute own exclusive offset from bsum, then in-block scan
__global__ __launch_bounds__(256) void scanfin2_kernel(const int* __restrict__ deg,
                                                       const int* __restrict__ bsum,
                                                       int* __restrict__ rowstart) {
    const int t = threadIdx.x, b = blockIdx.x;
    int v0 = (t < b) ? bsum[t] : 0;     // b <= 195 < 256, t<b implies valid
#pragma unroll
    for (int m = 32; m; m >>= 1) v0 += __shfl_xor(v0, m);
    __shared__ int ws[4];
    if ((t & 63) == 0) ws[t >> 6] = v0;
    __syncthreads();
    const int bexc = ws[0] + ws[1] + ws[2] + ws[3];

    int idx = b * 256 + t;
    int v = (idx < N_NODES) ? deg[idx] : 0;
    __shared__ int s[256];
    __syncthreads();
    s[t] = v;
    __syncthreads();
#pragma unroll
    for (int off = 1; off < 256; off <<= 1) {
        int x = (t >= off) ? s[t - off] : 0;
        __syncthreads();
        s[t] += x;
        __syncthreads();
    }
    if (idx < N_NODES) rowstart[idx] = bexc + s[t] - v;
    if (b == 0 && t == 0) rowstart[N_NODES] = N_EDGES;
}

__global__ __launch_bounds__(256) void fill_csr_kernel(
    const int* __restrict__ src, const int* __restrict__ dst,
    const int* __restrict__ rowstart, int* __restrict__ ctr,
    int* __restrict__ eidx, int* __restrict__ esrc) {
    int e = blockIdx.x * 256 + threadIdx.x;
    if (e >= N_EDGES) return;
    int d = dst[e];
    int pos = atomicAdd(&ctr[d], 1);
    int slot = rowstart[d] + pos;
    eidx[slot] = e;
    esrc[slot] = src[e];
}

// ===== fused h + q/k/v GEMM: 512 thr, 128 rows/block ======================
__global__ __launch_bounds__(512) void gemm_hqkv_kernel(
    const float* __restrict__ X, const unsigned short* __restrict__ Wt,
    const float* __restrict__ b1, const float* __restrict__ bq,
    const float* __restrict__ bk, const float* __restrict__ bv,
    unsigned short* __restrict__ hb, unsigned short* __restrict__ qo,
    unsigned short* __restrict__ ko, unsigned short* __restrict__ vo, int nrows) {
    __shared__ alignas(16) unsigned char Wl[32768];
    __shared__ alignas(16) unsigned char Ht[32768];   // 8 waves x 16 rows x 256B
    const int t = threadIdx.x;
    const int l = t & 63, wave = t >> 6;
    const int l15 = l & 15, lg = l >> 4;
    const int r0 = blockIdx.x * 128 + wave * 16;
    const int arow = r0 + l15;
    const bool aok = arow < nrows;
    const int orow0 = r0 + lg * 4;
    unsigned char* HtW = Ht + wave * 4096;

    // stage W1
#pragma unroll
    for (int i = 0; i < 4; ++i) {
        int c = t + 512 * i;            // 2048 16B chunks
        int n = c >> 4, s = c & 15;
        bf16x8 val = *(const bf16x8*)(Wt + c * 8);
        *(bf16x8*)(Wl + n * 256 + ((s * 16) ^ ((n & 7) << 4))) = val;
    }
    // x f32 -> bf16 A-frags
    bf16x8 af[4];
#pragma unroll
    for (int k0 = 0; k0 < 4; ++k0) {
        float4 a0 = {0.f, 0.f, 0.f, 0.f}, a1 = {0.f, 0.f, 0.f, 0.f};
        if (aok) {
            const float4* ap = (const float4*)(X + (size_t)arow * DIM + k0 * 32 + lg * 8);
            a0 = ap[0]; a1 = ap[1];
        }
        bf16x8 f;
        f[0] = (short)f2bf(a0.x); f[1] = (short)f2bf(a0.y);
        f[2] = (short)f2bf(a0.z); f[3] = (short)f2bf(a0.w);
        f[4] = (short)f2bf(a1.x); f[5] = (short)f2bf(a1.y);
        f[6] = (short)f2bf(a1.z); f[7] = (short)f2bf(a1.w);
        af[k0] = f;
    }
    __syncthreads();

    {
        f32x4 acc[8];
#pragma unroll
        for (int n = 0; n < 8; ++n) acc[n] = (f32x4){0.f, 0.f, 0.f, 0.f};
#pragma unroll
        for (int k0 = 0; k0 < 4; ++k0) {
#pragma unroll
            for (int n = 0; n < 8; ++n) {
                int row = n * 16 + l15;
                int kb = (k0 * 64 + lg * 16) ^ ((row & 7) << 4);
                bf16x8 bfr = *(bf16x8*)(Wl + row * 256 + kb);
                acc[n] = __builtin_amdgcn_mfma_f32_16x16x32_bf16(af[k0], bfr, acc[n], 0, 0, 0);
            }
        }
        // epilogue: h = relu(acc + b1) -> hb + Ht (swizzled)
#pragma unroll
        for (int n = 0; n < 8; ++n) {
            int col = n * 16 + l15;
            float bvv = b1[col];
#pragma unroll
            for (int i = 0; i < 4; ++i) {
                int rloc = lg * 4 + i;
                unsigned short hv = f2bf(fmaxf(acc[n][i] + bvv, 0.f));
                if (orow0 + i < nrows) hb[(size_t)(orow0 + i) * DIM + col] = hv;
                *(unsigned short*)(HtW + ((rloc * 256 + col * 2) ^ ((rloc & 7) << 4))) = hv;
            }
        }
    }
    __syncthreads();   // W1 reads + Ht writes complete

    // A-frags of h from Ht
    bf16x8 af2[4];
#pragma unroll
    for (int k0 = 0; k0 < 4; ++k0)
        af2[k0] = *(const bf16x8*)(HtW + ((l15 * 256 + k0 * 64 + lg * 16) ^ ((l15 & 7) << 4)));

    for (int m = 0; m < 3; ++m) {
        const unsigned short* wsrc = (m == 0) ? Wt + 16384 : (m == 1) ? Wt + 32768 : Wt + 49152;
        const float* bias = (m == 0) ? bq : (m == 1) ? bk : bv;
        unsigned short* outp = (m == 0) ? qo : (m == 1) ? ko : vo;
#pragma unroll
        for (int i = 0; i < 4; ++i) {
            int c = t + 512 * i;
            int n = c >> 4, s = c & 15;
            bf16x8 val = *(const bf16x8*)(wsrc + c * 8);
            *(bf16x8*)(Wl + n * 256 + ((s * 16) ^ ((n & 7) << 4))) = val;
        }
        __syncthreads();
        f32x4 acc[8];
#pragma unroll
        for (int n = 0; n < 8; ++n) acc[n] = (f32x4){0.f, 0.f, 0.f, 0.f};
#pragma unroll
        for (int k0 = 0; k0 < 4; ++k0) {
#pragma unroll
            for (int n = 0; n < 8; ++n) {
                int row = n * 16 + l15;
                int kb = (k0 * 64 + lg * 16) ^ ((row & 7) << 4);
                bf16x8 bfr = *(bf16x8*)(Wl + row * 256 + kb);
                acc[n] = __builtin_amdgcn_mfma_f32_16x16x32_bf16(af2[k0], bfr, acc[n], 0, 0, 0);
            }
        }
#pragma unroll
        for (int n = 0; n < 8; ++n) {
            int col = n * 16 + l15;
            float bvv = bias[col];
#pragma unroll
            for (int i = 0; i < 4; ++i) {
                int r = orow0 + i;
                if (r < nrows) outp[(size_t)r * DIM + col] = f2bf(acc[n][i] + bvv);
            }
        }
        __syncthreads();   // before next restage
    }
}

// ===== fused scores + softmax + aggregation (wave per dst node) ============
__global__ __launch_bounds__(256) void node_attn_kernel(
    const unsigned short* __restrict__ qb, const unsigned short* __restrict__ kb,
    const unsigned short* __restrict__ vb, const float* __restrict__ secb,
    const int* __restrict__ eidx, const int* __restrict__ esrc,
    const int* __restrict__ rowstart, float* __restrict__ attn_out,
    unsigned short* __restrict__ aggb) {
    int node = blockIdx.x * 4 + (threadIdx.x >> 6);
    if (node >= N_NODES) return;
    const int lane = threadIdx.x & 63;
    const int start = rowstart[node];
    const int deg = rowstart[node + 1] - start;
    if (deg == 0) {
        ((unsigned*)(aggb + (size_t)node * DIM))[lane] = 0u;
        return;
    }
    const int h = lane & 7;     // head (score phases)
    const int le = lane >> 3;   // edge slot 0..7
    const int hc = le;          // head (aggregation mapping)

    float qv[16];
    {
        const bf16x8* qp = (const bf16x8*)(qb + (size_t)node * DIM + h * DHEAD);
        bf16x8 q0 = qp[0], q1 = qp[1];
#pragma unroll
        for (int i = 0; i < 8; ++i) {
            qv[i] = bf2f((unsigned short)q0[i]);
            qv[8 + i] = bf2f((unsigned short)q1[i]);
        }
    }

    if (deg <= 64) {
        // ---------- fast path: coalesced CSR preload + register scores ------
        int sall = 0, eall = 0;
        if (lane < deg) {
            int idx = start + lane;
            sall = esrc[idx];
            eall = eidx[idx];
        }
        float sc[8];
        float m = -INFINITY;
#pragma unroll
        for (int t = 0; t < 8; ++t) {
            sc[t] = -INFINITY;
            if (t * 8 < deg) {                       // wave-uniform
                int jj = t * 8 + le;
                bool valid = jj < deg;
                int s = __shfl(sall, valid ? jj : deg - 1);
                const bf16x8* kp = (const bf16x8*)(kb + (size_t)s * DIM + h * DHEAD);
                bf16x8 k0 = kp[0], k1 = kp[1];
                float acc = 0.f;
#pragma unroll
                for (int i = 0; i < 8; ++i) {
                    acc = fmaf(qv[i], bf2f((unsigned short)k0[i]), acc);
                    acc = fmaf(qv[8 + i], bf2f((unsigned short)k1[i]), acc);
                }
                if (valid) sc[t] = acc * 0.25f + secb[s * NHEAD + h];
            }
            m = fmaxf(m, sc[t]);
        }
        m = fmaxf(m, __shfl_xor(m, 8));
        m = fmaxf(m, __shfl_xor(m, 16));
        m = fmaxf(m, __shfl_xor(m, 32));

        float ev[8];
        float ssum = 0.f;
#pragma unroll
        for (int t = 0; t < 8; ++t) {
            ev[t] = (t * 8 + le < deg) ? __expf(sc[t] - m) : 0.f;
            ssum += ev[t];
        }
        ssum += __shfl_xor(ssum, 8);
        ssum += __shfl_xor(ssum, 16);
        ssum += __shfl_xor(ssum, 32);
        const float rinv = 1.f / (ssum + 1e-9f);     // head (lane&7)

        float2 acc2 = {0.f, 0.f};
#pragma unroll
        for (int t = 0; t < 8; ++t) {
            if (t * 8 < deg) {                       // wave-uniform
#pragma unroll
                for (int le2 = 0; le2 < 8; ++le2) {
                    int jj = t * 8 + le2;            // uniform
                    int s = __shfl(sall, (jj < deg) ? jj : deg - 1);  // uniform
                    float evd = __shfl(ev[t], le2 * 8 + hc);
                    unsigned vv = ((const unsigned*)(vb + (size_t)s * DIM))[lane];
                    acc2.x = fmaf(evd, bf2f((unsigned short)(vv & 0xFFFFu)), acc2.x);
                    acc2.y = fmaf(evd, bf2f((unsigned short)(vv >> 16)), acc2.y);
                }
            }
        }
        const float rinv_c = __shfl(rinv, hc);       // head (lane>>3)
        unsigned short o0 = f2bf(acc2.x * rinv_c);
        unsigned short o1 = f2bf(acc2.y * rinv_c);
        ((unsigned*)(aggb + (size_t)node * DIM))[lane] =
            (unsigned)o0 | ((unsigned)o1 << 16);

        // attn write: shfl hoisted OUT of the divergent guard (EXEC-safe)
#pragma unroll
        for (int t = 0; t < 8; ++t) {
            int jj = t * 8 + le;
            int e = __shfl(eall, (jj < deg) ? jj : 0);   // all lanes execute
            if (jj < deg) attn_out[(size_t)e * NHEAD + h] = ev[t] * rinv;
        }
        return;
    }

    // ---------- slow path (deg > 64): memory-staged, always correct ----------
    float m = -INFINITY;
    for (int j = 0; j < deg; j += 8) {
        int jj = j + le;
        float sc = -INFINITY;
        if (jj < deg) {
            int idx = start + jj;
            int s = esrc[idx];
            const bf16x8* kp = (const bf16x8*)(kb + (size_t)s * DIM + h * DHEAD);
            bf16x8 k0 = kp[0], k1 = kp[1];
            float acc = 0.f;
#pragma unroll
            for (int i = 0; i < 8; ++i) {
                acc = fmaf(qv[i], bf2f((unsigned short)k0[i]), acc);
                acc = fmaf(qv[8 + i], bf2f((unsigned short)k1[i]), acc);
            }
            sc = acc * 0.25f + secb[s * NHEAD + h];
            int e = eidx[idx];
            attn_out[(size_t)e * NHEAD + h] = sc;
        }
        m = fmaxf(m, sc);
    }
    m = fmaxf(m, __shfl_xor(m, 8));
    m = fmaxf(m, __shfl_xor(m, 16));
    m = fmaxf(m, __shfl_xor(m, 32));

    float ssum = 0.f;
    float2 acc2 = {0.f, 0.f};
    for (int j = 0; j < deg; j += 8) {
        int jj = j + le;
        float ev = 0.f;
        if (jj < deg) {
            int e = eidx[start + jj];
            ev = __expf(attn_out[(size_t)e * NHEAD + h] - m);
        }
        ssum += ev;
        int lim = deg - j; if (lim > 8) lim = 8;
        for (int le2 = 0; le2 < lim; ++le2) {
            float evd = __shfl(ev, le2 * 8 + hc);
            int s = esrc[start + j + le2];
            unsigned vv = ((const unsigned*)(vb + (size_t)s * DIM))[lane];
            acc2.x = fmaf(evd, bf2f((unsigned short)(vv & 0xFFFFu)), acc2.x);
            acc2.y = fmaf(evd, bf2f((unsigned short)(vv >> 16)), acc2.y);
        }
    }
    ssum += __shfl_xor(ssum, 8);
    ssum += __shfl_xor(ssum, 16);
    ssum += __shfl_xor(ssum, 32);
    const float rinv = 1.f / (ssum + 1e-9f);
    const float rinv_c = __shfl(rinv, hc);

    unsigned short o0 = f2bf(acc2.x * rinv_c);
    unsigned short o1 = f2bf(acc2.y * rinv_c);
    ((unsigned*)(aggb + (size_t)node * DIM))[lane] =
        (unsigned)o0 | ((unsigned)o1 << 16);

    for (int j = 0; j < deg; j += 8) {
        int jj = j + le;
        if (jj < deg) {
            int e = eidx[start + jj];
            float sc = attn_out[(size_t)e * NHEAD + h];
            attn_out[(size_t)e * NHEAD + h] = __expf(sc - m) * rinv;
        }
    }
}

// ===== fused double GEMM+LN: out = LN2(mid + relu(mid@W2+b2)),
//       mid = LN1(hb + agg@Wo+bo); midb never hits global. 512 thr/128 rows.
__global__ __launch_bounds__(512) void gemm_ln12_kernel(
    const unsigned short* __restrict__ A,      // aggb
    const unsigned short* __restrict__ Wt,     // Wo @ +0, W2 @ +16384
    const float* __restrict__ bo, const float* __restrict__ b2,
    const unsigned short* __restrict__ resid,  // hb
    const float* __restrict__ g1, const float* __restrict__ be1,
    const float* __restrict__ g2, const float* __restrict__ be2,
    float* __restrict__ outp, int nrows) {
    __shared__ alignas(16) unsigned char Wl[32768];
    __shared__ alignas(16) unsigned char Mt[32768];
    const int t = threadIdx.x;
    const int l = t & 63, wave = t >> 6;
    const int l15 = l & 15, lg = l >> 4;
    const int r0 = blockIdx.x * 128 + wave * 16;
    const int arow = r0 + l15;
    const bool aok = arow < nrows;
    const int orow0 = r0 + lg * 4;
    unsigned char* MtW = Mt + wave * 4096;

    // stage Wo
#pragma unroll
    for (int i = 0; i < 4; ++i) {
        int c = t + 512 * i;
        int n = c >> 4, s = c & 15;
        bf16x8 val = *(const bf16x8*)(Wt + c * 8);
        *(bf16x8*)(Wl + n * 256 + ((s * 16) ^ ((n & 7) << 4))) = val;
    }
    bf16x8 af[4];
#pragma unroll
    for (int k0 = 0; k0 < 4; ++k0) {
        bf16x8 z = (bf16x8){0, 0, 0, 0, 0, 0, 0, 0};
        af[k0] = aok ? *(const bf16x8*)(A + (size_t)arow * DIM + k0 * 32 + lg * 8) : z;
    }
    __syncthreads();

    float mid[8][4];    // bf16-rounded mid values, kept for LN2 residual
    {
        f32x4 acc[8];
#pragma unroll
        for (int n = 0; n < 8; ++n) acc[n] = (f32x4){0.f, 0.f, 0.f, 0.f};
#pragma unroll
        for (int k0 = 0; k0 < 4; ++k0) {
#pragma unroll
            for (int n = 0; n < 8; ++n) {
                int row = n * 16 + l15;
                int kb = (k0 * 64 + lg * 16) ^ ((row & 7) << 4);
                bf16x8 bfr = *(bf16x8*)(Wl + row * 256 + kb);
                acc[n] = __builtin_amdgcn_mfma_f32_16x16x32_bf16(af[k0], bfr, acc[n], 0, 0, 0);
            }
        }
        float bv[8], gv[8], bev[8];
#pragma unroll
        for (int n = 0; n < 8; ++n) {
            int col = n * 16 + l15;
            bv[n] = bo[col]; gv[n] = g1[col]; bev[n] = be1[col];
        }
#pragma unroll
        for (int i = 0; i < 4; ++i) {
            int r = orow0 + i;
            int rloc = lg * 4 + i;
            float xv[8];
            float s = 0.f;
            if (r < nrows) {
#pragma unroll
                for (int n = 0; n < 8; ++n) {
                    float val = acc[n][i] + bv[n]
                              + bf2f(resid[(size_t)r * DIM + n * 16 + l15]);
                    xv[n] = val;
                    s += val;
                }
            } else {
#pragma unroll
                for (int n = 0; n < 8; ++n) xv[n] = 0.f;
            }
            s += __shfl_xor(s, 1); s += __shfl_xor(s, 2);
            s += __shfl_xor(s, 4); s += __shfl_xor(s, 8);
            float mean = s * (1.f / 128.f);
            float var = 0.f;
#pragma unroll
            for (int n = 0; n < 8; ++n) {
                float d = xv[n] - mean;
                var += d * d;
            }
            var += __shfl_xor(var, 1); var += __shfl_xor(var, 2);
            var += __shfl_xor(var, 4); var += __shfl_xor(var, 8);
            float rstd = rsqrtf(var * (1.f / 128.f) + 1e-5f);
#pragma unroll
            for (int n = 0; n < 8; ++n) {
                int col = n * 16 + l15;
                unsigned short mb = f2bf((xv[n] - mean) * rstd * gv[n] + bev[n]);
                mid[n][i] = bf2f(mb);
                *(unsigned short*)(MtW + ((rloc * 256 + col * 2) ^ ((rloc & 7) << 4))) = mb;
            }
        }
    }
    __syncthreads();   // Wo reads + Mt writes complete

    bf16x8 af2[4];
#pragma unroll
    for (int k0 = 0; k0 < 4; ++k0)
        af2[k0] = *(const bf16x8*)(MtW + ((l15 * 256 + k0 * 64 + lg * 16) ^ ((l15 & 7) << 4)));

    // stage W2
#pragma unroll
    for (int i = 0; i < 4; ++i) {
        int c = t + 512 * i;
        int n = c >> 4, s = c & 15;
        bf16x8 val = *(const bf16x8*)(Wt + 16384 + c * 8);
        *(bf16x8*)(Wl + n * 256 + ((s * 16) ^ ((n & 7) << 4))) = val;
    }
    __syncthreads();

    {
        f32x4 acc[8];
#pragma unroll
        for (int n = 0; n < 8; ++n) acc[n] = (f32x4){0.f, 0.f, 0.f, 0.f};
#pragma unroll
        for (int k0 = 0; k0 < 4; ++k0) {
#pragma unroll
            for (int n = 0; n < 8; ++n) {
                int row = n * 16 + l15;
                int kb = (k0 * 64 + lg * 16) ^ ((row & 7) << 4);
                bf16x8 bfr = *(bf16x8*)(Wl + row * 256 + kb);
                acc[n] = __builtin_amdgcn_mfma_f32_16x16x32_bf16(af2[k0], bfr, acc[n], 0, 0, 0);
            }
        }
        float bv[8], gv[8], bev[8];
#pragma unroll
        for (int n = 0; n < 8; ++n) {
            int col = n * 16 + l15;
            bv[n] = b2[col]; gv[n] = g2[col]; bev[n] = be2[col];
        }
#pragma unroll
        for (int i = 0; i < 4; ++i) {
            int r = orow0 + i;
            float xv[8];
            float s = 0.f;
#pragma unroll
            for (int n = 0; n < 8; ++n) {
                float val = fmaxf(acc[n][i] + bv[n], 0.f) + mid[n][i];
                xv[n] = val;
                s += val;
            }
            s += __shfl_xor(s, 1); s += __shfl_xor(s, 2);
            s += __shfl_xor(s, 4); s += __shfl_xor(s, 8);
            float mean = s * (1.f / 128.f);
            float var = 0.f;
#pragma unroll
            for (int n = 0; n < 8; ++n) {
                float d = xv[n] - mean;
                var += d * d;
            }
            var += __shfl_xor(var, 1); var += __shfl_xor(var, 2);
            var += __shfl_xor(var, 4); var += __shfl_xor(var, 8);
            float rstd = rsqrtf(var * (1.f / 128.f) + 1e-5f);
            if (r < nrows) {
#pragma unroll
                for (int n = 0; n < 8; ++n) {
                    int col = n * 16 + l15;
                    outp[(size_t)r * DIM + col] = (xv[n] - mean) * rstd * gv[n] + bev[n];
                }
            }
        }
    }
}

extern "C" void kernel_launch(void* const* d_in, const int* in_sizes, int n_in,
                              void* d_out, int out_size, void* d_ws, size_t ws_size,
                              hipStream_t stream) {
    const float* x    = (const float*)d_in[0];
    const int*   ei   = (const int*)d_in[1];
    const float* sec  = (const float*)d_in[2];
    const float* W1   = (const float*)d_in[3];
    const float* b1   = (const float*)d_in[4];
    const float* W2   = (const float*)d_in[5];
    const float* b2   = (const float*)d_in[6];
    const float* Wq   = (const float*)d_in[7];
    const float* bq   = (const float*)d_in[8];
    const float* Wk   = (const float*)d_in[9];
    const float* bk   = (const float*)d_in[10];
    const float* Wv   = (const float*)d_in[11];
    const float* bvp  = (const float*)d_in[12];
    const float* Wsec = (const float*)d_in[13];
    const float* bsec = (const float*)d_in[14];
    const float* Wo   = (const float*)d_in[15];
    const float* bo   = (const float*)d_in[16];
    const float* g1   = (const float*)d_in[17];
    const float* be1  = (const float*)d_in[18];
    const float* g2   = (const float*)d_in[19];
    const float* be2  = (const float*)d_in[20];

    const int* srcp = ei;             // edge_index[0]
    const int* dstp = ei + N_EDGES;   // edge_index[1]

    char* wsb = (char*)d_ws;
    unsigned short* hb   = (unsigned short*)(wsb);              // 12.8MB
    unsigned short* qbu  = (unsigned short*)(wsb + 12800000);
    unsigned short* kbu  = (unsigned short*)(wsb + 25600000);
    unsigned short* vbu  = (unsigned short*)(wsb + 38400000);
    unsigned short* aggb = (unsigned short*)(wsb + 51200000);
    float* secb          = (float*)(wsb + 76800000);            // 1.6MB
    unsigned short* Wt   = (unsigned short*)(wsb + 78400000);   // 192KB
    int* deg             = (int*)(wsb + 78600000);              // 200KB
    int* ctr             = (int*)(wsb + 78800000);              // 200KB
    int* rowstart        = (int*)(wsb + 79000000);              // 200KB+4
    int* eidxb           = (int*)(wsb + 79200256);              // 3.2MB
    int* esrcb           = (int*)(wsb + 82400256);              // 3.2MB
    int* bsum            = (int*)(wsb + 85600256);              // 784B

    float* outp = (float*)d_out;                 // [N,128]
    float* attn = outp + (size_t)N_NODES * DIM;  // [E,8]

    dim3 blk(256);
    const int big_grid = (N_NODES + 127) / 128;      // 391 (512-thread kernels)
    const int egrid = (N_EDGES + 255) / 256;         // 3125
    const int wgrid = (N_NODES + 3) / 4;             // 12500

    setup_kernel<<<6 + 196 + 1563, blk, 0, stream>>>(W1, Wq, Wk, Wv, Wo, W2, Wt,
                                                     deg, ctr, sec, Wsec, bsec, secb);
    count_deg_kernel<<<egrid, blk, 0, stream>>>(dstp, deg);
    blocksum_kernel<<<NSCAN_BLK, blk, 0, stream>>>(deg, bsum);
    scanfin2_kernel<<<NSCAN_BLK, blk, 0, stream>>>(deg, bsum, rowstart);
    fill_csr_kernel<<<egrid, blk, 0, stream>>>(srcp, dstp, rowstart, ctr, eidxb, esrcb);

    gemm_hqkv_kernel<<<big_grid, dim3(512), 0, stream>>>(x, Wt, b1, bq, bk, bvp,
                                                         hb, qbu, kbu, vbu, N_NODES);

    node_attn_kernel<<<wgrid, blk, 0, stream>>>(qbu, kbu, vbu, secb, eidxb, esrcb,
                                                rowstart, attn, aggb);

    gemm_ln12_kernel<<<big_grid, dim3(512), 0, stream>>>(aggb, Wt + 65536, bo, b2, hb,
                                                         g1, be1, g2, be2, outp, N_NODES);
}

// Round 9
// 216.643 us; speedup vs baseline: 28.4494x; 1.0355x over previous
//
#include <hip/hip_runtime.h>
#include <hip/hip_bf16.h>
#include <math.h>

#define N_NODES 50000
#define N_EDGES 800000
#define DIM 128
#define NHEAD 8
#define DHEAD 16
#define SDIM 10
#define NSCAN_BLK 196   // ceil(N_NODES/256)
#define SETUP_W 48      // weight-prep blocks (6 matrices x 8 slices)
#define SETUP_CNT 3125  // count_deg blocks
#define SETUP_SEC 1563  // secbias blocks

typedef __attribute__((ext_vector_type(8))) short bf16x8;
typedef __attribute__((ext_vector_type(4))) float f32x4;

__device__ __forceinline__ float bf2f(unsigned short u) {
    return __uint_as_float(((unsigned)u) << 16);
}
__device__ __forceinline__ unsigned short f2bf(float f) {
    unsigned u = __float_as_uint(f);
    return (unsigned short)((u + 0x7FFFu + ((u >> 16) & 1u)) >> 16);
}

// ===== setup: weight prep (48 blks) + count_deg (3125 blks) + secbias =======
// deg/ctr are pre-zeroed by hipMemsetAsync before this kernel.
__global__ __launch_bounds__(256) void setup_kernel(
    const float* __restrict__ W1, const float* __restrict__ Wq,
    const float* __restrict__ Wk, const float* __restrict__ Wv,
    const float* __restrict__ Wo, const float* __restrict__ W2,
    unsigned short* __restrict__ Wt, const int* __restrict__ dst,
    int* __restrict__ deg, const float* __restrict__ sec,
    const float* __restrict__ Wsec, const float* __restrict__ bsec,
    float* __restrict__ secb) {
    const int b = blockIdx.x, t = threadIdx.x;
    if (b < SETUP_W) {
        const int mtx = b >> 3, slice = b & 7;
        const float* W = (mtx == 0) ? W1 : (mtx == 1) ? Wq : (mtx == 2) ? Wk :
                         (mtx == 3) ? Wv : (mtx == 4) ? Wo : W2;
        unsigned short* o = Wt + mtx * 16384;
#pragma unroll
        for (int i = 0; i < 8; ++i) {
            int idx = slice * 2048 + t + 256 * i;   // k-major element index
            int k = idx >> 7, n = idx & 127;
            o[n * 128 + k] = f2bf(W[idx]);
        }
    } else if (b < SETUP_W + SETUP_CNT) {           // count_deg
        int e = (b - SETUP_W) * 256 + t;
        if (e < N_EDGES) atomicAdd(&deg[dst[e]], 1);
    } else {                                        // secbias
        int idx = (b - SETUP_W - SETUP_CNT) * 256 + t;
        if (idx < N_NODES * NHEAD) {
            int n = idx >> 3, h = idx & 7;
            float acc = bsec[h];
#pragma unroll
            for (int j = 0; j < SDIM; ++j)
                acc = fmaf(sec[n * SDIM + j], Wsec[j * NHEAD + h], acc);
            secb[idx] = acc;
        }
    }
}

__global__ __launch_bounds__(256) void blocksum_kernel(const int* __restrict__ deg,
                                                       int* __restrict__ bsum) {
    const int t = threadIdx.x;
    int idx = blockIdx.x * 256 + t;
    int v = (idx < N_NODES) ? deg[idx] : 0;
#pragma unroll
    for (int m = 32; m; m >>= 1) v += __shfl_xor(v, m);
    __shared__ int ws[4];
    if ((t & 63) == 0) ws[t >> 6] = v;
    __syncthreads();
    if (t == 0) bsum[blockIdx.x] = ws[0] + ws[1] + ws[2] + ws[3];
}

// per-block: compute own exclusive offset from bsum, then in-block scan
__global__ __launch_bounds__(256) void scanfin2_kernel(const int* __restrict__ deg,
                                                       const int* __restrict__ bsum,
                                                       int* __restrict__ rowstart) {
    const int t = threadIdx.x, b = blockIdx.x;
    int v0 = (t < b) ? bsum[t] : 0;     // b <= 195 < 256, t<b implies valid
#pragma unroll
    for (int m = 32; m; m >>= 1) v0 += __shfl_xor(v0, m);
    __shared__ int ws[4];
    if ((t & 63) == 0) ws[t >> 6] = v0;
    __syncthreads();
    const int bexc = ws[0] + ws[1] + ws[2] + ws[3];

    int idx = b * 256 + t;
    int v = (idx < N_NODES) ? deg[idx] : 0;
    __shared__ int s[256];
    __syncthreads();
    s[t] = v;
    __syncthreads();
#pragma unroll
    for (int off = 1; off < 256; off <<= 1) {
        int x = (t >= off) ? s[t - off] : 0;
        __syncthreads();
        s[t] += x;
        __syncthreads();
    }
    if (idx < N_NODES) rowstart[idx] = bexc + s[t] - v;
    if (b == 0 && t == 0) rowstart[N_NODES] = N_EDGES;
}

// packed CSR fill: one 8B scattered write per edge {src, e}
__global__ __launch_bounds__(256) void fill_csr_kernel(
    const int* __restrict__ src, const int* __restrict__ dst,
    const int* __restrict__ rowstart, int* __restrict__ ctr,
    int2* __restrict__ epair) {
    int e = blockIdx.x * 256 + threadIdx.x;
    if (e >= N_EDGES) return;
    int d = dst[e];
    int pos = atomicAdd(&ctr[d], 1);
    epair[rowstart[d] + pos] = make_int2(src[e], e);
}

// ===== fused h + q/k/v GEMM: 512 thr, 128 rows/block ======================
__global__ __launch_bounds__(512) void gemm_hqkv_kernel(
    const float* __restrict__ X, const unsigned short* __restrict__ Wt,
    const float* __restrict__ b1, const float* __restrict__ bq,
    const float* __restrict__ bk, const float* __restrict__ bv,
    unsigned short* __restrict__ hb, unsigned short* __restrict__ qo,
    unsigned short* __restrict__ ko, unsigned short* __restrict__ vo, int nrows) {
    __shared__ alignas(16) unsigned char Wl[32768];
    __shared__ alignas(16) unsigned char Ht[32768];   // 8 waves x 16 rows x 256B
    const int t = threadIdx.x;
    const int l = t & 63, wave = t >> 6;
    const int l15 = l & 15, lg = l >> 4;
    const int r0 = blockIdx.x * 128 + wave * 16;
    const int arow = r0 + l15;
    const bool aok = arow < nrows;
    const int orow0 = r0 + lg * 4;
    unsigned char* HtW = Ht + wave * 4096;

    // stage W1
#pragma unroll
    for (int i = 0; i < 4; ++i) {
        int c = t + 512 * i;            // 2048 16B chunks
        int n = c >> 4, s = c & 15;
        bf16x8 val = *(const bf16x8*)(Wt + c * 8);
        *(bf16x8*)(Wl + n * 256 + ((s * 16) ^ ((n & 7) << 4))) = val;
    }
    // x f32 -> bf16 A-frags
    bf16x8 af[4];
#pragma unroll
    for (int k0 = 0; k0 < 4; ++k0) {
        float4 a0 = {0.f, 0.f, 0.f, 0.f}, a1 = {0.f, 0.f, 0.f, 0.f};
        if (aok) {
            const float4* ap = (const float4*)(X + (size_t)arow * DIM + k0 * 32 + lg * 8);
            a0 = ap[0]; a1 = ap[1];
        }
        bf16x8 f;
        f[0] = (short)f2bf(a0.x); f[1] = (short)f2bf(a0.y);
        f[2] = (short)f2bf(a0.z); f[3] = (short)f2bf(a0.w);
        f[4] = (short)f2bf(a1.x); f[5] = (short)f2bf(a1.y);
        f[6] = (short)f2bf(a1.z); f[7] = (short)f2bf(a1.w);
        af[k0] = f;
    }
    __syncthreads();

    {
        f32x4 acc[8];
#pragma unroll
        for (int n = 0; n < 8; ++n) acc[n] = (f32x4){0.f, 0.f, 0.f, 0.f};
#pragma unroll
        for (int k0 = 0; k0 < 4; ++k0) {
#pragma unroll
            for (int n = 0; n < 8; ++n) {
                int row = n * 16 + l15;
                int kb = (k0 * 64 + lg * 16) ^ ((row & 7) << 4);
                bf16x8 bfr = *(bf16x8*)(Wl + row * 256 + kb);
                acc[n] = __builtin_amdgcn_mfma_f32_16x16x32_bf16(af[k0], bfr, acc[n], 0, 0, 0);
            }
        }
        // epilogue: h = relu(acc + b1) -> hb + Ht (swizzled)
#pragma unroll
        for (int n = 0; n < 8; ++n) {
            int col = n * 16 + l15;
            float bvv = b1[col];
#pragma unroll
            for (int i = 0; i < 4; ++i) {
                int rloc = lg * 4 + i;
                unsigned short hv = f2bf(fmaxf(acc[n][i] + bvv, 0.f));
                if (orow0 + i < nrows) hb[(size_t)(orow0 + i) * DIM + col] = hv;
                *(unsigned short*)(HtW + ((rloc * 256 + col * 2) ^ ((rloc & 7) << 4))) = hv;
            }
        }
    }
    __syncthreads();   // W1 reads + Ht writes complete

    // A-frags of h from Ht
    bf16x8 af2[4];
#pragma unroll
    for (int k0 = 0; k0 < 4; ++k0)
        af2[k0] = *(const bf16x8*)(HtW + ((l15 * 256 + k0 * 64 + lg * 16) ^ ((l15 & 7) << 4)));

    for (int m = 0; m < 3; ++m) {
        const unsigned short* wsrc = (m == 0) ? Wt + 16384 : (m == 1) ? Wt + 32768 : Wt + 49152;
        const float* bias = (m == 0) ? bq : (m == 1) ? bk : bv;
        unsigned short* outp = (m == 0) ? qo : (m == 1) ? ko : vo;
#pragma unroll
        for (int i = 0; i < 4; ++i) {
            int c = t + 512 * i;
            int n = c >> 4, s = c & 15;
            bf16x8 val = *(const bf16x8*)(wsrc + c * 8);
            *(bf16x8*)(Wl + n * 256 + ((s * 16) ^ ((n & 7) << 4))) = val;
        }
        __syncthreads();
        f32x4 acc[8];
#pragma unroll
        for (int n = 0; n < 8; ++n) acc[n] = (f32x4){0.f, 0.f, 0.f, 0.f};
#pragma unroll
        for (int k0 = 0; k0 < 4; ++k0) {
#pragma unroll
            for (int n = 0; n < 8; ++n) {
                int row = n * 16 + l15;
                int kb = (k0 * 64 + lg * 16) ^ ((row & 7) << 4);
                bf16x8 bfr = *(bf16x8*)(Wl + row * 256 + kb);
                acc[n] = __builtin_amdgcn_mfma_f32_16x16x32_bf16(af2[k0], bfr, acc[n], 0, 0, 0);
            }
        }
#pragma unroll
        for (int n = 0; n < 8; ++n) {
            int col = n * 16 + l15;
            float bvv = bias[col];
#pragma unroll
            for (int i = 0; i < 4; ++i) {
                int r = orow0 + i;
                if (r < nrows) outp[(size_t)r * DIM + col] = f2bf(acc[n][i] + bvv);
            }
        }
        __syncthreads();   // before next restage
    }
}

// ===== fused scores + softmax + aggregation (wave per dst node) ============
__global__ __launch_bounds__(256) void node_attn_kernel(
    const unsigned short* __restrict__ qb, const unsigned short* __restrict__ kb,
    const unsigned short* __restrict__ vb, const float* __restrict__ secb,
    const int2* __restrict__ epair, const int* __restrict__ rowstart,
    float* __restrict__ attn_out, unsigned short* __restrict__ aggb) {
    int node = blockIdx.x * 4 + (threadIdx.x >> 6);
    if (node >= N_NODES) return;
    const int lane = threadIdx.x & 63;
    const int start = rowstart[node];
    const int deg = rowstart[node + 1] - start;
    if (deg == 0) {
        ((unsigned*)(aggb + (size_t)node * DIM))[lane] = 0u;
        return;
    }
    const int h = lane & 7;     // head (score phases)
    const int le = lane >> 3;   // edge slot 0..7
    const int hc = le;          // head (aggregation mapping)

    float qv[16];
    {
        const bf16x8* qp = (const bf16x8*)(qb + (size_t)node * DIM + h * DHEAD);
        bf16x8 q0 = qp[0], q1 = qp[1];
#pragma unroll
        for (int i = 0; i < 8; ++i) {
            qv[i] = bf2f((unsigned short)q0[i]);
            qv[8 + i] = bf2f((unsigned short)q1[i]);
        }
    }

    if (deg <= 64) {
        // ---------- fast path: coalesced int2 preload + register scores ----
        int sall = 0, eall = 0;
        if (lane < deg) {
            int2 p = epair[start + lane];
            sall = p.x;
            eall = p.y;
        }
        float sc[8];
        float m = -INFINITY;
#pragma unroll
        for (int t = 0; t < 8; ++t) {
            sc[t] = -INFINITY;
            if (t * 8 < deg) {                       // wave-uniform
                int jj = t * 8 + le;
                bool valid = jj < deg;
                int s = __shfl(sall, valid ? jj : deg - 1);
                const bf16x8* kp = (const bf16x8*)(kb + (size_t)s * DIM + h * DHEAD);
                bf16x8 k0 = kp[0], k1 = kp[1];
                float acc = 0.f;
#pragma unroll
                for (int i = 0; i < 8; ++i) {
                    acc = fmaf(qv[i], bf2f((unsigned short)k0[i]), acc);
                    acc = fmaf(qv[8 + i], bf2f((unsigned short)k1[i]), acc);
                }
                if (valid) sc[t] = acc * 0.25f + secb[s * NHEAD + h];
            }
            m = fmaxf(m, sc[t]);
        }
        m = fmaxf(m, __shfl_xor(m, 8));
        m = fmaxf(m, __shfl_xor(m, 16));
        m = fmaxf(m, __shfl_xor(m, 32));

        float ev[8];
        float ssum = 0.f;
#pragma unroll
        for (int t = 0; t < 8; ++t) {
            ev[t] = (t * 8 + le < deg) ? __expf(sc[t] - m) : 0.f;
            ssum += ev[t];
        }
        ssum += __shfl_xor(ssum, 8);
        ssum += __shfl_xor(ssum, 16);
        ssum += __shfl_xor(ssum, 32);
        const float rinv = 1.f / (ssum + 1e-9f);     // head (lane&7)

        float2 acc2 = {0.f, 0.f};
#pragma unroll
        for (int t = 0; t < 8; ++t) {
            if (t * 8 < deg) {                       // wave-uniform
#pragma unroll
                for (int le2 = 0; le2 < 8; ++le2) {
                    int jj = t * 8 + le2;            // uniform
                    int s = __shfl(sall, (jj < deg) ? jj : deg - 1);  // uniform
                    float evd = __shfl(ev[t], le2 * 8 + hc);
                    unsigned vv = ((const unsigned*)(vb + (size_t)s * DIM))[lane];
                    acc2.x = fmaf(evd, bf2f((unsigned short)(vv & 0xFFFFu)), acc2.x);
                    acc2.y = fmaf(evd, bf2f((unsigned short)(vv >> 16)), acc2.y);
                }
            }
        }
        const float rinv_c = __shfl(rinv, hc);       // head (lane>>3)
        unsigned short o0 = f2bf(acc2.x * rinv_c);
        unsigned short o1 = f2bf(acc2.y * rinv_c);
        ((unsigned*)(aggb + (size_t)node * DIM))[lane] =
            (unsigned)o0 | ((unsigned)o1 << 16);

        // attn write: shfl hoisted OUT of the divergent guard (EXEC-safe)
#pragma unroll
        for (int t = 0; t < 8; ++t) {
            int jj = t * 8 + le;
            int e = __shfl(eall, (jj < deg) ? jj : 0);   // all lanes execute
            if (jj < deg) attn_out[(size_t)e * NHEAD + h] = ev[t] * rinv;
        }
        return;
    }

    // ---------- slow path (deg > 64): memory-staged, always correct ----------
    float m = -INFINITY;
    for (int j = 0; j < deg; j += 8) {
        int jj = j + le;
        float sc = -INFINITY;
        if (jj < deg) {
            int2 p = epair[start + jj];
            int s = p.x;
            const bf16x8* kp = (const bf16x8*)(kb + (size_t)s * DIM + h * DHEAD);
            bf16x8 k0 = kp[0], k1 = kp[1];
            float acc = 0.f;
#pragma unroll
            for (int i = 0; i < 8; ++i) {
                acc = fmaf(qv[i], bf2f((unsigned short)k0[i]), acc);
                acc = fmaf(qv[8 + i], bf2f((unsigned short)k1[i]), acc);
            }
            sc = acc * 0.25f + secb[s * NHEAD + h];
            attn_out[(size_t)p.y * NHEAD + h] = sc;
        }
        m = fmaxf(m, sc);
    }
    m = fmaxf(m, __shfl_xor(m, 8));
    m = fmaxf(m, __shfl_xor(m, 16));
    m = fmaxf(m, __shfl_xor(m, 32));

    float ssum = 0.f;
    float2 acc2 = {0.f, 0.f};
    for (int j = 0; j < deg; j += 8) {
        int jj = j + le;
        float ev = 0.f;
        if (jj < deg) {
            int e = epair[start + jj].y;
            ev = __expf(attn_out[(size_t)e * NHEAD + h] - m);
        }
        ssum += ev;
        int lim = deg - j; if (lim > 8) lim = 8;
        for (int le2 = 0; le2 < lim; ++le2) {
            float evd = __shfl(ev, le2 * 8 + hc);
            int s = epair[start + j + le2].x;
            unsigned vv = ((const unsigned*)(vb + (size_t)s * DIM))[lane];
            acc2.x = fmaf(evd, bf2f((unsigned short)(vv & 0xFFFFu)), acc2.x);
            acc2.y = fmaf(evd, bf2f((unsigned short)(vv >> 16)), acc2.y);
        }
    }
    ssum += __shfl_xor(ssum, 8);
    ssum += __shfl_xor(ssum, 16);
    ssum += __shfl_xor(ssum, 32);
    const float rinv = 1.f / (ssum + 1e-9f);
    const float rinv_c = __shfl(rinv, hc);

    unsigned short o0 = f2bf(acc2.x * rinv_c);
    unsigned short o1 = f2bf(acc2.y * rinv_c);
    ((unsigned*)(aggb + (size_t)node * DIM))[lane] =
        (unsigned)o0 | ((unsigned)o1 << 16);

    for (int j = 0; j < deg; j += 8) {
        int jj = j + le;
        if (jj < deg) {
            int e = epair[start + jj].y;
            float sc = attn_out[(size_t)e * NHEAD + h];
            attn_out[(size_t)e * NHEAD + h] = __expf(sc - m) * rinv;
        }
    }
}

// ===== fused double GEMM+LN: out = LN2(mid + relu(mid@W2+b2)),
//       mid = LN1(hb + agg@Wo+bo); midb never hits global. 512 thr/128 rows.
__global__ __launch_bounds__(512) void gemm_ln12_kernel(
    const unsigned short* __restrict__ A,      // aggb
    const unsigned short* __restrict__ Wt,     // Wo @ +0, W2 @ +16384
    const float* __restrict__ bo, const float* __restrict__ b2,
    const unsigned short* __restrict__ resid,  // hb
    const float* __restrict__ g1, const float* __restrict__ be1,
    const float* __restrict__ g2, const float* __restrict__ be2,
    float* __restrict__ outp, int nrows) {
    __shared__ alignas(16) unsigned char Wl[32768];
    __shared__ alignas(16) unsigned char Mt[32768];
    const int t = threadIdx.x;
    const int l = t & 63, wave = t >> 6;
    const int l15 = l & 15, lg = l >> 4;
    const int r0 = blockIdx.x * 128 + wave * 16;
    const int arow = r0 + l15;
    const bool aok = arow < nrows;
    const int orow0 = r0 + lg * 4;
    unsigned char* MtW = Mt + wave * 4096;

    // stage Wo
#pragma unroll
    for (int i = 0; i < 4; ++i) {
        int c = t + 512 * i;
        int n = c >> 4, s = c & 15;
        bf16x8 val = *(const bf16x8*)(Wt + c * 8);
        *(bf16x8*)(Wl + n * 256 + ((s * 16) ^ ((n & 7) << 4))) = val;
    }
    bf16x8 af[4];
#pragma unroll
    for (int k0 = 0; k0 < 4; ++k0) {
        bf16x8 z = (bf16x8){0, 0, 0, 0, 0, 0, 0, 0};
        af[k0] = aok ? *(const bf16x8*)(A + (size_t)arow * DIM + k0 * 32 + lg * 8) : z;
    }
    __syncthreads();

    float mid[8][4];    // bf16-rounded mid values, kept for LN2 residual
    {
        f32x4 acc[8];
#pragma unroll
        for (int n = 0; n < 8; ++n) acc[n] = (f32x4){0.f, 0.f, 0.f, 0.f};
#pragma unroll
        for (int k0 = 0; k0 < 4; ++k0) {
#pragma unroll
            for (int n = 0; n < 8; ++n) {
                int row = n * 16 + l15;
                int kb = (k0 * 64 + lg * 16) ^ ((row & 7) << 4);
                bf16x8 bfr = *(bf16x8*)(Wl + row * 256 + kb);
                acc[n] = __builtin_amdgcn_mfma_f32_16x16x32_bf16(af[k0], bfr, acc[n], 0, 0, 0);
            }
        }
        float bv[8], gv[8], bev[8];
#pragma unroll
        for (int n = 0; n < 8; ++n) {
            int col = n * 16 + l15;
            bv[n] = bo[col]; gv[n] = g1[col]; bev[n] = be1[col];
        }
#pragma unroll
        for (int i = 0; i < 4; ++i) {
            int r = orow0 + i;
            int rloc = lg * 4 + i;
            float xv[8];
            float s = 0.f;
            if (r < nrows) {
#pragma unroll
                for (int n = 0; n < 8; ++n) {
                    float val = acc[n][i] + bv[n]
                              + bf2f(resid[(size_t)r * DIM + n * 16 + l15]);
                    xv[n] = val;
                    s += val;
                }
            } else {
#pragma unroll
                for (int n = 0; n < 8; ++n) xv[n] = 0.f;
            }
            s += __shfl_xor(s, 1); s += __shfl_xor(s, 2);
            s += __shfl_xor(s, 4); s += __shfl_xor(s, 8);
            float mean = s * (1.f / 128.f);
            float var = 0.f;
#pragma unroll
            for (int n = 0; n < 8; ++n) {
                float d = xv[n] - mean;
                var += d * d;
            }
            var += __shfl_xor(var, 1); var += __shfl_xor(var, 2);
            var += __shfl_xor(var, 4); var += __shfl_xor(var, 8);
            float rstd = rsqrtf(var * (1.f / 128.f) + 1e-5f);
#pragma unroll
            for (int n = 0; n < 8; ++n) {
                int col = n * 16 + l15;
                unsigned short mb = f2bf((xv[n] - mean) * rstd * gv[n] + bev[n]);
                mid[n][i] = bf2f(mb);
                *(unsigned short*)(MtW + ((rloc * 256 + col * 2) ^ ((rloc & 7) << 4))) = mb;
            }
        }
    }
    __syncthreads();   // Wo reads + Mt writes complete

    bf16x8 af2[4];
#pragma unroll
    for (int k0 = 0; k0 < 4; ++k0)
        af2[k0] = *(const bf16x8*)(MtW + ((l15 * 256 + k0 * 64 + lg * 16) ^ ((l15 & 7) << 4)));

    // stage W2
#pragma unroll
    for (int i = 0; i < 4; ++i) {
        int c = t + 512 * i;
        int n = c >> 4, s = c & 15;
        bf16x8 val = *(const bf16x8*)(Wt + 16384 + c * 8);
        *(bf16x8*)(Wl + n * 256 + ((s * 16) ^ ((n & 7) << 4))) = val;
    }
    __syncthreads();

    {
        f32x4 acc[8];
#pragma unroll
        for (int n = 0; n < 8; ++n) acc[n] = (f32x4){0.f, 0.f, 0.f, 0.f};
#pragma unroll
        for (int k0 = 0; k0 < 4; ++k0) {
#pragma unroll
            for (int n = 0; n < 8; ++n) {
                int row = n * 16 + l15;
                int kb = (k0 * 64 + lg * 16) ^ ((row & 7) << 4);
                bf16x8 bfr = *(bf16x8*)(Wl + row * 256 + kb);
                acc[n] = __builtin_amdgcn_mfma_f32_16x16x32_bf16(af2[k0], bfr, acc[n], 0, 0, 0);
            }
        }
        float bv[8], gv[8], bev[8];
#pragma unroll
        for (int n = 0; n < 8; ++n) {
            int col = n * 16 + l15;
            bv[n] = b2[col]; gv[n] = g2[col]; bev[n] = be2[col];
        }
#pragma unroll
        for (int i = 0; i < 4; ++i) {
            int r = orow0 + i;
            float xv[8];
            float s = 0.f;
#pragma unroll
            for (int n = 0; n < 8; ++n) {
                float val = fmaxf(acc[n][i] + bv[n], 0.f) + mid[n][i];
                xv[n] = val;
                s += val;
            }
            s += __shfl_xor(s, 1); s += __shfl_xor(s, 2);
            s += __shfl_xor(s, 4); s += __shfl_xor(s, 8);
            float mean = s * (1.f / 128.f);
            float var = 0.f;
#pragma unroll
            for (int n = 0; n < 8; ++n) {
                float d = xv[n] - mean;
                var += d * d;
            }
            var += __shfl_xor(var, 1); var += __shfl_xor(var, 2);
            var += __shfl_xor(var, 4); var += __shfl_xor(var, 8);
            float rstd = rsqrtf(var * (1.f / 128.f) + 1e-5f);
            if (r < nrows) {
#pragma unroll
                for (int n = 0; n < 8; ++n) {
                    int col = n * 16 + l15;
                    outp[(size_t)r * DIM + col] = (xv[n] - mean) * rstd * gv[n] + bev[n];
                }
            }
        }
    }
}

extern "C" void kernel_launch(void* const* d_in, const int* in_sizes, int n_in,
                              void* d_out, int out_size, void* d_ws, size_t ws_size,
                              hipStream_t stream) {
    const float* x    = (const float*)d_in[0];
    const int*   ei   = (const int*)d_in[1];
    const float* sec  = (const float*)d_in[2];
    const float* W1   = (const float*)d_in[3];
    const float* b1   = (const float*)d_in[4];
    const float* W2   = (const float*)d_in[5];
    const float* b2   = (const float*)d_in[6];
    const float* Wq   = (const float*)d_in[7];
    const float* bq   = (const float*)d_in[8];
    const float* Wk   = (const float*)d_in[9];
    const float* bk   = (const float*)d_in[10];
    const float* Wv   = (const float*)d_in[11];
    const float* bvp  = (const float*)d_in[12];
    const float* Wsec = (const float*)d_in[13];
    const float* bsec = (const float*)d_in[14];
    const float* Wo   = (const float*)d_in[15];
    const float* bo   = (const float*)d_in[16];
    const float* g1   = (const float*)d_in[17];
    const float* be1  = (const float*)d_in[18];
    const float* g2   = (const float*)d_in[19];
    const float* be2  = (const float*)d_in[20];

    const int* srcp = ei;             // edge_index[0]
    const int* dstp = ei + N_EDGES;   // edge_index[1]

    char* wsb = (char*)d_ws;
    unsigned short* hb   = (unsigned short*)(wsb);              // 12.8MB
    unsigned short* qbu  = (unsigned short*)(wsb + 12800000);
    unsigned short* kbu  = (unsigned short*)(wsb + 25600000);
    unsigned short* vbu  = (unsigned short*)(wsb + 38400000);
    unsigned short* aggb = (unsigned short*)(wsb + 51200000);
    float* secb          = (float*)(wsb + 76800000);            // 1.6MB
    unsigned short* Wt   = (unsigned short*)(wsb + 78400000);   // 192KB
    int* deg             = (int*)(wsb + 78600000);              // 200KB
    int* ctr             = (int*)(wsb + 78800000);              // 200KB
    int* rowstart        = (int*)(wsb + 79000000);              // 200KB+4
    int2* epair          = (int2*)(wsb + 79200256);             // 6.4MB
    int* bsum            = (int*)(wsb + 85600512);              // 784B

    float* outp = (float*)d_out;                 // [N,128]
    float* attn = outp + (size_t)N_NODES * DIM;  // [E,8]

    dim3 blk(256);
    const int big_grid = (N_NODES + 127) / 128;      // 391 (512-thread kernels)
    const int egrid = (N_EDGES + 255) / 256;         // 3125
    const int wgrid = (N_NODES + 3) / 4;             // 12500

    // zero deg+ctr (adjacent 400KB) — graph-capturable async memset
    hipMemsetAsync(deg, 0, 400000, stream);

    setup_kernel<<<SETUP_W + SETUP_CNT + SETUP_SEC, blk, 0, stream>>>(
        W1, Wq, Wk, Wv, Wo, W2, Wt, dstp, deg, sec, Wsec, bsec, secb);
    blocksum_kernel<<<NSCAN_BLK, blk, 0, stream>>>(deg, bsum);
    scanfin2_kernel<<<NSCAN_BLK, blk, 0, stream>>>(deg, bsum, rowstart);
    fill_csr_kernel<<<egrid, blk, 0, stream>>>(srcp, dstp, rowstart, ctr, epair);

    gemm_hqkv_kernel<<<big_grid, dim3(512), 0, stream>>>(x, Wt, b1, bq, bk, bvp,
                                                         hb, qbu, kbu, vbu, N_NODES);

    node_attn_kernel<<<wgrid, blk, 0, stream>>>(qbu, kbu, vbu, secb, epair,
                                                rowstart, attn, aggb);

    gemm_ln12_kernel<<<big_grid, dim3(512), 0, stream>>>(aggb, Wt + 65536, bo, b2, hb,
                                                         g1, be1, g2, be2, outp, N_NODES);
}

// Round 10
// 194.864 us; speedup vs baseline: 31.6290x; 1.1118x over previous
//
#include <hip/hip_runtime.h>
#include <hip/hip_bf16.h>
#include <hip/hip_fp16.h>
#include <math.h>

#define N_NODES 50000
#define N_EDGES 800000
#define DIM 128
#define NHEAD 8
#define DHEAD 16
#define SDIM 10
#define NSCAN_BLK 196   // ceil(N_NODES/256)
#define SETUP_W 48      // weight-prep blocks (6 matrices x 8 slices)
#define SETUP_CNT 3125  // count_deg blocks
#define SETUP_SEC 1563  // secbias blocks
#define HQKV_GRID 391   // (N_NODES+127)/128
#define FILL_GRID 1563  // ceil(N_EDGES/512)

typedef __attribute__((ext_vector_type(8))) short bf16x8;
typedef __attribute__((ext_vector_type(4))) float f32x4;
typedef _Float16 h16x2 __attribute__((ext_vector_type(2)));

#if __has_builtin(__builtin_amdgcn_fdot2)
#define HAVE_FDOT2 1
#else
#define HAVE_FDOT2 0
#endif

__device__ __forceinline__ float bf2f(unsigned short u) {
    return __uint_as_float(((unsigned)u) << 16);
}
__device__ __forceinline__ unsigned short f2bf(float f) {
    unsigned u = __float_as_uint(f);
    return (unsigned short)((u + 0x7FFFu + ((u >> 16) & 1u)) >> 16);
}
__device__ __forceinline__ unsigned short f2h(float f) {
    __half h = __float2half(f);
    return *reinterpret_cast<unsigned short*>(&h);
}
__device__ __forceinline__ float h2f(unsigned short u) {
    __half h = *reinterpret_cast<__half*>(&u);
    return __half2float(h);
}

union frag16 { bf16x8 v[2]; h16x2 h[8]; unsigned short u[16]; };

// ===== setup: weight prep (48 blks) + count_deg (3125 blks) + secbias =======
// deg/ctr are pre-zeroed by hipMemsetAsync before this kernel.
__global__ __launch_bounds__(256) void setup_kernel(
    const float* __restrict__ W1, const float* __restrict__ Wq,
    const float* __restrict__ Wk, const float* __restrict__ Wv,
    const float* __restrict__ Wo, const float* __restrict__ W2,
    unsigned short* __restrict__ Wt, const int* __restrict__ dst,
    int* __restrict__ deg, const float* __restrict__ sec,
    const float* __restrict__ Wsec, const float* __restrict__ bsec,
    float* __restrict__ secb) {
    const int b = blockIdx.x, t = threadIdx.x;
    if (b < SETUP_W) {
        const int mtx = b >> 3, slice = b & 7;
        const float* W = (mtx == 0) ? W1 : (mtx == 1) ? Wq : (mtx == 2) ? Wk :
                         (mtx == 3) ? Wv : (mtx == 4) ? Wo : W2;
        unsigned short* o = Wt + mtx * 16384;
#pragma unroll
        for (int i = 0; i < 8; ++i) {
            int idx = slice * 2048 + t + 256 * i;   // k-major element index
            int k = idx >> 7, n = idx & 127;
            o[n * 128 + k] = f2bf(W[idx]);
        }
    } else if (b < SETUP_W + SETUP_CNT) {           // count_deg
        int e = (b - SETUP_W) * 256 + t;
        if (e < N_EDGES) atomicAdd(&deg[dst[e]], 1);
    } else {                                        // secbias
        int idx = (b - SETUP_W - SETUP_CNT) * 256 + t;
        if (idx < N_NODES * NHEAD) {
            int n = idx >> 3, h = idx & 7;
            float acc = bsec[h];
#pragma unroll
            for (int j = 0; j < SDIM; ++j)
                acc = fmaf(sec[n * SDIM + j], Wsec[j * NHEAD + h], acc);
            secb[idx] = acc;
        }
    }
}

__global__ __launch_bounds__(256) void blocksum_kernel(const int* __restrict__ deg,
                                                       int* __restrict__ bsum) {
    const int t = threadIdx.x;
    int idx = blockIdx.x * 256 + t;
    int v = (idx < N_NODES) ? deg[idx] : 0;
#pragma unroll
    for (int m = 32; m; m >>= 1) v += __shfl_xor(v, m);
    __shared__ int ws[4];
    if ((t & 63) == 0) ws[t >> 6] = v;
    __syncthreads();
    if (t == 0) bsum[blockIdx.x] = ws[0] + ws[1] + ws[2] + ws[3];
}

// per-block: compute own exclusive offset from bsum, then in-block scan
__global__ __launch_bounds__(256) void scanfin2_kernel(const int* __restrict__ deg,
                                                       const int* __restrict__ bsum,
                                                       int* __restrict__ rowstart) {
    const int t = threadIdx.x, b = blockIdx.x;
    int v0 = (t < b) ? bsum[t] : 0;     // b <= 195 < 256, t<b implies valid
#pragma unroll
    for (int m = 32; m; m >>= 1) v0 += __shfl_xor(v0, m);
    __shared__ int ws[4];
    if ((t & 63) == 0) ws[t >> 6] = v0;
    __syncthreads();
    const int bexc = ws[0] + ws[1] + ws[2] + ws[3];

    int idx = b * 256 + t;
    int v = (idx < N_NODES) ? deg[idx] : 0;
    __shared__ int s[256];
    __syncthreads();
    s[t] = v;
    __syncthreads();
#pragma unroll
    for (int off = 1; off < 256; off <<= 1) {
        int x = (t >= off) ? s[t - off] : 0;
        __syncthreads();
        s[t] += x;
        __syncthreads();
    }
    if (idx < N_NODES) rowstart[idx] = bexc + s[t] - v;
    if (b == 0 && t == 0) rowstart[N_NODES] = N_EDGES;
}

// ===== fused: blocks 0..HQKV_GRID-1 = h+q/k/v GEMM; rest = CSR fill =======
// (independent work co-scheduled: latency-bound scatter hides under GEMM)
// q,k stored as f16; v,h as bf16.
__global__ __launch_bounds__(512) void fill_hqkv_kernel(
    const int* __restrict__ src, const int* __restrict__ dst,
    const int* __restrict__ rowstart, int* __restrict__ ctr,
    int2* __restrict__ epair,
    const float* __restrict__ X, const unsigned short* __restrict__ Wt,
    const float* __restrict__ b1, const float* __restrict__ bq,
    const float* __restrict__ bk, const float* __restrict__ bv,
    unsigned short* __restrict__ hb, unsigned short* __restrict__ qo,
    unsigned short* __restrict__ ko, unsigned short* __restrict__ vo, int nrows) {
    __shared__ alignas(16) unsigned char Wl[32768];
    __shared__ alignas(16) unsigned char Ht[32768];   // 8 waves x 16 rows x 256B
    const int t = threadIdx.x;

    if (blockIdx.x >= HQKV_GRID) {
        // ---------------- CSR fill ----------------
        int e = (blockIdx.x - HQKV_GRID) * 512 + t;
        if (e < N_EDGES) {
            int d = dst[e];
            int pos = atomicAdd(&ctr[d], 1);
            epair[rowstart[d] + pos] = make_int2(src[e], e);
        }
        return;
    }

    // ---------------- h + q/k/v GEMM ----------------
    const int l = t & 63, wave = t >> 6;
    const int l15 = l & 15, lg = l >> 4;
    const int r0 = blockIdx.x * 128 + wave * 16;
    const int arow = r0 + l15;
    const bool aok = arow < nrows;
    const int orow0 = r0 + lg * 4;
    unsigned char* HtW = Ht + wave * 4096;

    // stage W1
#pragma unroll
    for (int i = 0; i < 4; ++i) {
        int c = t + 512 * i;            // 2048 16B chunks
        int n = c >> 4, s = c & 15;
        bf16x8 val = *(const bf16x8*)(Wt + c * 8);
        *(bf16x8*)(Wl + n * 256 + ((s * 16) ^ ((n & 7) << 4))) = val;
    }
    // x f32 -> bf16 A-frags
    bf16x8 af[4];
#pragma unroll
    for (int k0 = 0; k0 < 4; ++k0) {
        float4 a0 = {0.f, 0.f, 0.f, 0.f}, a1 = {0.f, 0.f, 0.f, 0.f};
        if (aok) {
            const float4* ap = (const float4*)(X + (size_t)arow * DIM + k0 * 32 + lg * 8);
            a0 = ap[0]; a1 = ap[1];
        }
        bf16x8 f;
        f[0] = (short)f2bf(a0.x); f[1] = (short)f2bf(a0.y);
        f[2] = (short)f2bf(a0.z); f[3] = (short)f2bf(a0.w);
        f[4] = (short)f2bf(a1.x); f[5] = (short)f2bf(a1.y);
        f[6] = (short)f2bf(a1.z); f[7] = (short)f2bf(a1.w);
        af[k0] = f;
    }
    __syncthreads();

    {
        f32x4 acc[8];
#pragma unroll
        for (int n = 0; n < 8; ++n) acc[n] = (f32x4){0.f, 0.f, 0.f, 0.f};
#pragma unroll
        for (int k0 = 0; k0 < 4; ++k0) {
#pragma unroll
            for (int n = 0; n < 8; ++n) {
                int row = n * 16 + l15;
                int kb = (k0 * 64 + lg * 16) ^ ((row & 7) << 4);
                bf16x8 bfr = *(bf16x8*)(Wl + row * 256 + kb);
                acc[n] = __builtin_amdgcn_mfma_f32_16x16x32_bf16(af[k0], bfr, acc[n], 0, 0, 0);
            }
        }
        // epilogue: h = relu(acc + b1) -> hb + Ht (swizzled)
#pragma unroll
        for (int n = 0; n < 8; ++n) {
            int col = n * 16 + l15;
            float bvv = b1[col];
#pragma unroll
            for (int i = 0; i < 4; ++i) {
                int rloc = lg * 4 + i;
                unsigned short hv = f2bf(fmaxf(acc[n][i] + bvv, 0.f));
                if (orow0 + i < nrows) hb[(size_t)(orow0 + i) * DIM + col] = hv;
                *(unsigned short*)(HtW + ((rloc * 256 + col * 2) ^ ((rloc & 7) << 4))) = hv;
            }
        }
    }
    __syncthreads();   // W1 reads + Ht writes complete

    // A-frags of h from Ht
    bf16x8 af2[4];
#pragma unroll
    for (int k0 = 0; k0 < 4; ++k0)
        af2[k0] = *(const bf16x8*)(HtW + ((l15 * 256 + k0 * 64 + lg * 16) ^ ((l15 & 7) << 4)));

    for (int m = 0; m < 3; ++m) {
        const unsigned short* wsrc = (m == 0) ? Wt + 16384 : (m == 1) ? Wt + 32768 : Wt + 49152;
        const float* bias = (m == 0) ? bq : (m == 1) ? bk : bv;
        unsigned short* outp = (m == 0) ? qo : (m == 1) ? ko : vo;
#pragma unroll
        for (int i = 0; i < 4; ++i) {
            int c = t + 512 * i;
            int n = c >> 4, s = c & 15;
            bf16x8 val = *(const bf16x8*)(wsrc + c * 8);
            *(bf16x8*)(Wl + n * 256 + ((s * 16) ^ ((n & 7) << 4))) = val;
        }
        __syncthreads();
        f32x4 acc[8];
#pragma unroll
        for (int n = 0; n < 8; ++n) acc[n] = (f32x4){0.f, 0.f, 0.f, 0.f};
#pragma unroll
        for (int k0 = 0; k0 < 4; ++k0) {
#pragma unroll
            for (int n = 0; n < 8; ++n) {
                int row = n * 16 + l15;
                int kb = (k0 * 64 + lg * 16) ^ ((row & 7) << 4);
                bf16x8 bfr = *(bf16x8*)(Wl + row * 256 + kb);
                acc[n] = __builtin_amdgcn_mfma_f32_16x16x32_bf16(af2[k0], bfr, acc[n], 0, 0, 0);
            }
        }
#pragma unroll
        for (int n = 0; n < 8; ++n) {
            int col = n * 16 + l15;
            float bvv = bias[col];
#pragma unroll
            for (int i = 0; i < 4; ++i) {
                int r = orow0 + i;
                if (r < nrows) {
                    float val = acc[n][i] + bvv;
                    // q,k as f16 (fdot2 operands); v as bf16
                    outp[(size_t)r * DIM + col] = (m < 2) ? f2h(val) : f2bf(val);
                }
            }
        }
        __syncthreads();   // before next restage
    }
}

// score dot: q,k are f16 rows (16 elems) held in frag16 unions
__device__ __forceinline__ float score_dot(const frag16& q, const frag16& k) {
#if HAVE_FDOT2
    float a0 = 0.f, a1 = 0.f;
#pragma unroll
    for (int i = 0; i < 4; ++i) {
        a0 = __builtin_amdgcn_fdot2(q.h[2 * i], k.h[2 * i], a0, false);
        a1 = __builtin_amdgcn_fdot2(q.h[2 * i + 1], k.h[2 * i + 1], a1, false);
    }
    return a0 + a1;
#else
    float acc = 0.f;
#pragma unroll
    for (int i = 0; i < 16; ++i) acc = fmaf(h2f(q.u[i]), h2f(k.u[i]), acc);
    return acc;
#endif
}

// ===== fused scores + softmax + aggregation (wave per dst node) ============
__global__ __launch_bounds__(256) void node_attn_kernel(
    const unsigned short* __restrict__ qb, const unsigned short* __restrict__ kb,
    const unsigned short* __restrict__ vb, const float* __restrict__ secb,
    const int2* __restrict__ epair, const int* __restrict__ rowstart,
    float* __restrict__ attn_out, unsigned short* __restrict__ aggb) {
    int node = blockIdx.x * 4 + (threadIdx.x >> 6);
    if (node >= N_NODES) return;
    const int lane = threadIdx.x & 63;
    const int start = rowstart[node];
    const int deg = rowstart[node + 1] - start;
    if (deg == 0) {
        ((unsigned*)(aggb + (size_t)node * DIM))[lane] = 0u;
        return;
    }
    const int h = lane & 7;     // head (score phases)
    const int le = lane >> 3;   // edge slot 0..7
    const int hc = le;          // head (aggregation mapping)

    frag16 qf;
    {
        const bf16x8* qp = (const bf16x8*)(qb + (size_t)node * DIM + h * DHEAD);
        qf.v[0] = qp[0]; qf.v[1] = qp[1];
    }

    if (deg <= 64) {
        // ---------- fast path: coalesced int2 preload + register scores ----
        int sall = 0, eall = 0;
        if (lane < deg) {
            int2 p = epair[start + lane];
            sall = p.x;
            eall = p.y;
        }
        float sc[8];
        float m = -INFINITY;
#pragma unroll
        for (int t = 0; t < 8; ++t) {
            sc[t] = -INFINITY;
            if (t * 8 < deg) {                       // wave-uniform
                int jj = t * 8 + le;
                bool valid = jj < deg;
                int s = __shfl(sall, valid ? jj : deg - 1);
                const bf16x8* kp = (const bf16x8*)(kb + (size_t)s * DIM + h * DHEAD);
                frag16 kf;
                kf.v[0] = kp[0]; kf.v[1] = kp[1];
                float acc = score_dot(qf, kf);
                if (valid) sc[t] = acc * 0.25f + secb[s * NHEAD + h];
            }
            m = fmaxf(m, sc[t]);
        }
        m = fmaxf(m, __shfl_xor(m, 8));
        m = fmaxf(m, __shfl_xor(m, 16));
        m = fmaxf(m, __shfl_xor(m, 32));

        float ev[8];
        float ssum = 0.f;
#pragma unroll
        for (int t = 0; t < 8; ++t) {
            ev[t] = (t * 8 + le < deg) ? __expf(sc[t] - m) : 0.f;
            ssum += ev[t];
        }
        ssum += __shfl_xor(ssum, 8);
        ssum += __shfl_xor(ssum, 16);
        ssum += __shfl_xor(ssum, 32);
        const float rinv = 1.f / (ssum + 1e-9f);     // head (lane&7)

        float2 acc2 = {0.f, 0.f};
#pragma unroll
        for (int t = 0; t < 8; ++t) {
            if (t * 8 < deg) {                       // wave-uniform
#pragma unroll
                for (int le2 = 0; le2 < 8; ++le2) {
                    int jj = t * 8 + le2;            // uniform
                    int s = __shfl(sall, (jj < deg) ? jj : deg - 1);  // uniform
                    float evd = __shfl(ev[t], le2 * 8 + hc);
                    unsigned vv = ((const unsigned*)(vb + (size_t)s * DIM))[lane];
                    acc2.x = fmaf(evd, bf2f((unsigned short)(vv & 0xFFFFu)), acc2.x);
                    acc2.y = fmaf(evd, bf2f((unsigned short)(vv >> 16)), acc2.y);
                }
            }
        }
        const float rinv_c = __shfl(rinv, hc);       // head (lane>>3)
        unsigned short o0 = f2bf(acc2.x * rinv_c);
        unsigned short o1 = f2bf(acc2.y * rinv_c);
        ((unsigned*)(aggb + (size_t)node * DIM))[lane] =
            (unsigned)o0 | ((unsigned)o1 << 16);

        // attn write: shfl hoisted OUT of the divergent guard (EXEC-safe)
#pragma unroll
        for (int t = 0; t < 8; ++t) {
            int jj = t * 8 + le;
            int e = __shfl(eall, (jj < deg) ? jj : 0);   // all lanes execute
            if (jj < deg) attn_out[(size_t)e * NHEAD + h] = ev[t] * rinv;
        }
        return;
    }

    // ---------- slow path (deg > 64): memory-staged, always correct ----------
    float m = -INFINITY;
    for (int j = 0; j < deg; j += 8) {
        int jj = j + le;
        float sc = -INFINITY;
        if (jj < deg) {
            int2 p = epair[start + jj];
            int s = p.x;
            const bf16x8* kp = (const bf16x8*)(kb + (size_t)s * DIM + h * DHEAD);
            frag16 kf;
            kf.v[0] = kp[0]; kf.v[1] = kp[1];
            float acc = score_dot(qf, kf);
            sc = acc * 0.25f + secb[s * NHEAD + h];
            attn_out[(size_t)p.y * NHEAD + h] = sc;
        }
        m = fmaxf(m, sc);
    }
    m = fmaxf(m, __shfl_xor(m, 8));
    m = fmaxf(m, __shfl_xor(m, 16));
    m = fmaxf(m, __shfl_xor(m, 32));

    float ssum = 0.f;
    float2 acc2 = {0.f, 0.f};
    for (int j = 0; j < deg; j += 8) {
        int jj = j + le;
        float ev = 0.f;
        if (jj < deg) {
            int e = epair[start + jj].y;
            ev = __expf(attn_out[(size_t)e * NHEAD + h] - m);
        }
        ssum += ev;
        int lim = deg - j; if (lim > 8) lim = 8;
        for (int le2 = 0; le2 < lim; ++le2) {
            float evd = __shfl(ev, le2 * 8 + hc);
            int s = epair[start + j + le2].x;
            unsigned vv = ((const unsigned*)(vb + (size_t)s * DIM))[lane];
            acc2.x = fmaf(evd, bf2f((unsigned short)(vv & 0xFFFFu)), acc2.x);
            acc2.y = fmaf(evd, bf2f((unsigned short)(vv >> 16)), acc2.y);
        }
    }
    ssum += __shfl_xor(ssum, 8);
    ssum += __shfl_xor(ssum, 16);
    ssum += __shfl_xor(ssum, 32);
    const float rinv = 1.f / (ssum + 1e-9f);
    const float rinv_c = __shfl(rinv, hc);

    unsigned short o0 = f2bf(acc2.x * rinv_c);
    unsigned short o1 = f2bf(acc2.y * rinv_c);
    ((unsigned*)(aggb + (size_t)node * DIM))[lane] =
        (unsigned)o0 | ((unsigned)o1 << 16);

    for (int j = 0; j < deg; j += 8) {
        int jj = j + le;
        if (jj < deg) {
            int e = epair[start + jj].y;
            float sc = attn_out[(size_t)e * NHEAD + h];
            attn_out[(size_t)e * NHEAD + h] = __expf(sc - m) * rinv;
        }
    }
}

// ===== fused double GEMM+LN: out = LN2(mid + relu(mid@W2+b2)),
//       mid = LN1(hb + agg@Wo+bo); midb never hits global. 512 thr/128 rows.
__global__ __launch_bounds__(512) void gemm_ln12_kernel(
    const unsigned short* __restrict__ A,      // aggb
    const unsigned short* __restrict__ Wt,     // Wo @ +0, W2 @ +16384
    const float* __restrict__ bo, const float* __restrict__ b2,
    const unsigned short* __restrict__ resid,  // hb
    const float* __restrict__ g1, const float* __restrict__ be1,
    const float* __restrict__ g2, const float* __restrict__ be2,
    float* __restrict__ outp, int nrows) {
    __shared__ alignas(16) unsigned char Wl[32768];
    __shared__ alignas(16) unsigned char Mt[32768];
    const int t = threadIdx.x;
    const int l = t & 63, wave = t >> 6;
    const int l15 = l & 15, lg = l >> 4;
    const int r0 = blockIdx.x * 128 + wave * 16;
    const int arow = r0 + l15;
    const bool aok = arow < nrows;
    const int orow0 = r0 + lg * 4;
    unsigned char* MtW = Mt + wave * 4096;

    // stage Wo
#pragma unroll
    for (int i = 0; i < 4; ++i) {
        int c = t + 512 * i;
        int n = c >> 4, s = c & 15;
        bf16x8 val = *(const bf16x8*)(Wt + c * 8);
        *(bf16x8*)(Wl + n * 256 + ((s * 16) ^ ((n & 7) << 4))) = val;
    }
    bf16x8 af[4];
#pragma unroll
    for (int k0 = 0; k0 < 4; ++k0) {
        bf16x8 z = (bf16x8){0, 0, 0, 0, 0, 0, 0, 0};
        af[k0] = aok ? *(const bf16x8*)(A + (size_t)arow * DIM + k0 * 32 + lg * 8) : z;
    }
    __syncthreads();

    float mid[8][4];    // bf16-rounded mid values, kept for LN2 residual
    {
        f32x4 acc[8];
#pragma unroll
        for (int n = 0; n < 8; ++n) acc[n] = (f32x4){0.f, 0.f, 0.f, 0.f};
#pragma unroll
        for (int k0 = 0; k0 < 4; ++k0) {
#pragma unroll
            for (int n = 0; n < 8; ++n) {
                int row = n * 16 + l15;
                int kb = (k0 * 64 + lg * 16) ^ ((row & 7) << 4);
                bf16x8 bfr = *(bf16x8*)(Wl + row * 256 + kb);
                acc[n] = __builtin_amdgcn_mfma_f32_16x16x32_bf16(af[k0], bfr, acc[n], 0, 0, 0);
            }
        }
        float bv[8], gv[8], bev[8];
#pragma unroll
        for (int n = 0; n < 8; ++n) {
            int col = n * 16 + l15;
            bv[n] = bo[col]; gv[n] = g1[col]; bev[n] = be1[col];
        }
#pragma unroll
        for (int i = 0; i < 4; ++i) {
            int r = orow0 + i;
            int rloc = lg * 4 + i;
            float xv[8];
            float s = 0.f;
            if (r < nrows) {
#pragma unroll
                for (int n = 0; n < 8; ++n) {
                    float val = acc[n][i] + bv[n]
                              + bf2f(resid[(size_t)r * DIM + n * 16 + l15]);
                    xv[n] = val;
                    s += val;
                }
            } else {
#pragma unroll
                for (int n = 0; n < 8; ++n) xv[n] = 0.f;
            }
            s += __shfl_xor(s, 1); s += __shfl_xor(s, 2);
            s += __shfl_xor(s, 4); s += __shfl_xor(s, 8);
            float mean = s * (1.f / 128.f);
            float var = 0.f;
#pragma unroll
            for (int n = 0; n < 8; ++n) {
                float d = xv[n] - mean;
                var += d * d;
            }
            var += __shfl_xor(var, 1); var += __shfl_xor(var, 2);
            var += __shfl_xor(var, 4); var += __shfl_xor(var, 8);
            float rstd = rsqrtf(var * (1.f / 128.f) + 1e-5f);
#pragma unroll
            for (int n = 0; n < 8; ++n) {
                int col = n * 16 + l15;
                unsigned short mb = f2bf((xv[n] - mean) * rstd * gv[n] + bev[n]);
                mid[n][i] = bf2f(mb);
                *(unsigned short*)(MtW + ((rloc * 256 + col * 2) ^ ((rloc & 7) << 4))) = mb;
            }
        }
    }
    __syncthreads();   // Wo reads + Mt writes complete

    bf16x8 af2[4];
#pragma unroll
    for (int k0 = 0; k0 < 4; ++k0)
        af2[k0] = *(const bf16x8*)(MtW + ((l15 * 256 + k0 * 64 + lg * 16) ^ ((l15 & 7) << 4)));

    // stage W2
#pragma unroll
    for (int i = 0; i < 4; ++i) {
        int c = t + 512 * i;
        int n = c >> 4, s = c & 15;
        bf16x8 val = *(const bf16x8*)(Wt + 16384 + c * 8);
        *(bf16x8*)(Wl + n * 256 + ((s * 16) ^ ((n & 7) << 4))) = val;
    }
    __syncthreads();

    {
        f32x4 acc[8];
#pragma unroll
        for (int n = 0; n < 8; ++n) acc[n] = (f32x4){0.f, 0.f, 0.f, 0.f};
#pragma unroll
        for (int k0 = 0; k0 < 4; ++k0) {
#pragma unroll
            for (int n = 0; n < 8; ++n) {
                int row = n * 16 + l15;
                int kb = (k0 * 64 + lg * 16) ^ ((row & 7) << 4);
                bf16x8 bfr = *(bf16x8*)(Wl + row * 256 + kb);
                acc[n] = __builtin_amdgcn_mfma_f32_16x16x32_bf16(af2[k0], bfr, acc[n], 0, 0, 0);
            }
        }
        float bv[8], gv[8], bev[8];
#pragma unroll
        for (int n = 0; n < 8; ++n) {
            int col = n * 16 + l15;
            bv[n] = b2[col]; gv[n] = g2[col]; bev[n] = be2[col];
        }
#pragma unroll
        for (int i = 0; i < 4; ++i) {
            int r = orow0 + i;
            float xv[8];
            float s = 0.f;
#pragma unroll
            for (int n = 0; n < 8; ++n) {
                float val = fmaxf(acc[n][i] + bv[n], 0.f) + mid[n][i];
                xv[n] = val;
                s += val;
            }
            s += __shfl_xor(s, 1); s += __shfl_xor(s, 2);
            s += __shfl_xor(s, 4); s += __shfl_xor(s, 8);
            float mean = s * (1.f / 128.f);
            float var = 0.f;
#pragma unroll
            for (int n = 0; n < 8; ++n) {
                float d = xv[n] - mean;
                var += d * d;
            }
            var += __shfl_xor(var, 1); var += __shfl_xor(var, 2);
            var += __shfl_xor(var, 4); var += __shfl_xor(var, 8);
            float rstd = rsqrtf(var * (1.f / 128.f) + 1e-5f);
            if (r < nrows) {
#pragma unroll
                for (int n = 0; n < 8; ++n) {
                    int col = n * 16 + l15;
                    outp[(size_t)r * DIM + col] = (xv[n] - mean) * rstd * gv[n] + bev[n];
                }
            }
        }
    }
}

extern "C" void kernel_launch(void* const* d_in, const int* in_sizes, int n_in,
                              void* d_out, int out_size, void* d_ws, size_t ws_size,
                              hipStream_t stream) {
    const float* x    = (const float*)d_in[0];
    const int*   ei   = (const int*)d_in[1];
    const float* sec  = (const float*)d_in[2];
    const float* W1   = (const float*)d_in[3];
    const float* b1   = (const float*)d_in[4];
    const float* W2   = (const float*)d_in[5];
    const float* b2   = (const float*)d_in[6];
    const float* Wq   = (const float*)d_in[7];
    const float* bq   = (const float*)d_in[8];
    const float* Wk   = (const float*)d_in[9];
    const float* bk   = (const float*)d_in[10];
    const float* Wv   = (const float*)d_in[11];
    const float* bvp  = (const float*)d_in[12];
    const float* Wsec = (const float*)d_in[13];
    const float* bsec = (const float*)d_in[14];
    const float* Wo   = (const float*)d_in[15];
    const float* bo   = (const float*)d_in[16];
    const float* g1   = (const float*)d_in[17];
    const float* be1  = (const float*)d_in[18];
    const float* g2   = (const float*)d_in[19];
    const float* be2  = (const float*)d_in[20];

    const int* srcp = ei;             // edge_index[0]
    const int* dstp = ei + N_EDGES;   // edge_index[1]

    char* wsb = (char*)d_ws;
    unsigned short* hb   = (unsigned short*)(wsb);              // 12.8MB
    unsigned short* qbu  = (unsigned short*)(wsb + 12800000);   // f16
    unsigned short* kbu  = (unsigned short*)(wsb + 25600000);   // f16
    unsigned short* vbu  = (unsigned short*)(wsb + 38400000);   // bf16
    unsigned short* aggb = (unsigned short*)(wsb + 51200000);
    float* secb          = (float*)(wsb + 76800000);            // 1.6MB
    unsigned short* Wt   = (unsigned short*)(wsb + 78400000);   // 192KB
    int* deg             = (int*)(wsb + 78600000);              // 200KB
    int* ctr             = (int*)(wsb + 78800000);              // 200KB
    int* rowstart        = (int*)(wsb + 79000000);              // 200KB+4
    int2* epair          = (int2*)(wsb + 79200256);             // 6.4MB
    int* bsum            = (int*)(wsb + 85600512);              // 784B

    float* outp = (float*)d_out;                 // [N,128]
    float* attn = outp + (size_t)N_NODES * DIM;  // [E,8]

    dim3 blk(256);
    const int wgrid = (N_NODES + 3) / 4;             // 12500

    // zero deg+ctr (adjacent 400KB) — graph-capturable async memset
    hipMemsetAsync(deg, 0, 400000, stream);

    setup_kernel<<<SETUP_W + SETUP_CNT + SETUP_SEC, blk, 0, stream>>>(
        W1, Wq, Wk, Wv, Wo, W2, Wt, dstp, deg, sec, Wsec, bsec, secb);
    blocksum_kernel<<<NSCAN_BLK, blk, 0, stream>>>(deg, bsum);
    scanfin2_kernel<<<NSCAN_BLK, blk, 0, stream>>>(deg, bsum, rowstart);

    fill_hqkv_kernel<<<HQKV_GRID + FILL_GRID, dim3(512), 0, stream>>>(
        srcp, dstp, rowstart, ctr, epair,
        x, Wt, b1, bq, bk, bvp, hb, qbu, kbu, vbu, N_NODES);

    node_attn_kernel<<<wgrid, blk, 0, stream>>>(qbu, kbu, vbu, secb, epair,
                                                rowstart, attn, aggb);

    gemm_ln12_kernel<<<HQKV_GRID, dim3(512), 0, stream>>>(aggb, Wt + 65536, bo, b2, hb,
                                                          g1, be1, g2, be2, outp, N_NODES);
}

// Round 11
// 184.281 us; speedup vs baseline: 33.4455x; 1.0574x over previous
//
#include <hip/hip_runtime.h>
#include <hip/hip_bf16.h>
#include <hip/hip_fp16.h>
#include <math.h>

#define N_NODES 50000
#define N_EDGES 800000
#define DIM 128
#define NHEAD 8
#define DHEAD 16
#define SDIM 10
#define NSCAN_BLK 196   // ceil(N_NODES/256)
#define SETUP_W 48      // weight-prep blocks (6 matrices x 8 slices)
#define SETUP_CNT 3125  // count_deg blocks
#define SETUP_SEC 1563  // secbias blocks
#define HQKV_GRID 391   // (N_NODES+127)/128
#define FILL_GRID 1563  // ceil(N_EDGES/512)

typedef __attribute__((ext_vector_type(8))) short bf16x8;
typedef __attribute__((ext_vector_type(4))) float f32x4;
typedef float f32x2 __attribute__((ext_vector_type(2)));

#if __has_builtin(__builtin_amdgcn_cvt_pk_f32_fp8)
#define HAVE_FP8_DEC 1
#else
#define HAVE_FP8_DEC 0
#endif
#if __has_builtin(__builtin_amdgcn_cvt_pk_fp8_f32)
#define HAVE_FP8_ENC 1
#else
#define HAVE_FP8_ENC 0
#endif

__device__ __forceinline__ float bf2f(unsigned short u) {
    return __uint_as_float(((unsigned)u) << 16);
}
__device__ __forceinline__ unsigned short f2bf(float f) {
    unsigned u = __float_as_uint(f);
    return (unsigned short)((u + 0x7FFFu + ((u >> 16) & 1u)) >> 16);
}

// ---- fp8 e4m3fn helpers (HW cvt when available; exact manual fallback) ----
__device__ __forceinline__ float fp8dec1(unsigned b) {
    // e4m3 bits -> f16 bits (exp +8 handled by *256); exact incl. subnormals
    unsigned short hb = (unsigned short)(((b & 0x80u) << 8) | ((b & 0x7Fu) << 7));
    __half hh = *reinterpret_cast<__half*>(&hb);
    return __half2float(hh) * 256.f;
}
template <bool HI>
__device__ __forceinline__ f32x2 dec2fp8(unsigned w) {
#if HAVE_FP8_DEC
    return __builtin_amdgcn_cvt_pk_f32_fp8((int)w, HI);
#else
    unsigned b0 = HI ? ((w >> 16) & 0xFFu) : (w & 0xFFu);
    unsigned b1 = HI ? (w >> 24) : ((w >> 8) & 0xFFu);
    f32x2 r; r.x = fp8dec1(b0); r.y = fp8dec1(b1); return r;
#endif
}
__device__ __forceinline__ unsigned char f2fp8(float f) {
#if HAVE_FP8_ENC
    return (unsigned char)(__builtin_amdgcn_cvt_pk_fp8_f32(f, f, 0, false) & 0xFF);
#else
    unsigned u = __float_as_uint(f);
    unsigned s = (u >> 24) & 0x80u;
    float a = fabsf(f);
    if (a >= 464.f) return (unsigned char)(s | 0x7E);     // clamp to 448
    if (a < 0.015625f) {                                  // subnormal: q/512
        int q = (int)rintf(a * 512.f);
        return (unsigned char)(s | (unsigned)q);
    }
    int e = (int)((u >> 23) & 0xFF) - 127;
    unsigned man = u & 0x7FFFFFu;
    unsigned keep = man >> 20, rest = man & 0xFFFFFu;
    if (rest > 0x80000u || (rest == 0x80000u && (keep & 1u))) {
        if (++keep == 8u) { keep = 0u; ++e; if (e > 8) return (unsigned char)(s | 0x7E); }
    }
    return (unsigned char)(s | ((unsigned)(e + 7) << 3) | keep);
#endif
}

// ===== setup: weight prep (48 blks) + count_deg (3125 blks) + secbias =======
// deg/ctr are pre-zeroed by hipMemsetAsync before this kernel.
__global__ __launch_bounds__(256) void setup_kernel(
    const float* __restrict__ W1, const float* __restrict__ Wq,
    const float* __restrict__ Wk, const float* __restrict__ Wv,
    const float* __restrict__ Wo, const float* __restrict__ W2,
    unsigned short* __restrict__ Wt, const int* __restrict__ dst,
    int* __restrict__ deg, const float* __restrict__ sec,
    const float* __restrict__ Wsec, const float* __restrict__ bsec,
    float* __restrict__ secb) {
    const int b = blockIdx.x, t = threadIdx.x;
    if (b < SETUP_W) {
        const int mtx = b >> 3, slice = b & 7;
        const float* W = (mtx == 0) ? W1 : (mtx == 1) ? Wq : (mtx == 2) ? Wk :
                         (mtx == 3) ? Wv : (mtx == 4) ? Wo : W2;
        unsigned short* o = Wt + mtx * 16384;
#pragma unroll
        for (int i = 0; i < 8; ++i) {
            int idx = slice * 2048 + t + 256 * i;   // k-major element index
            int k = idx >> 7, n = idx & 127;
            o[n * 128 + k] = f2bf(W[idx]);
        }
    } else if (b < SETUP_W + SETUP_CNT) {           // count_deg
        int e = (b - SETUP_W) * 256 + t;
        if (e < N_EDGES) atomicAdd(&deg[dst[e]], 1);
    } else {                                        // secbias
        int idx = (b - SETUP_W - SETUP_CNT) * 256 + t;
        if (idx < N_NODES * NHEAD) {
            int n = idx >> 3, h = idx & 7;
            float acc = bsec[h];
#pragma unroll
            for (int j = 0; j < SDIM; ++j)
                acc = fmaf(sec[n * SDIM + j], Wsec[j * NHEAD + h], acc);
            secb[idx] = acc;
        }
    }
}

__global__ __launch_bounds__(256) void blocksum_kernel(const int* __restrict__ deg,
                                                       int* __restrict__ bsum) {
    const int t = threadIdx.x;
    int idx = blockIdx.x * 256 + t;
    int v = (idx < N_NODES) ? deg[idx] : 0;
#pragma unroll
    for (int m = 32; m; m >>= 1) v += __shfl_xor(v, m);
    __shared__ int ws[4];
    if ((t & 63) == 0) ws[t >> 6] = v;
    __syncthreads();
    if (t == 0) bsum[blockIdx.x] = ws[0] + ws[1] + ws[2] + ws[3];
}

// per-block: compute own exclusive offset from bsum, then in-block scan
__global__ __launch_bounds__(256) void scanfin2_kernel(const int* __restrict__ deg,
                                                       const int* __restrict__ bsum,
                                                       int* __restrict__ rowstart) {
    const int t = threadIdx.x, b = blockIdx.x;
    int v0 = (t < b) ? bsum[t] : 0;     // b <= 195 < 256, t<b implies valid
#pragma unroll
    for (int m = 32; m; m >>= 1) v0 += __shfl_xor(v0, m);
    __shared__ int ws[4];
    if ((t & 63) == 0) ws[t >> 6] = v0;
    __syncthreads();
    const int bexc = ws[0] + ws[1] + ws[2] + ws[3];

    int idx = b * 256 + t;
    int v = (idx < N_NODES) ? deg[idx] : 0;
    __shared__ int s[256];
    __syncthreads();
    s[t] = v;
    __syncthreads();
#pragma unroll
    for (int off = 1; off < 256; off <<= 1) {
        int x = (t >= off) ? s[t - off] : 0;
        __syncthreads();
        s[t] += x;
        __syncthreads();
    }
    if (idx < N_NODES) rowstart[idx] = bexc + s[t] - v;
    if (b == 0 && t == 0) rowstart[N_NODES] = N_EDGES;
}

// ===== fused: blocks 0..HQKV_GRID-1 = h+q/k/v GEMM; rest = CSR fill =======
// q,v,h stored bf16; k stored fp8 e4m3 (halves the score-gather bytes).
__global__ __launch_bounds__(512) void fill_hqkv_kernel(
    const int* __restrict__ src, const int* __restrict__ dst,
    const int* __restrict__ rowstart, int* __restrict__ ctr,
    int2* __restrict__ epair,
    const float* __restrict__ X, const unsigned short* __restrict__ Wt,
    const float* __restrict__ b1, const float* __restrict__ bq,
    const float* __restrict__ bk, const float* __restrict__ bv,
    unsigned short* __restrict__ hb, unsigned short* __restrict__ qo,
    unsigned char* __restrict__ ko8, unsigned short* __restrict__ vo, int nrows) {
    __shared__ alignas(16) unsigned char Wl[32768];
    __shared__ alignas(16) unsigned char Ht[32768];   // 8 waves x 16 rows x 256B
    const int t = threadIdx.x;

    if (blockIdx.x >= HQKV_GRID) {
        // ---------------- CSR fill ----------------
        int e = (blockIdx.x - HQKV_GRID) * 512 + t;
        if (e < N_EDGES) {
            int d = dst[e];
            int pos = atomicAdd(&ctr[d], 1);
            epair[rowstart[d] + pos] = make_int2(src[e], e);
        }
        return;
    }

    // ---------------- h + q/k/v GEMM ----------------
    const int l = t & 63, wave = t >> 6;
    const int l15 = l & 15, lg = l >> 4;
    const int r0 = blockIdx.x * 128 + wave * 16;
    const int arow = r0 + l15;
    const bool aok = arow < nrows;
    const int orow0 = r0 + lg * 4;
    unsigned char* HtW = Ht + wave * 4096;

    // stage W1
#pragma unroll
    for (int i = 0; i < 4; ++i) {
        int c = t + 512 * i;            // 2048 16B chunks
        int n = c >> 4, s = c & 15;
        bf16x8 val = *(const bf16x8*)(Wt + c * 8);
        *(bf16x8*)(Wl + n * 256 + ((s * 16) ^ ((n & 7) << 4))) = val;
    }
    // x f32 -> bf16 A-frags
    bf16x8 af[4];
#pragma unroll
    for (int k0 = 0; k0 < 4; ++k0) {
        float4 a0 = {0.f, 0.f, 0.f, 0.f}, a1 = {0.f, 0.f, 0.f, 0.f};
        if (aok) {
            const float4* ap = (const float4*)(X + (size_t)arow * DIM + k0 * 32 + lg * 8);
            a0 = ap[0]; a1 = ap[1];
        }
        bf16x8 f;
        f[0] = (short)f2bf(a0.x); f[1] = (short)f2bf(a0.y);
        f[2] = (short)f2bf(a0.z); f[3] = (short)f2bf(a0.w);
        f[4] = (short)f2bf(a1.x); f[5] = (short)f2bf(a1.y);
        f[6] = (short)f2bf(a1.z); f[7] = (short)f2bf(a1.w);
        af[k0] = f;
    }
    __syncthreads();

    {
        f32x4 acc[8];
#pragma unroll
        for (int n = 0; n < 8; ++n) acc[n] = (f32x4){0.f, 0.f, 0.f, 0.f};
#pragma unroll
        for (int k0 = 0; k0 < 4; ++k0) {
#pragma unroll
            for (int n = 0; n < 8; ++n) {
                int row = n * 16 + l15;
                int kb = (k0 * 64 + lg * 16) ^ ((row & 7) << 4);
                bf16x8 bfr = *(bf16x8*)(Wl + row * 256 + kb);
                acc[n] = __builtin_amdgcn_mfma_f32_16x16x32_bf16(af[k0], bfr, acc[n], 0, 0, 0);
            }
        }
        // epilogue: h = relu(acc + b1) -> hb + Ht (swizzled)
#pragma unroll
        for (int n = 0; n < 8; ++n) {
            int col = n * 16 + l15;
            float bvv = b1[col];
#pragma unroll
            for (int i = 0; i < 4; ++i) {
                int rloc = lg * 4 + i;
                unsigned short hv = f2bf(fmaxf(acc[n][i] + bvv, 0.f));
                if (orow0 + i < nrows) hb[(size_t)(orow0 + i) * DIM + col] = hv;
                *(unsigned short*)(HtW + ((rloc * 256 + col * 2) ^ ((rloc & 7) << 4))) = hv;
            }
        }
    }
    __syncthreads();   // W1 reads + Ht writes complete

    // A-frags of h from Ht
    bf16x8 af2[4];
#pragma unroll
    for (int k0 = 0; k0 < 4; ++k0)
        af2[k0] = *(const bf16x8*)(HtW + ((l15 * 256 + k0 * 64 + lg * 16) ^ ((l15 & 7) << 4)));

    for (int m = 0; m < 3; ++m) {
        const unsigned short* wsrc = (m == 0) ? Wt + 16384 : (m == 1) ? Wt + 32768 : Wt + 49152;
        const float* bias = (m == 0) ? bq : (m == 1) ? bk : bv;
#pragma unroll
        for (int i = 0; i < 4; ++i) {
            int c = t + 512 * i;
            int n = c >> 4, s = c & 15;
            bf16x8 val = *(const bf16x8*)(wsrc + c * 8);
            *(bf16x8*)(Wl + n * 256 + ((s * 16) ^ ((n & 7) << 4))) = val;
        }
        __syncthreads();
        f32x4 acc[8];
#pragma unroll
        for (int n = 0; n < 8; ++n) acc[n] = (f32x4){0.f, 0.f, 0.f, 0.f};
#pragma unroll
        for (int k0 = 0; k0 < 4; ++k0) {
#pragma unroll
            for (int n = 0; n < 8; ++n) {
                int row = n * 16 + l15;
                int kb = (k0 * 64 + lg * 16) ^ ((row & 7) << 4);
                bf16x8 bfr = *(bf16x8*)(Wl + row * 256 + kb);
                acc[n] = __builtin_amdgcn_mfma_f32_16x16x32_bf16(af2[k0], bfr, acc[n], 0, 0, 0);
            }
        }
#pragma unroll
        for (int n = 0; n < 8; ++n) {
            int col = n * 16 + l15;
            float bvv = bias[col];
#pragma unroll
            for (int i = 0; i < 4; ++i) {
                int r = orow0 + i;
                if (r < nrows) {
                    float val = acc[n][i] + bvv;
                    if (m == 0)      qo[(size_t)r * DIM + col] = f2bf(val);
                    else if (m == 1) ko8[(size_t)r * DIM + col] = f2fp8(val);
                    else             vo[(size_t)r * DIM + col] = f2bf(val);
                }
            }
        }
        __syncthreads();   // before next restage
    }
}

// fp8 k-row dot against qv[16] floats (row = 16B at kb8 + s*128 + h*16)
__device__ __forceinline__ float score_dot_fp8(const float* qv, uint4 kw) {
    float a0 = 0.f, a1 = 0.f;
    f32x2 p;
    p = dec2fp8<false>(kw.x); a0 = fmaf(qv[0],  p.x, a0); a1 = fmaf(qv[1],  p.y, a1);
    p = dec2fp8<true >(kw.x); a0 = fmaf(qv[2],  p.x, a0); a1 = fmaf(qv[3],  p.y, a1);
    p = dec2fp8<false>(kw.y); a0 = fmaf(qv[4],  p.x, a0); a1 = fmaf(qv[5],  p.y, a1);
    p = dec2fp8<true >(kw.y); a0 = fmaf(qv[6],  p.x, a0); a1 = fmaf(qv[7],  p.y, a1);
    p = dec2fp8<false>(kw.z); a0 = fmaf(qv[8],  p.x, a0); a1 = fmaf(qv[9],  p.y, a1);
    p = dec2fp8<true >(kw.z); a0 = fmaf(qv[10], p.x, a0); a1 = fmaf(qv[11], p.y, a1);
    p = dec2fp8<false>(kw.w); a0 = fmaf(qv[12], p.x, a0); a1 = fmaf(qv[13], p.y, a1);
    p = dec2fp8<true >(kw.w); a0 = fmaf(qv[14], p.x, a0); a1 = fmaf(qv[15], p.y, a1);
    return a0 + a1;
}

// ===== fused scores + softmax + aggregation (wave per dst node) ============
__global__ __launch_bounds__(256) void node_attn_kernel(
    const unsigned short* __restrict__ qb, const unsigned char* __restrict__ kb8,
    const unsigned short* __restrict__ vb, const float* __restrict__ secb,
    const int2* __restrict__ epair, const int* __restrict__ rowstart,
    float* __restrict__ attn_out, unsigned short* __restrict__ aggb) {
    int node = blockIdx.x * 4 + (threadIdx.x >> 6);
    if (node >= N_NODES) return;
    const int lane = threadIdx.x & 63;
    const int start = rowstart[node];
    const int deg = rowstart[node + 1] - start;
    if (deg == 0) {
        ((unsigned*)(aggb + (size_t)node * DIM))[lane] = 0u;
        return;
    }
    const int h = lane & 7;     // head (score phases)
    const int le = lane >> 3;   // edge slot 0..7
    const int hc = le;          // head (aggregation mapping)

    float qv[16];
    {
        const bf16x8* qp = (const bf16x8*)(qb + (size_t)node * DIM + h * DHEAD);
        bf16x8 q0 = qp[0], q1 = qp[1];
#pragma unroll
        for (int i = 0; i < 8; ++i) {
            qv[i] = bf2f((unsigned short)q0[i]);
            qv[8 + i] = bf2f((unsigned short)q1[i]);
        }
    }

    if (deg <= 64) {
        // ---------- fast path: coalesced int2 preload + register scores ----
        int sall = 0, eall = 0;
        if (lane < deg) {
            int2 p = epair[start + lane];
            sall = p.x;
            eall = p.y;
        }
        float sc[8];
        float m = -INFINITY;
#pragma unroll
        for (int t = 0; t < 8; ++t) {
            sc[t] = -INFINITY;
            if (t * 8 < deg) {                       // wave-uniform
                int jj = t * 8 + le;
                bool valid = jj < deg;
                int s = __shfl(sall, valid ? jj : deg - 1);
                uint4 kw = *(const uint4*)(kb8 + (size_t)s * DIM + h * 16);
                float acc = score_dot_fp8(qv, kw);
                if (valid) sc[t] = acc * 0.25f + secb[s * NHEAD + h];
            }
            m = fmaxf(m, sc[t]);
        }
        m = fmaxf(m, __shfl_xor(m, 8));
        m = fmaxf(m, __shfl_xor(m, 16));
        m = fmaxf(m, __shfl_xor(m, 32));

        float ev[8];
        float ssum = 0.f;
#pragma unroll
        for (int t = 0; t < 8; ++t) {
            ev[t] = (t * 8 + le < deg) ? __expf(sc[t] - m) : 0.f;
            ssum += ev[t];
        }
        ssum += __shfl_xor(ssum, 8);
        ssum += __shfl_xor(ssum, 16);
        ssum += __shfl_xor(ssum, 32);
        const float rinv = 1.f / (ssum + 1e-9f);     // head (lane&7)

        float2 acc2 = {0.f, 0.f};
#pragma unroll
        for (int t = 0; t < 8; ++t) {
            if (t * 8 < deg) {                       // wave-uniform
                // batch all 8 gathers (independent, in flight together)
                unsigned vvr[8];
#pragma unroll
                for (int le2 = 0; le2 < 8; ++le2) {
                    int jj = t * 8 + le2;            // uniform
                    int s = __shfl(sall, (jj < deg) ? jj : deg - 1);  // uniform
                    vvr[le2] = ((const unsigned*)(vb + (size_t)s * DIM))[lane];
                }
#pragma unroll
                for (int le2 = 0; le2 < 8; ++le2) {
                    float evd = __shfl(ev[t], le2 * 8 + hc);
                    acc2.x = fmaf(evd, bf2f((unsigned short)(vvr[le2] & 0xFFFFu)), acc2.x);
                    acc2.y = fmaf(evd, bf2f((unsigned short)(vvr[le2] >> 16)), acc2.y);
                }
            }
        }
        const float rinv_c = __shfl(rinv, hc);       // head (lane>>3)
        unsigned short o0 = f2bf(acc2.x * rinv_c);
        unsigned short o1 = f2bf(acc2.y * rinv_c);
        ((unsigned*)(aggb + (size_t)node * DIM))[lane] =
            (unsigned)o0 | ((unsigned)o1 << 16);

        // attn write: shfl hoisted OUT of the divergent guard (EXEC-safe)
#pragma unroll
        for (int t = 0; t < 8; ++t) {
            int jj = t * 8 + le;
            int e = __shfl(eall, (jj < deg) ? jj : 0);   // all lanes execute
            if (jj < deg) attn_out[(size_t)e * NHEAD + h] = ev[t] * rinv;
        }
        return;
    }

    // ---------- slow path (deg > 64): memory-staged, always correct ----------
    float m = -INFINITY;
    for (int j = 0; j < deg; j += 8) {
        int jj = j + le;
        float sc = -INFINITY;
        if (jj < deg) {
            int2 p = epair[start + jj];
            int s = p.x;
            uint4 kw = *(const uint4*)(kb8 + (size_t)s * DIM + h * 16);
            float acc = score_dot_fp8(qv, kw);
            sc = acc * 0.25f + secb[s * NHEAD + h];
            attn_out[(size_t)p.y * NHEAD + h] = sc;
        }
        m = fmaxf(m, sc);
    }
    m = fmaxf(m, __shfl_xor(m, 8));
    m = fmaxf(m, __shfl_xor(m, 16));
    m = fmaxf(m, __shfl_xor(m, 32));

    float ssum = 0.f;
    float2 acc2 = {0.f, 0.f};
    for (int j = 0; j < deg; j += 8) {
        int jj = j + le;
        float ev = 0.f;
        if (jj < deg) {
            int e = epair[start + jj].y;
            ev = __expf(attn_out[(size_t)e * NHEAD + h] - m);
        }
        ssum += ev;
        int lim = deg - j; if (lim > 8) lim = 8;
        for (int le2 = 0; le2 < lim; ++le2) {
            float evd = __shfl(ev, le2 * 8 + hc);
            int s = epair[start + j + le2].x;
            unsigned vv = ((const unsigned*)(vb + (size_t)s * DIM))[lane];
            acc2.x = fmaf(evd, bf2f((unsigned short)(vv & 0xFFFFu)), acc2.x);
            acc2.y = fmaf(evd, bf2f((unsigned short)(vv >> 16)), acc2.y);
        }
    }
    ssum += __shfl_xor(ssum, 8);
    ssum += __shfl_xor(ssum, 16);
    ssum += __shfl_xor(ssum, 32);
    const float rinv = 1.f / (ssum + 1e-9f);
    const float rinv_c = __shfl(rinv, hc);

    unsigned short o0 = f2bf(acc2.x * rinv_c);
    unsigned short o1 = f2bf(acc2.y * rinv_c);
    ((unsigned*)(aggb + (size_t)node * DIM))[lane] =
        (unsigned)o0 | ((unsigned)o1 << 16);

    for (int j = 0; j < deg; j += 8) {
        int jj = j + le;
        if (jj < deg) {
            int e = epair[start + jj].y;
            float sc = attn_out[(size_t)e * NHEAD + h];
            attn_out[(size_t)e * NHEAD + h] = __expf(sc - m) * rinv;
        }
    }
}

// ===== fused double GEMM+LN: out = LN2(mid + relu(mid@W2+b2)),
//       mid = LN1(hb + agg@Wo+bo); midb never hits global. 512 thr/128 rows.
__global__ __launch_bounds__(512) void gemm_ln12_kernel(
    const unsigned short* __restrict__ A,      // aggb
    const unsigned short* __restrict__ Wt,     // Wo @ +0, W2 @ +16384
    const float* __restrict__ bo, const float* __restrict__ b2,
    const unsigned short* __restrict__ resid,  // hb
    const float* __restrict__ g1, const float* __restrict__ be1,
    const float* __restrict__ g2, const float* __restrict__ be2,
    float* __restrict__ outp, int nrows) {
    __shared__ alignas(16) unsigned char Wl[32768];
    __shared__ alignas(16) unsigned char Mt[32768];
    const int t = threadIdx.x;
    const int l = t & 63, wave = t >> 6;
    const int l15 = l & 15, lg = l >> 4;
    const int r0 = blockIdx.x * 128 + wave * 16;
    const int arow = r0 + l15;
    const bool aok = arow < nrows;
    const int orow0 = r0 + lg * 4;
    unsigned char* MtW = Mt + wave * 4096;

    // stage Wo
#pragma unroll
    for (int i = 0; i < 4; ++i) {
        int c = t + 512 * i;
        int n = c >> 4, s = c & 15;
        bf16x8 val = *(const bf16x8*)(Wt + c * 8);
        *(bf16x8*)(Wl + n * 256 + ((s * 16) ^ ((n & 7) << 4))) = val;
    }
    bf16x8 af[4];
#pragma unroll
    for (int k0 = 0; k0 < 4; ++k0) {
        bf16x8 z = (bf16x8){0, 0, 0, 0, 0, 0, 0, 0};
        af[k0] = aok ? *(const bf16x8*)(A + (size_t)arow * DIM + k0 * 32 + lg * 8) : z;
    }
    __syncthreads();

    float mid[8][4];    // bf16-rounded mid values, kept for LN2 residual
    {
        f32x4 acc[8];
#pragma unroll
        for (int n = 0; n < 8; ++n) acc[n] = (f32x4){0.f, 0.f, 0.f, 0.f};
#pragma unroll
        for (int k0 = 0; k0 < 4; ++k0) {
#pragma unroll
            for (int n = 0; n < 8; ++n) {
                int row = n * 16 + l15;
                int kb = (k0 * 64 + lg * 16) ^ ((row & 7) << 4);
                bf16x8 bfr = *(bf16x8*)(Wl + row * 256 + kb);
                acc[n] = __builtin_amdgcn_mfma_f32_16x16x32_bf16(af[k0], bfr, acc[n], 0, 0, 0);
            }
        }
        float bv[8], gv[8], bev[8];
#pragma unroll
        for (int n = 0; n < 8; ++n) {
            int col = n * 16 + l15;
            bv[n] = bo[col]; gv[n] = g1[col]; bev[n] = be1[col];
        }
#pragma unroll
        for (int i = 0; i < 4; ++i) {
            int r = orow0 + i;
            int rloc = lg * 4 + i;
            float xv[8];
            float s = 0.f;
            if (r < nrows) {
#pragma unroll
                for (int n = 0; n < 8; ++n) {
                    float val = acc[n][i] + bv[n]
                              + bf2f(resid[(size_t)r * DIM + n * 16 + l15]);
                    xv[n] = val;
                    s += val;
                }
            } else {
#pragma unroll
                for (int n = 0; n < 8; ++n) xv[n] = 0.f;
            }
            s += __shfl_xor(s, 1); s += __shfl_xor(s, 2);
            s += __shfl_xor(s, 4); s += __shfl_xor(s, 8);
            float mean = s * (1.f / 128.f);
            float var = 0.f;
#pragma unroll
            for (int n = 0; n < 8; ++n) {
                float d = xv[n] - mean;
                var += d * d;
            }
            var += __shfl_xor(var, 1); var += __shfl_xor(var, 2);
            var += __shfl_xor(var, 4); var += __shfl_xor(var, 8);
            float rstd = rsqrtf(var * (1.f / 128.f) + 1e-5f);
#pragma unroll
            for (int n = 0; n < 8; ++n) {
                int col = n * 16 + l15;
                unsigned short mb = f2bf((xv[n] - mean) * rstd * gv[n] + bev[n]);
                mid[n][i] = bf2f(mb);
                *(unsigned short*)(MtW + ((rloc * 256 + col * 2) ^ ((rloc & 7) << 4))) = mb;
            }
        }
    }
    __syncthreads();   // Wo reads + Mt writes complete

    bf16x8 af2[4];
#pragma unroll
    for (int k0 = 0; k0 < 4; ++k0)
        af2[k0] = *(const bf16x8*)(MtW + ((l15 * 256 + k0 * 64 + lg * 16) ^ ((l15 & 7) << 4)));

    // stage W2
#pragma unroll
    for (int i = 0; i < 4; ++i) {
        int c = t + 512 * i;
        int n = c >> 4, s = c & 15;
        bf16x8 val = *(const bf16x8*)(Wt + 16384 + c * 8);
        *(bf16x8*)(Wl + n * 256 + ((s * 16) ^ ((n & 7) << 4))) = val;
    }
    __syncthreads();

    {
        f32x4 acc[8];
#pragma unroll
        for (int n = 0; n < 8; ++n) acc[n] = (f32x4){0.f, 0.f, 0.f, 0.f};
#pragma unroll
        for (int k0 = 0; k0 < 4; ++k0) {
#pragma unroll
            for (int n = 0; n < 8; ++n) {
                int row = n * 16 + l15;
                int kb = (k0 * 64 + lg * 16) ^ ((row & 7) << 4);
                bf16x8 bfr = *(bf16x8*)(Wl + row * 256 + kb);
                acc[n] = __builtin_amdgcn_mfma_f32_16x16x32_bf16(af2[k0], bfr, acc[n], 0, 0, 0);
            }
        }
        float bv[8], gv[8], bev[8];
#pragma unroll
        for (int n = 0; n < 8; ++n) {
            int col = n * 16 + l15;
            bv[n] = b2[col]; gv[n] = g2[col]; bev[n] = be2[col];
        }
#pragma unroll
        for (int i = 0; i < 4; ++i) {
            int r = orow0 + i;
            float xv[8];
            float s = 0.f;
#pragma unroll
            for (int n = 0; n < 8; ++n) {
                float val = fmaxf(acc[n][i] + bv[n], 0.f) + mid[n][i];
                xv[n] = val;
                s += val;
            }
            s += __shfl_xor(s, 1); s += __shfl_xor(s, 2);
            s += __shfl_xor(s, 4); s += __shfl_xor(s, 8);
            float mean = s * (1.f / 128.f);
            float var = 0.f;
#pragma unroll
            for (int n = 0; n < 8; ++n) {
                float d = xv[n] - mean;
                var += d * d;
            }
            var += __shfl_xor(var, 1); var += __shfl_xor(var, 2);
            var += __shfl_xor(var, 4); var += __shfl_xor(var, 8);
            float rstd = rsqrtf(var * (1.f / 128.f) + 1e-5f);
            if (r < nrows) {
#pragma unroll
                for (int n = 0; n < 8; ++n) {
                    int col = n * 16 + l15;
                    outp[(size_t)r * DIM + col] = (xv[n] - mean) * rstd * gv[n] + bev[n];
                }
            }
        }
    }
}

extern "C" void kernel_launch(void* const* d_in, const int* in_sizes, int n_in,
                              void* d_out, int out_size, void* d_ws, size_t ws_size,
                              hipStream_t stream) {
    const float* x    = (const float*)d_in[0];
    const int*   ei   = (const int*)d_in[1];
    const float* sec  = (const float*)d_in[2];
    const float* W1   = (const float*)d_in[3];
    const float* b1   = (const float*)d_in[4];
    const float* W2   = (const float*)d_in[5];
    const float* b2   = (const float*)d_in[6];
    const float* Wq   = (const float*)d_in[7];
    const float* bq   = (const float*)d_in[8];
    const float* Wk   = (const float*)d_in[9];
    const float* bk   = (const float*)d_in[10];
    const float* Wv   = (const float*)d_in[11];
    const float* bvp  = (const float*)d_in[12];
    const float* Wsec = (const float*)d_in[13];
    const float* bsec = (const float*)d_in[14];
    const float* Wo   = (const float*)d_in[15];
    const float* bo   = (const float*)d_in[16];
    const float* g1   = (const float*)d_in[17];
    const float* be1  = (const float*)d_in[18];
    const float* g2   = (const float*)d_in[19];
    const float* be2  = (const float*)d_in[20];

    const int* srcp = ei;             // edge_index[0]
    const int* dstp = ei + N_EDGES;   // edge_index[1]

    char* wsb = (char*)d_ws;
    unsigned short* hb   = (unsigned short*)(wsb);              // 12.8MB bf16
    unsigned short* qbu  = (unsigned short*)(wsb + 12800000);   // bf16
    unsigned char*  kb8  = (unsigned char*)(wsb + 25600000);    // fp8, 6.4MB
    unsigned short* vbu  = (unsigned short*)(wsb + 38400000);   // bf16
    unsigned short* aggb = (unsigned short*)(wsb + 51200000);
    float* secb          = (float*)(wsb + 76800000);            // 1.6MB
    unsigned short* Wt   = (unsigned short*)(wsb + 78400000);   // 192KB
    int* deg             = (int*)(wsb + 78600000);              // 200KB
    int* ctr             = (int*)(wsb + 78800000);              // 200KB
    int* rowstart        = (int*)(wsb + 79000000);              // 200KB+4
    int2* epair          = (int2*)(wsb + 79200256);             // 6.4MB
    int* bsum            = (int*)(wsb + 85600512);              // 784B

    float* outp = (float*)d_out;                 // [N,128]
    float* attn = outp + (size_t)N_NODES * DIM;  // [E,8]

    dim3 blk(256);
    const int wgrid = (N_NODES + 3) / 4;             // 12500

    // zero deg+ctr (adjacent 400KB) — graph-capturable async memset
    hipMemsetAsync(deg, 0, 400000, stream);

    setup_kernel<<<SETUP_W + SETUP_CNT + SETUP_SEC, blk, 0, stream>>>(
        W1, Wq, Wk, Wv, Wo, W2, Wt, dstp, deg, sec, Wsec, bsec, secb);
    blocksum_kernel<<<NSCAN_BLK, blk, 0, stream>>>(deg, bsum);
    scanfin2_kernel<<<NSCAN_BLK, blk, 0, stream>>>(deg, bsum, rowstart);

    fill_hqkv_kernel<<<HQKV_GRID + FILL_GRID, dim3(512), 0, stream>>>(
        srcp, dstp, rowstart, ctr, epair,
        x, Wt, b1, bq, bk, bvp, hb, qbu, kb8, vbu, N_NODES);

    node_attn_kernel<<<wgrid, blk, 0, stream>>>(qbu, kb8, vbu, secb, epair,
                                                rowstart, attn, aggb);

    gemm_ln12_kernel<<<HQKV_GRID, dim3(512), 0, stream>>>(aggb, Wt + 65536, bo, b2, hb,
                                                          g1, be1, g2, be2, outp, N_NODES);
}